// Round 1
// 2772.086 us; speedup vs baseline: 1.0199x; 1.0199x over previous
//
#include <hip/hip_runtime.h>
#include <cmath>

#define Bb   32
#define Tt   512
#define INd  128
#define RES  2048
#define OUTd 64

#define BM 64
#define BN 64
#define BK 16

typedef unsigned short u16;
typedef __attribute__((ext_vector_type(4))) unsigned short u16x4;
typedef __attribute__((ext_vector_type(8))) unsigned short u16x8;
typedef __attribute__((ext_vector_type(8))) short bf8;
typedef __attribute__((ext_vector_type(4))) float f32x4;

// fp32 = bf16 hi (RNE) + bf16 lo (trunc residual); |err| <= 2^-17 |a|
__device__ __forceinline__ void splitf(float a, u16& h, u16& l) {
    unsigned u = __float_as_uint(a);
    unsigned r = (u + 0x7fffu + ((u >> 16) & 1u)) & 0xffff0000u;
    h = (u16)(r >> 16);
    float d = a - __uint_as_float(r);
    l = (u16)(__float_as_uint(d) >> 16);
}
__device__ __forceinline__ float bf2f(u16 h) {
    return __uint_as_float((unsigned)h << 16);
}
__device__ __forceinline__ void split8(const float4& a, const float4& b,
                                       u16x8& h, u16x8& l) {
    u16 hh, ll;
    splitf(a.x, hh, ll); h[0] = hh; l[0] = ll;
    splitf(a.y, hh, ll); h[1] = hh; l[1] = ll;
    splitf(a.z, hh, ll); h[2] = hh; l[2] = ll;
    splitf(a.w, hh, ll); h[3] = hh; l[3] = ll;
    splitf(b.x, hh, ll); h[4] = hh; l[4] = ll;
    splitf(b.y, hh, ll); h[5] = hh; l[5] = ll;
    splitf(b.z, hh, ll); h[6] = hh; l[6] = ll;
    splitf(b.w, hh, ll); h[7] = hh; l[7] = ll;
}

#define MICRO(SA, SB)                                                           \
  do {                                                                          \
    _Pragma("unroll")                                                           \
    for (int kk = 0; kk < BK; ++kk) {                                           \
      const float4 a4 = *(const float4*)&SA[kk][ty << 2];                       \
      const float4 b4 = *(const float4*)&SB[kk][tx << 2];                       \
      acc[0][0] += a4.x*b4.x; acc[0][1] += a4.x*b4.y;                           \
      acc[0][2] += a4.x*b4.z; acc[0][3] += a4.x*b4.w;                           \
      acc[1][0] += a4.y*b4.x; acc[1][1] += a4.y*b4.y;                           \
      acc[1][2] += a4.y*b4.z; acc[1][3] += a4.y*b4.w;                           \
      acc[2][0] += a4.z*b4.x; acc[2][1] += a4.z*b4.y;                           \
      acc[2][2] += a4.z*b4.z; acc[2][3] += a4.z*b4.w;                           \
      acc[3][0] += a4.w*b4.x; acc[3][1] += a4.w*b4.y;                           \
      acc[3][2] += a4.w*b4.z; acc[3][3] += a4.w*b4.w;                           \
    }                                                                           \
  } while (0)

// 128x128 tile, K=32 slice, bf16x3. LDS row stride 40 u16.
#define MFMA_TILE()                                                              \
  do {                                                                           \
    bf8 aH[4], aL[4], bH[4], bL[4];                                              \
    _Pragma("unroll")                                                            \
    for (int i = 0; i < 4; ++i) {                                                \
      const int ar = (wm*64 + i*16 + l15)*40 + quad*8;                           \
      aH[i] = *(const bf8*)&Ah[ar]; aL[i] = *(const bf8*)&Al[ar];                \
      const int br = (wn*64 + i*16 + l15)*40 + quad*8;                           \
      bH[i] = *(const bf8*)&Bh[br]; bL[i] = *(const bf8*)&Bl[br];                \
    }                                                                            \
    _Pragma("unroll")                                                            \
    for (int i = 0; i < 4; ++i)                                                  \
      _Pragma("unroll")                                                          \
      for (int j = 0; j < 4; ++j) {                                              \
        acc[i][j] = __builtin_amdgcn_mfma_f32_16x16x32_bf16(aH[i], bH[j], acc[i][j], 0, 0, 0); \
        acc[i][j] = __builtin_amdgcn_mfma_f32_16x16x32_bf16(aH[i], bL[j], acc[i][j], 0, 0, 0); \
        acc[i][j] = __builtin_amdgcn_mfma_f32_16x16x32_bf16(aL[i], bH[j], acc[i][j], 0, 0, 0); \
      }                                                                          \
  } while (0)

// Transpose + split weights: in (K x N fp32) -> outH/outL (N x K bf16).
__global__ __launch_bounds__(256)
void tconv_kernel(const float* __restrict__ in, u16* __restrict__ outH,
                  u16* __restrict__ outL, int K, int N)
{
    __shared__ float T[64][65];
    const int n0 = blockIdx.x * 64, k0 = blockIdx.y * 64;
    const int t = threadIdx.x;
    const int r = t >> 2, c0 = (t & 3) * 16;
#pragma unroll
    for (int i = 0; i < 4; ++i) {
        const float4 v = *(const float4*)&in[(size_t)(k0 + r) * N + n0 + c0 + 4*i];
        T[r][c0 + 4*i + 0] = v.x; T[r][c0 + 4*i + 1] = v.y;
        T[r][c0 + 4*i + 2] = v.z; T[r][c0 + 4*i + 3] = v.w;
    }
    __syncthreads();
    const int n = t >> 2, ck = (t & 3) * 16;
    u16x8 h0, h1, l0, l1;
#pragma unroll
    for (int i = 0; i < 8; ++i) { u16 h, l; splitf(T[ck + i][n], h, l); h0[i] = h; l0[i] = l; }
#pragma unroll
    for (int i = 0; i < 8; ++i) { u16 h, l; splitf(T[ck + 8 + i][n], h, l); h1[i] = h; l1[i] = l; }
    const size_t ob = (size_t)(n0 + n) * K + k0 + ck;
    *(u16x8*)&outH[ob] = h0; *(u16x8*)&outH[ob + 8] = h1;
    *(u16x8*)&outL[ob] = l0; *(u16x8*)&outL[ob + 8] = l1;
}

// Reservoir step on bf16 hi/lo state planes (row = b*512 + 4w + class).
// K-loop register-prefetches the next slice; epilogue via LDS (coalesced u16x8).
__global__ __launch_bounds__(256)
void step_mfma_kernel(u16* __restrict__ Sh, u16* __restrict__ Sl,
                      const float* __restrict__ X,
                      const u16* __restrict__ WTh, const u16* __restrict__ WTl,
                      const u16* __restrict__ WinTh, const u16* __restrict__ WinTl,
                      int cin, int cout, int s)
{
    __shared__ u16 LB[4 * 128 * 40];          // 40 KB, aliased below
    u16* Ah = LB;
    u16* Al = LB + 5120;
    u16* Bh = LB + 10240;
    u16* Bl = LB + 15360;
    float* Cf = (float*)LB;                   // 64x128 f32 = 32 KB (epilogue)

    const int tid = threadIdx.x;
    const int q0  = blockIdx.x * 128;         // reservoir-col tile
    const int b   = blockIdx.y;
    const int bofs = b * Tt;
    const int wid = tid >> 6, lane = tid & 63;
    const int wm = wid & 1, wn = wid >> 1;
    const int l15 = lane & 15, quad = lane >> 4;
    const int row  = tid & 127;               // staging row within 128-tile
    const int pick = tid >> 7;                // 0: A-operand (state), 1: B (W)

    f32x4 acc[4][4];
    const f32x4 zz = {0.f, 0.f, 0.f, 0.f};
#pragma unroll
    for (int i = 0; i < 4; ++i)
#pragma unroll
        for (int j = 0; j < 4; ++j) acc[i][j] = zz;

    u16* dH = (pick ? Bh : Ah) + row * 40;
    u16* dL = (pick ? Bl : Al) + row * 40;

    if (s > 0) {
        const size_t gr = pick ? (size_t)(q0 + row) * RES
                               : (size_t)(bofs + 4 * row + cin) * RES;
        const u16* gH = (pick ? WTh : Sh) + gr;
        const u16* gL = (pick ? WTl : Sl) + gr;
        u16x8 rh0, rh1, rh2, rh3, rl0, rl1, rl2, rl3;
#define LDK(K0)                                                                 \
        rh0 = *(const u16x8*)&gH[(K0) + 0];  rh1 = *(const u16x8*)&gH[(K0) + 8];\
        rh2 = *(const u16x8*)&gH[(K0) + 16]; rh3 = *(const u16x8*)&gH[(K0) + 24];\
        rl0 = *(const u16x8*)&gL[(K0) + 0];  rl1 = *(const u16x8*)&gL[(K0) + 8];\
        rl2 = *(const u16x8*)&gL[(K0) + 16]; rl3 = *(const u16x8*)&gL[(K0) + 24];
        LDK(0)
        for (int k0 = 0; k0 < RES; k0 += 32) {
            if (k0) __syncthreads();
            *(u16x8*)&dH[0]  = rh0; *(u16x8*)&dH[8]  = rh1;
            *(u16x8*)&dH[16] = rh2; *(u16x8*)&dH[24] = rh3;
            *(u16x8*)&dL[0]  = rl0; *(u16x8*)&dL[8]  = rl1;
            *(u16x8*)&dL[16] = rl2; *(u16x8*)&dL[24] = rl3;
            __syncthreads();
            if (k0 + 32 < RES) { LDK(k0 + 32) }
            MFMA_TILE();
        }
        __syncthreads();
#undef LDK
    }

    // input projection: K=128 over x[b, 4w+s-2, :] @ Win
    for (int k0 = 0; k0 < INd; k0 += 32) {
        if (pick == 0) {
            const int t = 4 * row + s - 2;
            u16x8 h0 = {0,0,0,0,0,0,0,0}, h1 = h0, h2 = h0, h3 = h0;
            u16x8 l0 = h0, l1 = h0, l2 = h0, l3 = h0;
            if (t >= 0) {
                const float* xr = X + (size_t)(bofs + t) * INd + k0;
                const float4 f0 = *(const float4*)&xr[0];
                const float4 f1 = *(const float4*)&xr[4];
                const float4 f2 = *(const float4*)&xr[8];
                const float4 f3 = *(const float4*)&xr[12];
                const float4 f4 = *(const float4*)&xr[16];
                const float4 f5 = *(const float4*)&xr[20];
                const float4 f6 = *(const float4*)&xr[24];
                const float4 f7 = *(const float4*)&xr[28];
                split8(f0, f1, h0, l0); split8(f2, f3, h1, l1);
                split8(f4, f5, h2, l2); split8(f6, f7, h3, l3);
            }
            *(u16x8*)&dH[0] = h0;  *(u16x8*)&dH[8] = h1;
            *(u16x8*)&dH[16] = h2; *(u16x8*)&dH[24] = h3;
            *(u16x8*)&dL[0] = l0;  *(u16x8*)&dL[8] = l1;
            *(u16x8*)&dL[16] = l2; *(u16x8*)&dL[24] = l3;
        } else {
            const size_t gr = (size_t)(q0 + row) * INd + k0;
            *(u16x8*)&dH[0]  = *(const u16x8*)&WinTh[gr];
            *(u16x8*)&dH[8]  = *(const u16x8*)&WinTh[gr + 8];
            *(u16x8*)&dH[16] = *(const u16x8*)&WinTh[gr + 16];
            *(u16x8*)&dH[24] = *(const u16x8*)&WinTh[gr + 24];
            *(u16x8*)&dL[0]  = *(const u16x8*)&WinTl[gr];
            *(u16x8*)&dL[8]  = *(const u16x8*)&WinTl[gr + 8];
            *(u16x8*)&dL[16] = *(const u16x8*)&WinTl[gr + 16];
            *(u16x8*)&dL[24] = *(const u16x8*)&WinTl[gr + 24];
        }
        __syncthreads();
        MFMA_TILE();
        __syncthreads();
    }

    // epilogue via LDS: all global I/O is coalesced u16x8.
    for (int h = 0; h < 2; ++h) {
        __syncthreads();
        if (wm == h) {
#pragma unroll
            for (int i = 0; i < 4; ++i)
#pragma unroll
                for (int j = 0; j < 4; ++j)
#pragma unroll
                    for (int rg = 0; rg < 4; ++rg)
                        Cf[(i * 16 + quad * 4 + rg) * 128 + wn * 64 + j * 16 + l15]
                            = acc[i][j][rg];
        }
        __syncthreads();
#pragma unroll
        for (int pass = 0; pass < 4; ++pass) {
            const int r  = (tid >> 4) + pass * 16;      // 0..63
            const int c0 = (tid & 15) * 8;              // 0..120
            const int wrow = h * 64 + r;
            const float4 v0 = *(const float4*)&Cf[r * 128 + c0];
            const float4 v1 = *(const float4*)&Cf[r * 128 + c0 + 4];
            float vv[8] = {v0.x, v0.y, v0.z, v0.w, v1.x, v1.y, v1.z, v1.w};
            u16x8 ph, pl;
            if (s > 0) {
                const size_t prow = (size_t)(bofs + 4 * wrow + cin) * RES + q0 + c0;
                ph = *(const u16x8*)&Sh[prow];
                pl = *(const u16x8*)&Sl[prow];
            }
            u16x8 oh, ol;
#pragma unroll
            for (int e = 0; e < 8; ++e) {
                float prev = (s > 0) ? (bf2f(ph[e]) + bf2f(pl[e])) : 0.f;
                float v = 0.7f * prev + 0.3f * sinf(vv[e]);
                u16 hh, ll; splitf(v, hh, ll);
                oh[e] = hh; ol[e] = ll;
            }
            const size_t orow = (size_t)(bofs + 4 * wrow + cout) * RES + q0 + c0;
            *(u16x8*)&Sh[orow] = oh;
            *(u16x8*)&Sl[orow] = ol;
        }
    }
}

// Gram on bf16 planes: A[b] = (Sh+Sl)(Sh+Sl)^T + ones + reg*I, bf16x3.
__global__ __launch_bounds__(256)
void gram_mfma_kernel(const u16* __restrict__ Sh, const u16* __restrict__ Sl,
                      float* __restrict__ A, const float* __restrict__ lam)
{
    __shared__ u16 LB[4 * 128 * 40];
    u16* Ah = LB;
    u16* Al = LB + 5120;
    u16* Bh = LB + 10240;
    u16* Bl = LB + 15360;
    float* Cf = (float*)LB;                   // 64 x 132 f32 = 33.8 KB

    const int tid = threadIdx.x;
    const int bt  = blockIdx.y;
    int ti = 0, rem = (int)blockIdx.x;
    while (rem >= 4 - ti) { rem -= 4 - ti; ++ti; }
    const int tj = ti + rem;
    const int n0 = ti * 128, m0 = tj * 128;
    const int bofs = bt * Tt;

    const int wid = tid >> 6, lane = tid & 63;
    const int wm = wid & 1, wn = wid >> 1;
    const int l15 = lane & 15, quad = lane >> 4;
    const int row  = tid & 127;
    const int pick = tid >> 7;

    f32x4 acc[4][4];
    const f32x4 zz = {0.f, 0.f, 0.f, 0.f};
#pragma unroll
    for (int i = 0; i < 4; ++i)
#pragma unroll
        for (int j = 0; j < 4; ++j) acc[i][j] = zz;

    u16* dH = (pick ? Bh : Ah) + row * 40;
    u16* dL = (pick ? Bl : Al) + row * 40;
    const size_t gr = (size_t)(bofs + (pick ? m0 : n0) + row) * RES;
    const u16* gH = Sh + gr;
    const u16* gL = Sl + gr;

    u16x8 rh0, rh1, rh2, rh3, rl0, rl1, rl2, rl3;
#define LDK(K0)                                                                 \
    rh0 = *(const u16x8*)&gH[(K0) + 0];  rh1 = *(const u16x8*)&gH[(K0) + 8];    \
    rh2 = *(const u16x8*)&gH[(K0) + 16]; rh3 = *(const u16x8*)&gH[(K0) + 24];   \
    rl0 = *(const u16x8*)&gL[(K0) + 0];  rl1 = *(const u16x8*)&gL[(K0) + 8];    \
    rl2 = *(const u16x8*)&gL[(K0) + 16]; rl3 = *(const u16x8*)&gL[(K0) + 24];
    LDK(0)
    for (int k0 = 0; k0 < RES; k0 += 32) {
        if (k0) __syncthreads();
        *(u16x8*)&dH[0]  = rh0; *(u16x8*)&dH[8]  = rh1;
        *(u16x8*)&dH[16] = rh2; *(u16x8*)&dH[24] = rh3;
        *(u16x8*)&dL[0]  = rl0; *(u16x8*)&dL[8]  = rl1;
        *(u16x8*)&dL[16] = rl2; *(u16x8*)&dL[24] = rl3;
        __syncthreads();
        if (k0 + 32 < RES) { LDK(k0 + 32) }
        MFMA_TILE();
    }
#undef LDK

    const float reg = log1pf(expf(lam[0]));
    float* Ab = A + (size_t)bt * 512 * 512;
    for (int h = 0; h < 2; ++h) {
        __syncthreads();
        if (wm == h) {
#pragma unroll
            for (int i = 0; i < 4; ++i)
#pragma unroll
                for (int j = 0; j < 4; ++j)
#pragma unroll
                    for (int rg = 0; rg < 4; ++rg)
                        Cf[(i * 16 + quad * 4 + rg) * 132 + wn * 64 + j * 16 + l15]
                            = acc[i][j][rg];
        }
        __syncthreads();
        // row-major half: rows nn = n0+h*64+r, cols m0..m0+127
#pragma unroll
        for (int pass = 0; pass < 4; ++pass) {
            const int r  = (tid >> 4) + pass * 16;
            const int c0 = (tid & 15) * 8;
            const int nn = n0 + h * 64 + r;
            float o[8];
#pragma unroll
            for (int e = 0; e < 8; ++e) {
                const int mm = m0 + c0 + e;
                float v = Cf[r * 132 + c0 + e] + 1.0f;
                if (nn == mm) v += reg;
                o[e] = v;
            }
            float* dst = Ab + (size_t)nn * 512 + m0 + c0;
            *(float4*)&dst[0] = make_float4(o[0], o[1], o[2], o[3]);
            *(float4*)&dst[4] = make_float4(o[4], o[5], o[6], o[7]);
        }
        // transposed half: rows mm = m0+rt, cols n0+h*64 .. +63
#pragma unroll
        for (int pass = 0; pass < 4; ++pass) {
            const int rt  = (tid >> 3) + pass * 32;     // 0..127
            const int c0t = (tid & 7) * 8;              // 0..56
            const int mm  = m0 + rt;
            float o[8];
#pragma unroll
            for (int e = 0; e < 8; ++e) {
                const int nn = n0 + h * 64 + c0t + e;
                float v = Cf[(c0t + e) * 132 + rt] + 1.0f;
                if (nn == mm) v += reg;
                o[e] = v;
            }
            float* dst = Ab + (size_t)mm * 512 + n0 + h * 64 + c0t;
            *(float4*)&dst[0] = make_float4(o[0], o[1], o[2], o[3]);
            *(float4*)&dst[4] = make_float4(o[4], o[5], o[6], o[7]);
        }
    }
}

// Diag-block Cholesky (64x64) + inverse, one wave per batch.
__global__ __launch_bounds__(64)
void chol_diag_inv_kernel(float* __restrict__ Aall, float* __restrict__ Winv,
                          float* __restrict__ WinvT, int k)
{
    __shared__ float P[64][65];
    __shared__ float W[64][65];
    const int b = blockIdx.x, c = threadIdx.x;
    float* A = Aall + (size_t)b * 512 * 512;
    const int j0 = 64 * k;

    for (int m = 0; m < 64; m += 4) {
        const float4 v = *(const float4*)(A + (size_t)(j0 + c) * 512 + j0 + m);
        P[c][m] = v.x; P[c][m+1] = v.y; P[c][m+2] = v.z; P[c][m+3] = v.w;
    }
    __syncthreads();
    for (int j = 0; j < 64; ++j) {
        const float d = sqrtf(P[j][j]);
        if (c >= j) P[c][j] = (c == j) ? d : P[c][j] / d;
        __syncthreads();
        const float pj = (c > j) ? P[c][j] : 0.f;
        for (int m = j + 1; m <= c; ++m) P[c][m] -= pj * P[m][j];
        __syncthreads();
    }
    for (int j = 0; j < 64; ++j) {
        float sv = (j == c) ? 1.f : 0.f;
        for (int m = c; m < j; ++m) sv -= P[j][m] * W[m][c];
        W[j][c] = (j >= c) ? sv / P[j][j] : 0.f;
    }
    __syncthreads();
    for (int m = 0; m < 64; m += 4)
        *(float4*)(A + (size_t)(j0 + c) * 512 + j0 + m) =
            make_float4(P[c][m], P[c][m+1], P[c][m+2], P[c][m+3]);
    float* Wo  = Winv  + ((size_t)b * 8 + k) * 64 * 64;
    float* WoT = WinvT + ((size_t)b * 8 + k) * 64 * 64;
    for (int j = 0; j < 64; ++j) Wo[(size_t)j * 64 + c] = W[j][c];
    for (int m = 0; m < 64; m += 4)
        *(float4*)(WoT + (size_t)c * 64 + m) =
            make_float4(W[m][c], W[m+1][c], W[m+2][c], W[m+3][c]);
}

// Panel TRSM via inverse: L[i0.., k] = A[i0.., k] @ W^T
__global__ __launch_bounds__(256)
void trsm_kernel(float* __restrict__ Aall, const float* __restrict__ WinvT, int k)
{
    __shared__ float St[BK][BM + 4];
    __shared__ float Wt[BK][BN + 4];
    float* A = Aall + (size_t)blockIdx.y * 512 * 512;
    const float* WT = WinvT + ((size_t)blockIdx.y * 8 + k) * 64 * 64;
    const int i0 = (k + 1 + blockIdx.x) * 64, p0 = k * 64;
    const int tid = threadIdx.x;
    const int li = tid >> 2, lk = (tid & 3) << 2;
    const int wk = tid >> 4, wq = (tid & 15) << 2;
    const int ty = tid >> 4, tx = tid & 15;
    float acc[4][4] = {};
    for (int k0 = 0; k0 < 64; k0 += BK) {
        const float4 u = *(const float4*)(A + (size_t)(i0 + li) * 512 + p0 + k0 + lk);
        St[lk + 0][li] = u.x; St[lk + 1][li] = u.y;
        St[lk + 2][li] = u.z; St[lk + 3][li] = u.w;
        *(float4*)&Wt[wk][wq] = *(const float4*)(WT + (size_t)(k0 + wk) * 64 + wq);
        __syncthreads();
        MICRO(St, Wt);
        __syncthreads();
    }
#pragma unroll
    for (int a = 0; a < 4; ++a) {
        const int r = i0 + (ty << 2) + a;
        *(float4*)(A + (size_t)r * 512 + p0 + (tx << 2)) =
            make_float4(acc[a][0], acc[a][1], acc[a][2], acc[a][3]);
    }
}

// Trailing update: A[ti,tj] -= L[ti,k] L[tj,k]^T
__global__ __launch_bounds__(256)
void chol_trailing_kernel(float* __restrict__ Aall, int k)
{
    __shared__ float Ut[BK][BM + 4];
    __shared__ float Vt[BK][BN + 4];
    float* A = Aall + (size_t)blockIdx.y * 512 * 512;
    const int tid = threadIdx.x;
    int a = 0, rem = (int)blockIdx.x;
    while (rem >= a + 1) { rem -= a + 1; ++a; }
    const int ti = k + 1 + a, tj = k + 1 + rem;
    const int i0 = ti * 64, j0c = tj * 64, p0 = k * 64;

    const int li = tid >> 2, lk = (tid & 3) << 2;
    const int ty = tid >> 4, tx = tid & 15;
    float acc[4][4] = {};

    for (int k0 = 0; k0 < 64; k0 += BK) {
        const float4 u = *(const float4*)(A + (size_t)(i0 + li) * 512 + p0 + k0 + lk);
        const float4 v = *(const float4*)(A + (size_t)(j0c + li) * 512 + p0 + k0 + lk);
        Ut[lk + 0][li] = u.x; Ut[lk + 1][li] = u.y;
        Ut[lk + 2][li] = u.z; Ut[lk + 3][li] = u.w;
        Vt[lk + 0][li] = v.x; Vt[lk + 1][li] = v.y;
        Vt[lk + 2][li] = v.z; Vt[lk + 3][li] = v.w;
        __syncthreads();
        MICRO(Ut, Vt);
        __syncthreads();
    }
#pragma unroll
    for (int aa = 0; aa < 4; ++aa) {
        const int r = i0 + (ty << 2) + aa;
        float* crow = A + (size_t)r * 512 + j0c + (tx << 2);
        float4 cv = *(const float4*)crow;
        cv.x -= acc[aa][0]; cv.y -= acc[aa][1];
        cv.z -= acc[aa][2]; cv.w -= acc[aa][3];
        *(float4*)crow = cv;
    }
}

// Blocked fwd+bwd solve, v3: 256 blocks (32 batches x 8 col-splits of 8 cols),
// ONE wave per block. V panel (512x8) lives in LDS with broadcast-only b64
// reads (stride 10 -> conflict-free); A / Winv operands stream global->regs
// in double-buffered 16-k chunks (no LDS staging, no inter-wave broadcast
// duplication). Barriers are single-wave (nearly free). Accumulation order
// per output element identical to fb_solve2 -> same numerics.
__global__ __launch_bounds__(64, 1)
void fb_solve3_kernel(const float* __restrict__ Aall,
                      const float* __restrict__ Winv,
                      const float* __restrict__ WinvT,
                      const float* __restrict__ Y, float* __restrict__ Zall)
{
    __shared__ float V[512][10];   // 8 used cols + 2 pad (bank spread)
    __shared__ float U[64][10];
    const int tid = threadIdx.x;
    const int b   = (int)blockIdx.x >> 3;
    const int c0  = ((int)blockIdx.x & 7) * 8;
    const int ty  = tid >> 2;            // 0..15 -> rows 4*ty..4*ty+3
    const int tx  = tid & 3;             // 0..3  -> cols 2*tx..2*tx+1
    const float* A   = Aall + (size_t)b * 512 * 512;
    const float* Yb  = Y    + (size_t)b * 512 * OUTd + c0;
    float*       Zb  = Zall + (size_t)b * 512 * OUTd + c0;
    const float* Wb  = Winv  + (size_t)b * 8 * 64 * 64 + 4 * ty;
    const float* WbT = WinvT + (size_t)b * 8 * 64 * 64 + 4 * ty;

    for (int t = tid; t < 512 * 4; t += 64) {
        const int row = t >> 2, p = (t & 3) * 2;
        *(float2*)&V[row][p] = *(const float2*)&Yb[(size_t)row * OUTd + p];
    }
    __syncthreads();

    float acc[4][2];
    f32x4 pa[4][4], pb[4][4];

// fwd A chunk: pa[r][q] = A[r0+4ty+r][kk0+4q .. +3]
#define LDA_F(dst, kk0)                                                         \
    { _Pragma("unroll") for (int r_ = 0; r_ < 4; ++r_)                          \
      _Pragma("unroll") for (int q_ = 0; q_ < 4; ++q_)                          \
        dst[r_][q_] = *(const f32x4*)&A[(size_t)(r0 + 4 * ty + r_) * 512 + (kk0) + 4 * q_]; }

#define CMP_F(P, kbase)                                                         \
    { _Pragma("unroll") for (int q_ = 0; q_ < 16; ++q_) {                       \
        const float2 v_ = *(const float2*)&V[(kbase) + q_][2 * tx];             \
        _Pragma("unroll") for (int r_ = 0; r_ < 4; ++r_) {                      \
          acc[r_][0] += P[r_][q_ >> 2][q_ & 3] * v_.x;                          \
          acc[r_][1] += P[r_][q_ >> 2][q_ & 3] * v_.y; } } }

// k-major chunk: dst[i>>2][i&3] = rows 4ty..4ty+3 of operand row (row0+i)
#define LDA_K(dst, base, row0, S)                                               \
    { _Pragma("unroll") for (int i_ = 0; i_ < 16; ++i_)                         \
        dst[i_ >> 2][i_ & 3] = *(const f32x4*)&(base)[(size_t)((row0) + i_) * (S)]; }

#define CMP_K(P, ARR, kbase)                                                    \
    { _Pragma("unroll") for (int i_ = 0; i_ < 16; ++i_) {                       \
        const float2 v_ = *(const float2*)&ARR[(kbase) + i_][2 * tx];           \
        _Pragma("unroll") for (int r_ = 0; r_ < 4; ++r_) {                      \
          acc[r_][0] += P[i_ >> 2][i_ & 3][r_] * v_.x;                          \
          acc[r_][1] += P[i_ >> 2][i_ & 3][r_] * v_.y; } } }

#define ZACC                                                                    \
    { _Pragma("unroll") for (int r_ = 0; r_ < 4; ++r_) {                        \
        acc[r_][0] = 0.f; acc[r_][1] = 0.f; } }

#define URES(R0)                                                                \
    { _Pragma("unroll") for (int r_ = 0; r_ < 4; ++r_)                          \
      _Pragma("unroll") for (int c_ = 0; c_ < 2; ++c_)                          \
        U[4 * ty + r_][2 * tx + c_] =                                           \
            V[(R0) + 4 * ty + r_][2 * tx + c_] - acc[r_][c_]; }

#define VOUT(R0)                                                                \
    { _Pragma("unroll") for (int r_ = 0; r_ < 4; ++r_)                          \
      _Pragma("unroll") for (int c_ = 0; c_ < 2; ++c_)                          \
        V[(R0) + 4 * ty + r_][2 * tx + c_] = acc[r_][c_]; }

#define DIAG(Wp)                                                                \
    { ZACC; LDA_K(pa, Wp, 0, 64); LDA_K(pb, Wp, 16, 64);                        \
      CMP_K(pa, U, 0);  LDA_K(pa, Wp, 32, 64);                                  \
      CMP_K(pb, U, 16); LDA_K(pb, Wp, 48, 64);                                  \
      CMP_K(pa, U, 32); CMP_K(pb, U, 48); }

    // ---- forward: V_k = W_k (Y_k - L[k, 0:64k] @ V) ----
    for (int k = 0; k < 8; ++k) {
        const int r0 = k * 64;
        ZACC;
        if (r0 > 0) {
            LDA_F(pa, 0);
            for (int k0 = 0; k0 < r0; k0 += 32) {
                LDA_F(pb, k0 + 16);
                CMP_F(pa, k0);
                if (k0 + 32 < r0) LDA_F(pa, k0 + 32);
                CMP_F(pb, k0 + 16);
            }
        }
        URES(r0);
        __syncthreads();
        DIAG(WbT + (size_t)k * 4096);
        VOUT(r0);
        __syncthreads();
    }

    // ---- backward: Z_k = W_k^T (V_k - L[64(k+1):, k]^T @ Z) ----
    for (int k = 7; k >= 0; --k) {
        const int r0 = k * 64;
        ZACC;
        if (r0 + 64 < 512) {
            const float* Ac = A + r0 + 4 * ty;
            LDA_K(pa, Ac, r0 + 64, 512);
            for (int m0 = r0 + 64; m0 < 512; m0 += 32) {
                LDA_K(pb, Ac, m0 + 16, 512);
                CMP_K(pa, V, m0);
                if (m0 + 32 < 512) LDA_K(pa, Ac, m0 + 32, 512);
                CMP_K(pb, V, m0 + 16);
            }
        }
        URES(r0);
        __syncthreads();
        DIAG(Wb + (size_t)k * 4096);
        VOUT(r0);
        __syncthreads();
    }

    for (int t = tid; t < 512 * 4; t += 64) {
        const int row = t >> 2, p = (t & 3) * 2;
        *(float2*)&Zb[(size_t)row * OUTd + p] = *(const float2*)&V[row][p];
    }
#undef LDA_F
#undef CMP_F
#undef LDA_K
#undef CMP_K
#undef ZACC
#undef URES
#undef VOUT
#undef DIAG
}

// w[b] = RS_b^T @ Z_b, RS reconstructed as h+l.
__global__ __launch_bounds__(256)
void out_kernel(const u16* __restrict__ Sh, const u16* __restrict__ Sl,
                const float* __restrict__ Z, float* __restrict__ Wout)
{
    __shared__ float Rt[BK][64 + 4];
    __shared__ float Zt[BK][64 + 4];
    const int tid = threadIdx.x;
    const int b   = blockIdx.y;
    const int d0  = blockIdx.x * 64;
    const int kk  = tid >> 4, cq = (tid & 15) << 2;
    const int ty  = tid >> 4, tx = tid & 15;
    float acc[4][4] = {};

    for (int k0 = 0; k0 < Tt; k0 += BK) {
        const size_t ri = (size_t)(b * Tt + k0 + kk) * RES + d0 + cq;
        const u16x4 hv = *(const u16x4*)&Sh[ri];
        const u16x4 lv = *(const u16x4*)&Sl[ri];
        Rt[kk][cq + 0] = bf2f(hv[0]) + bf2f(lv[0]);
        Rt[kk][cq + 1] = bf2f(hv[1]) + bf2f(lv[1]);
        Rt[kk][cq + 2] = bf2f(hv[2]) + bf2f(lv[2]);
        Rt[kk][cq + 3] = bf2f(hv[3]) + bf2f(lv[3]);
        *(float4*)&Zt[kk][cq] =
            *(const float4*)(Z + ((size_t)b * Tt + k0 + kk) * OUTd + cq);
        __syncthreads();
        MICRO(Rt, Zt);
        __syncthreads();
    }
#pragma unroll
    for (int a = 0; a < 4; ++a) {
        const int d = d0 + (ty << 2) + a;
        *(float4*)(Wout + ((size_t)b * RES + d) * OUTd + (tx << 2)) =
            make_float4(acc[a][0], acc[a][1], acc[a][2], acc[a][3]);
    }
}

__global__ __launch_bounds__(64)
void bias_kernel(const float* __restrict__ Z, float* __restrict__ Bout)
{
    const int b = blockIdx.x, o = threadIdx.x;
    const float* Zb = Z + (size_t)b * Tt * OUTd;
    float s = 0.f;
    for (int n = 0; n < Tt; ++n) s += Zb[(size_t)n * OUTd + o];
    Bout[(size_t)b * OUTd + o] = s;
}

extern "C" void kernel_launch(void* const* d_in, const int* in_sizes, int n_in,
                              void* d_out, int out_size, void* d_ws, size_t ws_size,
                              hipStream_t stream)
{
    const float* X    = (const float*)d_in[0];   // (32,512,128)
    const float* Y    = (const float*)d_in[1];   // (32,512,64)
    const float* Wres = (const float*)d_in[2];   // (2048,2048)
    const float* Win  = (const float*)d_in[3];   // (128,2048)
    const float* lam  = (const float*)d_in[4];   // scalar

    float* out  = (float*)d_out;
    float* Wout = out;
    float* Bout = out + (size_t)Bb * RES * OUTd;

    // ws: Sh 64 | Sl 64 | WTh 8 | WTl 8 | WinTh .5 | WinTl .5 | A 32 | Z 4 | Wi 4 | WiT 4 = 189 MB
    char* p = (char*)d_ws;
    u16* Sh    = (u16*)p;   p += (size_t)Bb * Tt * RES * 2;
    u16* Sl    = (u16*)p;   p += (size_t)Bb * Tt * RES * 2;
    u16* WTh   = (u16*)p;   p += (size_t)RES * RES * 2;
    u16* WTl   = (u16*)p;   p += (size_t)RES * RES * 2;
    u16* WinTh = (u16*)p;   p += (size_t)INd * RES * 2;
    u16* WinTl = (u16*)p;   p += (size_t)INd * RES * 2;
    float* A   = (float*)p; p += (size_t)Bb * 512 * 512 * 4;
    float* Z   = (float*)p; p += (size_t)Bb * Tt * OUTd * 4;
    float* Wi  = (float*)p; p += (size_t)Bb * 8 * 64 * 64 * 4;
    float* WiT = (float*)p;

    const dim3 blk(256);
    tconv_kernel<<<dim3(RES / 64, RES / 64), blk, 0, stream>>>(Wres, WTh, WTl, RES, RES);
    tconv_kernel<<<dim3(RES / 64, INd / 64), blk, 0, stream>>>(Win, WinTh, WinTl, INd, RES);

    // classes: s:(cin->cout) 0:(-,2) 1:(2,1) 2:(1,0) 3:(0,1) 4:(1,2) 5:(2,3)
    const dim3 sgrid(RES / 128, Bb);
    step_mfma_kernel<<<sgrid, blk, 0, stream>>>(Sh, Sl, X, WTh, WTl, WinTh, WinTl, 0, 2, 0);
    step_mfma_kernel<<<sgrid, blk, 0, stream>>>(Sh, Sl, X, WTh, WTl, WinTh, WinTl, 2, 1, 1);
    step_mfma_kernel<<<sgrid, blk, 0, stream>>>(Sh, Sl, X, WTh, WTl, WinTh, WinTl, 1, 0, 2);
    step_mfma_kernel<<<sgrid, blk, 0, stream>>>(Sh, Sl, X, WTh, WTl, WinTh, WinTl, 0, 1, 3);
    step_mfma_kernel<<<sgrid, blk, 0, stream>>>(Sh, Sl, X, WTh, WTl, WinTh, WinTl, 1, 2, 4);
    step_mfma_kernel<<<sgrid, blk, 0, stream>>>(Sh, Sl, X, WTh, WTl, WinTh, WinTl, 2, 3, 5);

    gram_mfma_kernel<<<dim3(10, Bb), blk, 0, stream>>>(Sh, Sl, A, lam);

    for (int k = 0; k < 8; ++k) {
        chol_diag_inv_kernel<<<dim3(Bb), dim3(64), 0, stream>>>(A, Wi, WiT, k);
        if (k < 7) {
            trsm_kernel<<<dim3(7 - k, Bb), blk, 0, stream>>>(A, WiT, k);
            const int m = 7 - k;
            chol_trailing_kernel<<<dim3(m * (m + 1) / 2, Bb), blk, 0, stream>>>(A, k);
        }
    }
    fb_solve3_kernel<<<dim3(Bb * 8), dim3(64), 0, stream>>>(A, Wi, WiT, Y, Z);

    out_kernel<<<dim3(RES / 64, Bb), blk, 0, stream>>>(Sh, Sl, Z, Wout);
    bias_kernel<<<dim3(Bb), dim3(OUTd), 0, stream>>>(Z, Bout);
}

// Round 2
// 2521.635 us; speedup vs baseline: 1.1212x; 1.0993x over previous
//
#include <hip/hip_runtime.h>
#include <cmath>

#define Bb   32
#define Tt   512
#define INd  128
#define RES  2048
#define OUTd 64

#define BM 64
#define BN 64
#define BK 16

typedef unsigned short u16;
typedef __attribute__((ext_vector_type(4))) unsigned short u16x4;
typedef __attribute__((ext_vector_type(8))) unsigned short u16x8;
typedef __attribute__((ext_vector_type(8))) short bf8;
typedef __attribute__((ext_vector_type(4))) float f32x4;

// fp32 = bf16 hi (RNE) + bf16 lo (trunc residual); |err| <= 2^-17 |a|
__device__ __forceinline__ void splitf(float a, u16& h, u16& l) {
    unsigned u = __float_as_uint(a);
    unsigned r = (u + 0x7fffu + ((u >> 16) & 1u)) & 0xffff0000u;
    h = (u16)(r >> 16);
    float d = a - __uint_as_float(r);
    l = (u16)(__float_as_uint(d) >> 16);
}
__device__ __forceinline__ float bf2f(u16 h) {
    return __uint_as_float((unsigned)h << 16);
}
__device__ __forceinline__ void split8(const float4& a, const float4& b,
                                       u16x8& h, u16x8& l) {
    u16 hh, ll;
    splitf(a.x, hh, ll); h[0] = hh; l[0] = ll;
    splitf(a.y, hh, ll); h[1] = hh; l[1] = ll;
    splitf(a.z, hh, ll); h[2] = hh; l[2] = ll;
    splitf(a.w, hh, ll); h[3] = hh; l[3] = ll;
    splitf(b.x, hh, ll); h[4] = hh; l[4] = ll;
    splitf(b.y, hh, ll); h[5] = hh; l[5] = ll;
    splitf(b.z, hh, ll); h[6] = hh; l[6] = ll;
    splitf(b.w, hh, ll); h[7] = hh; l[7] = ll;
}

// async global->LDS, 16B per lane. LDS dest is wave-uniform base + lane*16;
// global src is per-lane (carries the chunk swizzle).
__device__ __forceinline__ void gl_lds16(const u16* g, u16* l) {
    __builtin_amdgcn_global_load_lds(
        (const __attribute__((address_space(1))) unsigned int*)g,
        (__attribute__((address_space(3))) unsigned int*)l,
        16, 0, 0);
}

#define MICRO(SA, SB)                                                           \
  do {                                                                          \
    _Pragma("unroll")                                                           \
    for (int kk = 0; kk < BK; ++kk) {                                           \
      const float4 a4 = *(const float4*)&SA[kk][ty << 2];                       \
      const float4 b4 = *(const float4*)&SB[kk][tx << 2];                       \
      acc[0][0] += a4.x*b4.x; acc[0][1] += a4.x*b4.y;                           \
      acc[0][2] += a4.x*b4.z; acc[0][3] += a4.x*b4.w;                           \
      acc[1][0] += a4.y*b4.x; acc[1][1] += a4.y*b4.y;                           \
      acc[1][2] += a4.y*b4.z; acc[1][3] += a4.y*b4.w;                           \
      acc[2][0] += a4.z*b4.x; acc[2][1] += a4.z*b4.y;                           \
      acc[2][2] += a4.z*b4.z; acc[2][3] += a4.z*b4.w;                           \
      acc[3][0] += a4.w*b4.x; acc[3][1] += a4.w*b4.y;                           \
      acc[3][2] += a4.w*b4.z; acc[3][3] += a4.w*b4.w;                           \
    }                                                                           \
  } while (0)

// 128x128 tile, K=32 slice, bf16x3. Linear LDS rows of 32 u16 (64 B) with
// 16B-chunk XOR swizzle c' = c ^ ((row>>1)&3)  ->  max 2-way bank alias (free).
// Buffer layout (u16 offsets): Ah 0 | Al 4096 | Bh 8192 | Bl 12288.
#define MFMA_TILE(BUF)                                                           \
  do {                                                                           \
    bf8 aH[4], aL[4], bH[4], bL[4];                                              \
    const int qd = (quad ^ ((l15 >> 1) & 3)) << 3;                               \
    _Pragma("unroll")                                                            \
    for (int i = 0; i < 4; ++i) {                                                \
      const int ar = (wm*64 + i*16 + l15)*32 + qd;                               \
      const int br = (wn*64 + i*16 + l15)*32 + qd;                               \
      aH[i] = *(const bf8*)&(BUF)[ar];                                           \
      aL[i] = *(const bf8*)&(BUF)[4096 + ar];                                    \
      bH[i] = *(const bf8*)&(BUF)[8192 + br];                                    \
      bL[i] = *(const bf8*)&(BUF)[12288 + br];                                   \
    }                                                                            \
    _Pragma("unroll")                                                            \
    for (int i = 0; i < 4; ++i)                                                  \
      _Pragma("unroll")                                                          \
      for (int j = 0; j < 4; ++j) {                                              \
        acc[i][j] = __builtin_amdgcn_mfma_f32_16x16x32_bf16(aH[i], bH[j], acc[i][j], 0, 0, 0); \
        acc[i][j] = __builtin_amdgcn_mfma_f32_16x16x32_bf16(aH[i], bL[j], acc[i][j], 0, 0, 0); \
        acc[i][j] = __builtin_amdgcn_mfma_f32_16x16x32_bf16(aL[i], bH[j], acc[i][j], 0, 0, 0); \
      }                                                                          \
  } while (0)

// Transpose + split weights: in (K x N fp32) -> outH/outL (N x K bf16).
__global__ __launch_bounds__(256)
void tconv_kernel(const float* __restrict__ in, u16* __restrict__ outH,
                  u16* __restrict__ outL, int K, int N)
{
    __shared__ float T[64][65];
    const int n0 = blockIdx.x * 64, k0 = blockIdx.y * 64;
    const int t = threadIdx.x;
    const int r = t >> 2, c0 = (t & 3) * 16;
#pragma unroll
    for (int i = 0; i < 4; ++i) {
        const float4 v = *(const float4*)&in[(size_t)(k0 + r) * N + n0 + c0 + 4*i];
        T[r][c0 + 4*i + 0] = v.x; T[r][c0 + 4*i + 1] = v.y;
        T[r][c0 + 4*i + 2] = v.z; T[r][c0 + 4*i + 3] = v.w;
    }
    __syncthreads();
    const int n = t >> 2, ck = (t & 3) * 16;
    u16x8 h0, h1, l0, l1;
#pragma unroll
    for (int i = 0; i < 8; ++i) { u16 h, l; splitf(T[ck + i][n], h, l); h0[i] = h; l0[i] = l; }
#pragma unroll
    for (int i = 0; i < 8; ++i) { u16 h, l; splitf(T[ck + 8 + i][n], h, l); h1[i] = h; l1[i] = l; }
    const size_t ob = (size_t)(n0 + n) * K + k0 + ck;
    *(u16x8*)&outH[ob] = h0; *(u16x8*)&outH[ob + 8] = h1;
    *(u16x8*)&outL[ob] = l0; *(u16x8*)&outL[ob + 8] = l1;
}

// Reservoir step on bf16 hi/lo state planes (row = b*512 + 4w + class).
// v2: global_load_lds staging (width 16) into double-buffered 32-KB slice
// buffers; ONE barrier per K-slice. Epilogue via LDS (coalesced u16x8).
__global__ __launch_bounds__(256)
void step_mfma_kernel(u16* __restrict__ Sh, u16* __restrict__ Sl,
                      const float* __restrict__ X,
                      const u16* __restrict__ WTh, const u16* __restrict__ WTl,
                      const u16* __restrict__ WinTh, const u16* __restrict__ WinTl,
                      int cin, int cout, int s)
{
    __shared__ u16 LB[2 * 16384];             // 2 x 32 KB slice buffers
    u16* buf0 = LB;
    u16* buf1 = LB + 16384;
    float* Cf = (float*)LB;                   // 64x128 f32 = 32 KB (epilogue)

    const int tid = threadIdx.x;
    const int q0  = blockIdx.x * 128;         // reservoir-col tile
    const int b   = blockIdx.y;
    const int bofs = b * Tt;
    const int wid = tid >> 6, lane = tid & 63;
    const int wm = wid & 1, wn = wid >> 1;
    const int l15 = lane & 15, quad = lane >> 4;

    f32x4 acc[4][4];
    const f32x4 zz = {0.f, 0.f, 0.f, 0.f};
#pragma unroll
    for (int i = 0; i < 4; ++i)
#pragma unroll
        for (int j = 0; j < 4; ++j) acc[i][j] = zz;

    // per-wave slice staging: wid 0=Ah(Sh) 1=Al(Sl) 2=Bh(WTh) 3=Bl(WTl).
    // lane l covers row r = i*16 + (l>>2), dest chunk l&3; source chunk is
    // pre-swizzled: csrc = (l&3) ^ ((l>>3)&3)  (== (l&3) ^ ((r>>1)&3)).
    const int rl    = lane >> 2;
    const int csrc  = (((lane & 3) ^ ((lane >> 3) & 3)) << 3);
    const u16* plane = (wid == 0) ? (const u16*)Sh
                     : (wid == 1) ? (const u16*)Sl
                     : (wid == 2) ? WTh : WTl;

    auto stage = [&](u16* buf, int k0) {
        u16* ldst = buf + wid * 4096;
#pragma unroll
        for (int i = 0; i < 8; ++i) {
            const int r = i * 16 + rl;
            const size_t grow = (wid < 2) ? (size_t)(bofs + 4 * r + cin)
                                          : (size_t)(q0 + r);
            gl_lds16(&plane[grow * RES + k0 + csrc], ldst + i * 512);
        }
    };

    if (s > 0) {
        stage(buf0, 0);
        __syncthreads();                      // drains vmcnt -> buf0 ready
        for (int k0 = 0; k0 < RES; k0 += 32) {
            u16* cur = (k0 & 32) ? buf1 : buf0;
            u16* nxt = (k0 & 32) ? buf0 : buf1;
            if (k0 + 32 < RES) stage(nxt, k0 + 32);
            MFMA_TILE(cur);
            __syncthreads();                  // nxt staged; cur reads done
        }
    }

    // input projection: K=128 over x[b, 4w+s-2, :] @ Win.
    // waves 0,1: compute A rows (splitf) + swizzled ds_write; waves 2,3: gload B.
    for (int k0 = 0; k0 < INd; k0 += 32) {
        if (tid < 128) {
            const int rrow = tid;             // 0..127
            const int t = 4 * rrow + s - 2;
            u16x8 h0 = {0,0,0,0,0,0,0,0}, h1 = h0, h2 = h0, h3 = h0;
            u16x8 l0 = h0, l1 = h0, l2 = h0, l3 = h0;
            if (t >= 0) {
                const float* xr = X + (size_t)(bofs + t) * INd + k0;
                const float4 f0 = *(const float4*)&xr[0];
                const float4 f1 = *(const float4*)&xr[4];
                const float4 f2 = *(const float4*)&xr[8];
                const float4 f3 = *(const float4*)&xr[12];
                const float4 f4 = *(const float4*)&xr[16];
                const float4 f5 = *(const float4*)&xr[20];
                const float4 f6 = *(const float4*)&xr[24];
                const float4 f7 = *(const float4*)&xr[28];
                split8(f0, f1, h0, l0); split8(f2, f3, h1, l1);
                split8(f4, f5, h2, l2); split8(f6, f7, h3, l3);
            }
            const int sw = (rrow >> 1) & 3;
            u16* dA = buf0 + rrow * 32;
            *(u16x8*)&dA[(0 ^ sw) << 3] = h0;
            *(u16x8*)&dA[(1 ^ sw) << 3] = h1;
            *(u16x8*)&dA[(2 ^ sw) << 3] = h2;
            *(u16x8*)&dA[(3 ^ sw) << 3] = h3;
            u16* dL = buf0 + 4096 + rrow * 32;
            *(u16x8*)&dL[(0 ^ sw) << 3] = l0;
            *(u16x8*)&dL[(1 ^ sw) << 3] = l1;
            *(u16x8*)&dL[(2 ^ sw) << 3] = l2;
            *(u16x8*)&dL[(3 ^ sw) << 3] = l3;
        } else {
            const u16* wpl = (wid == 2) ? WinTh : WinTl;
            u16* ldst = buf0 + wid * 4096;
#pragma unroll
            for (int i = 0; i < 8; ++i) {
                const int r = i * 16 + rl;
                gl_lds16(&wpl[(size_t)(q0 + r) * INd + k0 + csrc], ldst + i * 512);
            }
        }
        __syncthreads();
        MFMA_TILE(buf0);
        __syncthreads();
    }

    // epilogue via LDS: all global I/O is coalesced u16x8.
    for (int h = 0; h < 2; ++h) {
        __syncthreads();
        if (wm == h) {
#pragma unroll
            for (int i = 0; i < 4; ++i)
#pragma unroll
                for (int j = 0; j < 4; ++j)
#pragma unroll
                    for (int rg = 0; rg < 4; ++rg)
                        Cf[(i * 16 + quad * 4 + rg) * 128 + wn * 64 + j * 16 + l15]
                            = acc[i][j][rg];
        }
        __syncthreads();
#pragma unroll
        for (int pass = 0; pass < 4; ++pass) {
            const int r  = (tid >> 4) + pass * 16;      // 0..63
            const int c0 = (tid & 15) * 8;              // 0..120
            const int wrow = h * 64 + r;
            const float4 v0 = *(const float4*)&Cf[r * 128 + c0];
            const float4 v1 = *(const float4*)&Cf[r * 128 + c0 + 4];
            float vv[8] = {v0.x, v0.y, v0.z, v0.w, v1.x, v1.y, v1.z, v1.w};
            u16x8 ph, pl;
            if (s > 0) {
                const size_t prow = (size_t)(bofs + 4 * wrow + cin) * RES + q0 + c0;
                ph = *(const u16x8*)&Sh[prow];
                pl = *(const u16x8*)&Sl[prow];
            }
            u16x8 oh, ol;
#pragma unroll
            for (int e = 0; e < 8; ++e) {
                float prev = (s > 0) ? (bf2f(ph[e]) + bf2f(pl[e])) : 0.f;
                float v = 0.7f * prev + 0.3f * sinf(vv[e]);
                u16 hh, ll; splitf(v, hh, ll);
                oh[e] = hh; ol[e] = ll;
            }
            const size_t orow = (size_t)(bofs + 4 * wrow + cout) * RES + q0 + c0;
            *(u16x8*)&Sh[orow] = oh;
            *(u16x8*)&Sl[orow] = ol;
        }
    }
}

// Gram on bf16 planes: A[b] = (Sh+Sl)(Sh+Sl)^T + ones + reg*I, bf16x3.
// v2: same global_load_lds double-buffered staging as step_mfma.
__global__ __launch_bounds__(256)
void gram_mfma_kernel(const u16* __restrict__ Sh, const u16* __restrict__ Sl,
                      float* __restrict__ A, const float* __restrict__ lam)
{
    __shared__ u16 LB[2 * 16384];
    u16* buf0 = LB;
    u16* buf1 = LB + 16384;
    float* Cf = (float*)LB;                   // 64 x 132 f32 = 33.8 KB

    const int tid = threadIdx.x;
    const int bt  = blockIdx.y;
    int ti = 0, rem = (int)blockIdx.x;
    while (rem >= 4 - ti) { rem -= 4 - ti; ++ti; }
    const int tj = ti + rem;
    const int n0 = ti * 128, m0 = tj * 128;
    const int bofs = bt * Tt;

    const int wid = tid >> 6, lane = tid & 63;
    const int wm = wid & 1, wn = wid >> 1;
    const int l15 = lane & 15, quad = lane >> 4;

    f32x4 acc[4][4];
    const f32x4 zz = {0.f, 0.f, 0.f, 0.f};
#pragma unroll
    for (int i = 0; i < 4; ++i)
#pragma unroll
        for (int j = 0; j < 4; ++j) acc[i][j] = zz;

    const int rl    = lane >> 2;
    const int csrc  = (((lane & 3) ^ ((lane >> 3) & 3)) << 3);
    const u16* plane = (wid & 1) ? Sl : Sh;
    const int rbase  = (wid < 2) ? n0 : m0;

    auto stage = [&](u16* buf, int k0) {
        u16* ldst = buf + wid * 4096;
#pragma unroll
        for (int i = 0; i < 8; ++i) {
            const int r = i * 16 + rl;
            gl_lds16(&plane[(size_t)(bofs + rbase + r) * RES + k0 + csrc],
                     ldst + i * 512);
        }
    };

    stage(buf0, 0);
    __syncthreads();
    for (int k0 = 0; k0 < RES; k0 += 32) {
        u16* cur = (k0 & 32) ? buf1 : buf0;
        u16* nxt = (k0 & 32) ? buf0 : buf1;
        if (k0 + 32 < RES) stage(nxt, k0 + 32);
        MFMA_TILE(cur);
        __syncthreads();
    }

    const float reg = log1pf(expf(lam[0]));
    float* Ab = A + (size_t)bt * 512 * 512;
    for (int h = 0; h < 2; ++h) {
        __syncthreads();
        if (wm == h) {
#pragma unroll
            for (int i = 0; i < 4; ++i)
#pragma unroll
                for (int j = 0; j < 4; ++j)
#pragma unroll
                    for (int rg = 0; rg < 4; ++rg)
                        Cf[(i * 16 + quad * 4 + rg) * 132 + wn * 64 + j * 16 + l15]
                            = acc[i][j][rg];
        }
        __syncthreads();
        // row-major half: rows nn = n0+h*64+r, cols m0..m0+127
#pragma unroll
        for (int pass = 0; pass < 4; ++pass) {
            const int r  = (tid >> 4) + pass * 16;
            const int c0 = (tid & 15) * 8;
            const int nn = n0 + h * 64 + r;
            float o[8];
#pragma unroll
            for (int e = 0; e < 8; ++e) {
                const int mm = m0 + c0 + e;
                float v = Cf[r * 132 + c0 + e] + 1.0f;
                if (nn == mm) v += reg;
                o[e] = v;
            }
            float* dst = Ab + (size_t)nn * 512 + m0 + c0;
            *(float4*)&dst[0] = make_float4(o[0], o[1], o[2], o[3]);
            *(float4*)&dst[4] = make_float4(o[4], o[5], o[6], o[7]);
        }
        // transposed half: rows mm = m0+rt, cols n0+h*64 .. +63
#pragma unroll
        for (int pass = 0; pass < 4; ++pass) {
            const int rt  = (tid >> 3) + pass * 32;     // 0..127
            const int c0t = (tid & 7) * 8;              // 0..56
            const int mm  = m0 + rt;
            float o[8];
#pragma unroll
            for (int e = 0; e < 8; ++e) {
                const int nn = n0 + h * 64 + c0t + e;
                float v = Cf[(c0t + e) * 132 + rt] + 1.0f;
                if (nn == mm) v += reg;
                o[e] = v;
            }
            float* dst = Ab + (size_t)mm * 512 + n0 + h * 64 + c0t;
            *(float4*)&dst[0] = make_float4(o[0], o[1], o[2], o[3]);
            *(float4*)&dst[4] = make_float4(o[4], o[5], o[6], o[7]);
        }
    }
}

// Diag-block Cholesky (64x64) + inverse, one wave per batch.
__global__ __launch_bounds__(64)
void chol_diag_inv_kernel(float* __restrict__ Aall, float* __restrict__ Winv,
                          float* __restrict__ WinvT, int k)
{
    __shared__ float P[64][65];
    __shared__ float W[64][65];
    const int b = blockIdx.x, c = threadIdx.x;
    float* A = Aall + (size_t)b * 512 * 512;
    const int j0 = 64 * k;

    for (int m = 0; m < 64; m += 4) {
        const float4 v = *(const float4*)(A + (size_t)(j0 + c) * 512 + j0 + m);
        P[c][m] = v.x; P[c][m+1] = v.y; P[c][m+2] = v.z; P[c][m+3] = v.w;
    }
    __syncthreads();
    for (int j = 0; j < 64; ++j) {
        const float d = sqrtf(P[j][j]);
        if (c >= j) P[c][j] = (c == j) ? d : P[c][j] / d;
        __syncthreads();
        const float pj = (c > j) ? P[c][j] : 0.f;
        for (int m = j + 1; m <= c; ++m) P[c][m] -= pj * P[m][j];
        __syncthreads();
    }
    for (int j = 0; j < 64; ++j) {
        float sv = (j == c) ? 1.f : 0.f;
        for (int m = c; m < j; ++m) sv -= P[j][m] * W[m][c];
        W[j][c] = (j >= c) ? sv / P[j][j] : 0.f;
    }
    __syncthreads();
    for (int m = 0; m < 64; m += 4)
        *(float4*)(A + (size_t)(j0 + c) * 512 + j0 + m) =
            make_float4(P[c][m], P[c][m+1], P[c][m+2], P[c][m+3]);
    float* Wo  = Winv  + ((size_t)b * 8 + k) * 64 * 64;
    float* WoT = WinvT + ((size_t)b * 8 + k) * 64 * 64;
    for (int j = 0; j < 64; ++j) Wo[(size_t)j * 64 + c] = W[j][c];
    for (int m = 0; m < 64; m += 4)
        *(float4*)(WoT + (size_t)c * 64 + m) =
            make_float4(W[m][c], W[m+1][c], W[m+2][c], W[m+3][c]);
}

// Panel TRSM via inverse: L[i0.., k] = A[i0.., k] @ W^T
__global__ __launch_bounds__(256)
void trsm_kernel(float* __restrict__ Aall, const float* __restrict__ WinvT, int k)
{
    __shared__ float St[BK][BM + 4];
    __shared__ float Wt[BK][BN + 4];
    float* A = Aall + (size_t)blockIdx.y * 512 * 512;
    const float* WT = WinvT + ((size_t)blockIdx.y * 8 + k) * 64 * 64;
    const int i0 = (k + 1 + blockIdx.x) * 64, p0 = k * 64;
    const int tid = threadIdx.x;
    const int li = tid >> 2, lk = (tid & 3) << 2;
    const int wk = tid >> 4, wq = (tid & 15) << 2;
    const int ty = tid >> 4, tx = tid & 15;
    float acc[4][4] = {};
    for (int k0 = 0; k0 < 64; k0 += BK) {
        const float4 u = *(const float4*)(A + (size_t)(i0 + li) * 512 + p0 + k0 + lk);
        St[lk + 0][li] = u.x; St[lk + 1][li] = u.y;
        St[lk + 2][li] = u.z; St[lk + 3][li] = u.w;
        *(float4*)&Wt[wk][wq] = *(const float4*)(WT + (size_t)(k0 + wk) * 64 + wq);
        __syncthreads();
        MICRO(St, Wt);
        __syncthreads();
    }
#pragma unroll
    for (int a = 0; a < 4; ++a) {
        const int r = i0 + (ty << 2) + a;
        *(float4*)(A + (size_t)r * 512 + p0 + (tx << 2)) =
            make_float4(acc[a][0], acc[a][1], acc[a][2], acc[a][3]);
    }
}

// Trailing update: A[ti,tj] -= L[ti,k] L[tj,k]^T
__global__ __launch_bounds__(256)
void chol_trailing_kernel(float* __restrict__ Aall, int k)
{
    __shared__ float Ut[BK][BM + 4];
    __shared__ float Vt[BK][BN + 4];
    float* A = Aall + (size_t)blockIdx.y * 512 * 512;
    const int tid = threadIdx.x;
    int a = 0, rem = (int)blockIdx.x;
    while (rem >= a + 1) { rem -= a + 1; ++a; }
    const int ti = k + 1 + a, tj = k + 1 + rem;
    const int i0 = ti * 64, j0c = tj * 64, p0 = k * 64;

    const int li = tid >> 2, lk = (tid & 3) << 2;
    const int ty = tid >> 4, tx = tid & 15;
    float acc[4][4] = {};

    for (int k0 = 0; k0 < 64; k0 += BK) {
        const float4 u = *(const float4*)(A + (size_t)(i0 + li) * 512 + p0 + k0 + lk);
        const float4 v = *(const float4*)(A + (size_t)(j0c + li) * 512 + p0 + k0 + lk);
        Ut[lk + 0][li] = u.x; Ut[lk + 1][li] = u.y;
        Ut[lk + 2][li] = u.z; Ut[lk + 3][li] = u.w;
        Vt[lk + 0][li] = v.x; Vt[lk + 1][li] = v.y;
        Vt[lk + 2][li] = v.z; Vt[lk + 3][li] = v.w;
        __syncthreads();
        MICRO(Ut, Vt);
        __syncthreads();
    }
#pragma unroll
    for (int aa = 0; aa < 4; ++aa) {
        const int r = i0 + (ty << 2) + aa;
        float* crow = A + (size_t)r * 512 + j0c + (tx << 2);
        float4 cv = *(const float4*)crow;
        cv.x -= acc[aa][0]; cv.y -= acc[aa][1];
        cv.z -= acc[aa][2]; cv.w -= acc[aa][3];
        *(float4*)crow = cv;
    }
}

// Blocked fwd+bwd solve, v3: 256 blocks (32 batches x 8 col-splits of 8 cols),
// ONE wave per block. V panel (512x8) lives in LDS with broadcast-only b64
// reads (stride 10 -> conflict-free); A / Winv operands stream global->regs
// in double-buffered 16-k chunks. Accumulation order per output element
// identical to fb_solve2 -> same numerics.
__global__ __launch_bounds__(64, 1)
void fb_solve3_kernel(const float* __restrict__ Aall,
                      const float* __restrict__ Winv,
                      const float* __restrict__ WinvT,
                      const float* __restrict__ Y, float* __restrict__ Zall)
{
    __shared__ float V[512][10];   // 8 used cols + 2 pad (bank spread)
    __shared__ float U[64][10];
    const int tid = threadIdx.x;
    const int b   = (int)blockIdx.x >> 3;
    const int c0  = ((int)blockIdx.x & 7) * 8;
    const int ty  = tid >> 2;            // 0..15 -> rows 4*ty..4*ty+3
    const int tx  = tid & 3;             // 0..3  -> cols 2*tx..2*tx+1
    const float* A   = Aall + (size_t)b * 512 * 512;
    const float* Yb  = Y    + (size_t)b * 512 * OUTd + c0;
    float*       Zb  = Zall + (size_t)b * 512 * OUTd + c0;
    const float* Wb  = Winv  + (size_t)b * 8 * 64 * 64 + 4 * ty;
    const float* WbT = WinvT + (size_t)b * 8 * 64 * 64 + 4 * ty;

    for (int t = tid; t < 512 * 4; t += 64) {
        const int row = t >> 2, p = (t & 3) * 2;
        *(float2*)&V[row][p] = *(const float2*)&Yb[(size_t)row * OUTd + p];
    }
    __syncthreads();

    float acc[4][2];
    f32x4 pa[4][4], pb[4][4];

#define LDA_F(dst, kk0)                                                         \
    { _Pragma("unroll") for (int r_ = 0; r_ < 4; ++r_)                          \
      _Pragma("unroll") for (int q_ = 0; q_ < 4; ++q_)                          \
        dst[r_][q_] = *(const f32x4*)&A[(size_t)(r0 + 4 * ty + r_) * 512 + (kk0) + 4 * q_]; }

#define CMP_F(P, kbase)                                                         \
    { _Pragma("unroll") for (int q_ = 0; q_ < 16; ++q_) {                       \
        const float2 v_ = *(const float2*)&V[(kbase) + q_][2 * tx];             \
        _Pragma("unroll") for (int r_ = 0; r_ < 4; ++r_) {                      \
          acc[r_][0] += P[r_][q_ >> 2][q_ & 3] * v_.x;                          \
          acc[r_][1] += P[r_][q_ >> 2][q_ & 3] * v_.y; } } }

#define LDA_K(dst, base, row0, S)                                               \
    { _Pragma("unroll") for (int i_ = 0; i_ < 16; ++i_)                         \
        dst[i_ >> 2][i_ & 3] = *(const f32x4*)&(base)[(size_t)((row0) + i_) * (S)]; }

#define CMP_K(P, ARR, kbase)                                                    \
    { _Pragma("unroll") for (int i_ = 0; i_ < 16; ++i_) {                       \
        const float2 v_ = *(const float2*)&ARR[(kbase) + i_][2 * tx];           \
        _Pragma("unroll") for (int r_ = 0; r_ < 4; ++r_) {                      \
          acc[r_][0] += P[i_ >> 2][i_ & 3][r_] * v_.x;                          \
          acc[r_][1] += P[i_ >> 2][i_ & 3][r_] * v_.y; } } }

#define ZACC                                                                    \
    { _Pragma("unroll") for (int r_ = 0; r_ < 4; ++r_) {                        \
        acc[r_][0] = 0.f; acc[r_][1] = 0.f; } }

#define URES(R0)                                                                \
    { _Pragma("unroll") for (int r_ = 0; r_ < 4; ++r_)                          \
      _Pragma("unroll") for (int c_ = 0; c_ < 2; ++c_)                          \
        U[4 * ty + r_][2 * tx + c_] =                                           \
            V[(R0) + 4 * ty + r_][2 * tx + c_] - acc[r_][c_]; }

#define VOUT(R0)                                                                \
    { _Pragma("unroll") for (int r_ = 0; r_ < 4; ++r_)                          \
      _Pragma("unroll") for (int c_ = 0; c_ < 2; ++c_)                          \
        V[(R0) + 4 * ty + r_][2 * tx + c_] = acc[r_][c_]; }

#define DIAG(Wp)                                                                \
    { ZACC; LDA_K(pa, Wp, 0, 64); LDA_K(pb, Wp, 16, 64);                        \
      CMP_K(pa, U, 0);  LDA_K(pa, Wp, 32, 64);                                  \
      CMP_K(pb, U, 16); LDA_K(pb, Wp, 48, 64);                                  \
      CMP_K(pa, U, 32); CMP_K(pb, U, 48); }

    // ---- forward: V_k = W_k (Y_k - L[k, 0:64k] @ V) ----
    for (int k = 0; k < 8; ++k) {
        const int r0 = k * 64;
        ZACC;
        if (r0 > 0) {
            LDA_F(pa, 0);
            for (int k0 = 0; k0 < r0; k0 += 32) {
                LDA_F(pb, k0 + 16);
                CMP_F(pa, k0);
                if (k0 + 32 < r0) LDA_F(pa, k0 + 32);
                CMP_F(pb, k0 + 16);
            }
        }
        URES(r0);
        __syncthreads();
        DIAG(WbT + (size_t)k * 4096);
        VOUT(r0);
        __syncthreads();
    }

    // ---- backward: Z_k = W_k^T (V_k - L[64(k+1):, k]^T @ Z) ----
    for (int k = 7; k >= 0; --k) {
        const int r0 = k * 64;
        ZACC;
        if (r0 + 64 < 512) {
            const float* Ac = A + r0 + 4 * ty;
            LDA_K(pa, Ac, r0 + 64, 512);
            for (int m0 = r0 + 64; m0 < 512; m0 += 32) {
                LDA_K(pb, Ac, m0 + 16, 512);
                CMP_K(pa, V, m0);
                if (m0 + 32 < 512) LDA_K(pa, Ac, m0 + 32, 512);
                CMP_K(pb, V, m0 + 16);
            }
        }
        URES(r0);
        __syncthreads();
        DIAG(Wb + (size_t)k * 4096);
        VOUT(r0);
        __syncthreads();
    }

    for (int t = tid; t < 512 * 4; t += 64) {
        const int row = t >> 2, p = (t & 3) * 2;
        *(float2*)&Zb[(size_t)row * OUTd + p] = *(const float2*)&V[row][p];
    }
#undef LDA_F
#undef CMP_F
#undef LDA_K
#undef CMP_K
#undef ZACC
#undef URES
#undef VOUT
#undef DIAG
}

// w[b] = RS_b^T @ Z_b, RS reconstructed as h+l.
__global__ __launch_bounds__(256)
void out_kernel(const u16* __restrict__ Sh, const u16* __restrict__ Sl,
                const float* __restrict__ Z, float* __restrict__ Wout)
{
    __shared__ float Rt[BK][64 + 4];
    __shared__ float Zt[BK][64 + 4];
    const int tid = threadIdx.x;
    const int b   = blockIdx.y;
    const int d0  = blockIdx.x * 64;
    const int kk  = tid >> 4, cq = (tid & 15) << 2;
    const int ty  = tid >> 4, tx = tid & 15;
    float acc[4][4] = {};

    for (int k0 = 0; k0 < Tt; k0 += BK) {
        const size_t ri = (size_t)(b * Tt + k0 + kk) * RES + d0 + cq;
        const u16x4 hv = *(const u16x4*)&Sh[ri];
        const u16x4 lv = *(const u16x4*)&Sl[ri];
        Rt[kk][cq + 0] = bf2f(hv[0]) + bf2f(lv[0]);
        Rt[kk][cq + 1] = bf2f(hv[1]) + bf2f(lv[1]);
        Rt[kk][cq + 2] = bf2f(hv[2]) + bf2f(lv[2]);
        Rt[kk][cq + 3] = bf2f(hv[3]) + bf2f(lv[3]);
        *(float4*)&Zt[kk][cq] =
            *(const float4*)(Z + ((size_t)b * Tt + k0 + kk) * OUTd + cq);
        __syncthreads();
        MICRO(Rt, Zt);
        __syncthreads();
    }
#pragma unroll
    for (int a = 0; a < 4; ++a) {
        const int d = d0 + (ty << 2) + a;
        *(float4*)(Wout + ((size_t)b * RES + d) * OUTd + (tx << 2)) =
            make_float4(acc[a][0], acc[a][1], acc[a][2], acc[a][3]);
    }
}

__global__ __launch_bounds__(64)
void bias_kernel(const float* __restrict__ Z, float* __restrict__ Bout)
{
    const int b = blockIdx.x, o = threadIdx.x;
    const float* Zb = Z + (size_t)b * Tt * OUTd;
    float s = 0.f;
    for (int n = 0; n < Tt; ++n) s += Zb[(size_t)n * OUTd + o];
    Bout[(size_t)b * OUTd + o] = s;
}

extern "C" void kernel_launch(void* const* d_in, const int* in_sizes, int n_in,
                              void* d_out, int out_size, void* d_ws, size_t ws_size,
                              hipStream_t stream)
{
    const float* X    = (const float*)d_in[0];   // (32,512,128)
    const float* Y    = (const float*)d_in[1];   // (32,512,64)
    const float* Wres = (const float*)d_in[2];   // (2048,2048)
    const float* Win  = (const float*)d_in[3];   // (128,2048)
    const float* lam  = (const float*)d_in[4];   // scalar

    float* out  = (float*)d_out;
    float* Wout = out;
    float* Bout = out + (size_t)Bb * RES * OUTd;

    // ws: Sh 64 | Sl 64 | WTh 8 | WTl 8 | WinTh .5 | WinTl .5 | A 32 | Z 4 | Wi 4 | WiT 4 = 189 MB
    char* p = (char*)d_ws;
    u16* Sh    = (u16*)p;   p += (size_t)Bb * Tt * RES * 2;
    u16* Sl    = (u16*)p;   p += (size_t)Bb * Tt * RES * 2;
    u16* WTh   = (u16*)p;   p += (size_t)RES * RES * 2;
    u16* WTl   = (u16*)p;   p += (size_t)RES * RES * 2;
    u16* WinTh = (u16*)p;   p += (size_t)INd * RES * 2;
    u16* WinTl = (u16*)p;   p += (size_t)INd * RES * 2;
    float* A   = (float*)p; p += (size_t)Bb * 512 * 512 * 4;
    float* Z   = (float*)p; p += (size_t)Bb * Tt * OUTd * 4;
    float* Wi  = (float*)p; p += (size_t)Bb * 8 * 64 * 64 * 4;
    float* WiT = (float*)p;

    const dim3 blk(256);
    tconv_kernel<<<dim3(RES / 64, RES / 64), blk, 0, stream>>>(Wres, WTh, WTl, RES, RES);
    tconv_kernel<<<dim3(RES / 64, INd / 64), blk, 0, stream>>>(Win, WinTh, WinTl, INd, RES);

    // classes: s:(cin->cout) 0:(-,2) 1:(2,1) 2:(1,0) 3:(0,1) 4:(1,2) 5:(2,3)
    const dim3 sgrid(RES / 128, Bb);
    step_mfma_kernel<<<sgrid, blk, 0, stream>>>(Sh, Sl, X, WTh, WTl, WinTh, WinTl, 0, 2, 0);
    step_mfma_kernel<<<sgrid, blk, 0, stream>>>(Sh, Sl, X, WTh, WTl, WinTh, WinTl, 2, 1, 1);
    step_mfma_kernel<<<sgrid, blk, 0, stream>>>(Sh, Sl, X, WTh, WTl, WinTh, WinTl, 1, 0, 2);
    step_mfma_kernel<<<sgrid, blk, 0, stream>>>(Sh, Sl, X, WTh, WTl, WinTh, WinTl, 0, 1, 3);
    step_mfma_kernel<<<sgrid, blk, 0, stream>>>(Sh, Sl, X, WTh, WTl, WinTh, WinTl, 1, 2, 4);
    step_mfma_kernel<<<sgrid, blk, 0, stream>>>(Sh, Sl, X, WTh, WTl, WinTh, WinTl, 2, 3, 5);

    gram_mfma_kernel<<<dim3(10, Bb), blk, 0, stream>>>(Sh, Sl, A, lam);

    for (int k = 0; k < 8; ++k) {
        chol_diag_inv_kernel<<<dim3(Bb), dim3(64), 0, stream>>>(A, Wi, WiT, k);
        if (k < 7) {
            trsm_kernel<<<dim3(7 - k, Bb), blk, 0, stream>>>(A, WiT, k);
            const int m = 7 - k;
            chol_trailing_kernel<<<dim3(m * (m + 1) / 2, Bb), blk, 0, stream>>>(A, k);
        }
    }
    fb_solve3_kernel<<<dim3(Bb * 8), dim3(64), 0, stream>>>(A, Wi, WiT, Y, Z);

    out_kernel<<<dim3(RES / 64, Bb), blk, 0, stream>>>(Sh, Sl, Z, Wout);
    bias_kernel<<<dim3(Bb), dim3(OUTd), 0, stream>>>(Z, Bout);
}

// Round 3
// 2136.752 us; speedup vs baseline: 1.3232x; 1.1801x over previous
//
#include <hip/hip_runtime.h>
#include <cmath>

#define Bb   32
#define Tt   512
#define INd  128
#define RES  2048
#define OUTd 64

#define BM 64
#define BN 64
#define BK 16

typedef unsigned short u16;
typedef __attribute__((ext_vector_type(4))) unsigned short u16x4;
typedef __attribute__((ext_vector_type(8))) unsigned short u16x8;
typedef __attribute__((ext_vector_type(8))) short bf8;
typedef __attribute__((ext_vector_type(4))) float f32x4;

// fp32 = bf16 hi (RNE) + bf16 lo (trunc residual); |err| <= 2^-17 |a|
__device__ __forceinline__ void splitf(float a, u16& h, u16& l) {
    unsigned u = __float_as_uint(a);
    unsigned r = (u + 0x7fffu + ((u >> 16) & 1u)) & 0xffff0000u;
    h = (u16)(r >> 16);
    float d = a - __uint_as_float(r);
    l = (u16)(__float_as_uint(d) >> 16);
}
__device__ __forceinline__ float bf2f(u16 h) {
    return __uint_as_float((unsigned)h << 16);
}
__device__ __forceinline__ void split8(const float4& a, const float4& b,
                                       u16x8& h, u16x8& l) {
    u16 hh, ll;
    splitf(a.x, hh, ll); h[0] = hh; l[0] = ll;
    splitf(a.y, hh, ll); h[1] = hh; l[1] = ll;
    splitf(a.z, hh, ll); h[2] = hh; l[2] = ll;
    splitf(a.w, hh, ll); h[3] = hh; l[3] = ll;
    splitf(b.x, hh, ll); h[4] = hh; l[4] = ll;
    splitf(b.y, hh, ll); h[5] = hh; l[5] = ll;
    splitf(b.z, hh, ll); h[6] = hh; l[6] = ll;
    splitf(b.w, hh, ll); h[7] = hh; l[7] = ll;
}

// async global->LDS, 16B per lane. LDS dest is wave-uniform base + lane*16;
// global src is per-lane (carries the chunk swizzle).
__device__ __forceinline__ void gl_lds16(const u16* g, u16* l) {
    __builtin_amdgcn_global_load_lds(
        (const __attribute__((address_space(1))) unsigned int*)g,
        (__attribute__((address_space(3))) unsigned int*)l,
        16, 0, 0);
}

#define MICRO(SA, SB)                                                           \
  do {                                                                          \
    _Pragma("unroll")                                                           \
    for (int kk = 0; kk < BK; ++kk) {                                           \
      const float4 a4 = *(const float4*)&SA[kk][ty << 2];                       \
      const float4 b4 = *(const float4*)&SB[kk][tx << 2];                       \
      acc[0][0] += a4.x*b4.x; acc[0][1] += a4.x*b4.y;                           \
      acc[0][2] += a4.x*b4.z; acc[0][3] += a4.x*b4.w;                           \
      acc[1][0] += a4.y*b4.x; acc[1][1] += a4.y*b4.y;                           \
      acc[1][2] += a4.y*b4.z; acc[1][3] += a4.y*b4.w;                           \
      acc[2][0] += a4.z*b4.x; acc[2][1] += a4.z*b4.y;                           \
      acc[2][2] += a4.z*b4.z; acc[2][3] += a4.z*b4.w;                           \
      acc[3][0] += a4.w*b4.x; acc[3][1] += a4.w*b4.y;                           \
      acc[3][2] += a4.w*b4.z; acc[3][3] += a4.w*b4.w;                           \
    }                                                                           \
  } while (0)

// 128x128 tile, K=32 slice, bf16x3. Linear LDS rows of 32 u16 (64 B) with
// 16B-chunk XOR swizzle c' = c ^ ((row>>1)&3)  ->  max 2-way bank alias (free).
// Buffer layout (u16 offsets): Ah 0 | Al 4096 | Bh 8192 | Bl 12288.
#define MFMA_TILE(BUF)                                                           \
  do {                                                                           \
    bf8 aH[4], aL[4], bH[4], bL[4];                                              \
    const int qd = (quad ^ ((l15 >> 1) & 3)) << 3;                               \
    _Pragma("unroll")                                                            \
    for (int i = 0; i < 4; ++i) {                                                \
      const int ar = (wm*64 + i*16 + l15)*32 + qd;                               \
      const int br = (wn*64 + i*16 + l15)*32 + qd;                               \
      aH[i] = *(const bf8*)&(BUF)[ar];                                           \
      aL[i] = *(const bf8*)&(BUF)[4096 + ar];                                    \
      bH[i] = *(const bf8*)&(BUF)[8192 + br];                                    \
      bL[i] = *(const bf8*)&(BUF)[12288 + br];                                   \
    }                                                                            \
    _Pragma("unroll")                                                            \
    for (int i = 0; i < 4; ++i)                                                  \
      _Pragma("unroll")                                                          \
      for (int j = 0; j < 4; ++j) {                                              \
        acc[i][j] = __builtin_amdgcn_mfma_f32_16x16x32_bf16(aH[i], bH[j], acc[i][j], 0, 0, 0); \
        acc[i][j] = __builtin_amdgcn_mfma_f32_16x16x32_bf16(aH[i], bL[j], acc[i][j], 0, 0, 0); \
        acc[i][j] = __builtin_amdgcn_mfma_f32_16x16x32_bf16(aL[i], bH[j], acc[i][j], 0, 0, 0); \
      }                                                                          \
  } while (0)

// Transpose + split weights: in (K x N fp32) -> outH/outL (N x K bf16).
__global__ __launch_bounds__(256)
void tconv_kernel(const float* __restrict__ in, u16* __restrict__ outH,
                  u16* __restrict__ outL, int K, int N)
{
    __shared__ float T[64][65];
    const int n0 = blockIdx.x * 64, k0 = blockIdx.y * 64;
    const int t = threadIdx.x;
    const int r = t >> 2, c0 = (t & 3) * 16;
#pragma unroll
    for (int i = 0; i < 4; ++i) {
        const float4 v = *(const float4*)&in[(size_t)(k0 + r) * N + n0 + c0 + 4*i];
        T[r][c0 + 4*i + 0] = v.x; T[r][c0 + 4*i + 1] = v.y;
        T[r][c0 + 4*i + 2] = v.z; T[r][c0 + 4*i + 3] = v.w;
    }
    __syncthreads();
    const int n = t >> 2, ck = (t & 3) * 16;
    u16x8 h0, h1, l0, l1;
#pragma unroll
    for (int i = 0; i < 8; ++i) { u16 h, l; splitf(T[ck + i][n], h, l); h0[i] = h; l0[i] = l; }
#pragma unroll
    for (int i = 0; i < 8; ++i) { u16 h, l; splitf(T[ck + 8 + i][n], h, l); h1[i] = h; l1[i] = l; }
    const size_t ob = (size_t)(n0 + n) * K + k0 + ck;
    *(u16x8*)&outH[ob] = h0; *(u16x8*)&outH[ob + 8] = h1;
    *(u16x8*)&outL[ob] = l0; *(u16x8*)&outL[ob + 8] = l1;
}

// Reservoir step on bf16 hi/lo state planes (row = b*512 + 4w + class).
// v2: global_load_lds staging (width 16) into double-buffered 32-KB slice
// buffers; ONE barrier per K-slice. Epilogue via LDS (coalesced u16x8).
__global__ __launch_bounds__(256)
void step_mfma_kernel(u16* __restrict__ Sh, u16* __restrict__ Sl,
                      const float* __restrict__ X,
                      const u16* __restrict__ WTh, const u16* __restrict__ WTl,
                      const u16* __restrict__ WinTh, const u16* __restrict__ WinTl,
                      int cin, int cout, int s)
{
    __shared__ u16 LB[2 * 16384];             // 2 x 32 KB slice buffers
    u16* buf0 = LB;
    u16* buf1 = LB + 16384;
    float* Cf = (float*)LB;                   // 64x128 f32 = 32 KB (epilogue)

    const int tid = threadIdx.x;
    const int q0  = blockIdx.x * 128;         // reservoir-col tile
    const int b   = blockIdx.y;
    const int bofs = b * Tt;
    const int wid = tid >> 6, lane = tid & 63;
    const int wm = wid & 1, wn = wid >> 1;
    const int l15 = lane & 15, quad = lane >> 4;

    f32x4 acc[4][4];
    const f32x4 zz = {0.f, 0.f, 0.f, 0.f};
#pragma unroll
    for (int i = 0; i < 4; ++i)
#pragma unroll
        for (int j = 0; j < 4; ++j) acc[i][j] = zz;

    // per-wave slice staging: wid 0=Ah(Sh) 1=Al(Sl) 2=Bh(WTh) 3=Bl(WTl).
    // lane l covers row r = i*16 + (l>>2), dest chunk l&3; source chunk is
    // pre-swizzled: csrc = (l&3) ^ ((l>>3)&3)  (== (l&3) ^ ((r>>1)&3)).
    const int rl    = lane >> 2;
    const int csrc  = (((lane & 3) ^ ((lane >> 3) & 3)) << 3);
    const u16* plane = (wid == 0) ? (const u16*)Sh
                     : (wid == 1) ? (const u16*)Sl
                     : (wid == 2) ? WTh : WTl;

    auto stage = [&](u16* buf, int k0) {
        u16* ldst = buf + wid * 4096;
#pragma unroll
        for (int i = 0; i < 8; ++i) {
            const int r = i * 16 + rl;
            const size_t grow = (wid < 2) ? (size_t)(bofs + 4 * r + cin)
                                          : (size_t)(q0 + r);
            gl_lds16(&plane[grow * RES + k0 + csrc], ldst + i * 512);
        }
    };

    if (s > 0) {
        stage(buf0, 0);
        __syncthreads();                      // drains vmcnt -> buf0 ready
        for (int k0 = 0; k0 < RES; k0 += 32) {
            u16* cur = (k0 & 32) ? buf1 : buf0;
            u16* nxt = (k0 & 32) ? buf0 : buf1;
            if (k0 + 32 < RES) stage(nxt, k0 + 32);
            MFMA_TILE(cur);
            __syncthreads();                  // nxt staged; cur reads done
        }
    }

    // input projection: K=128 over x[b, 4w+s-2, :] @ Win.
    // waves 0,1: compute A rows (splitf) + swizzled ds_write; waves 2,3: gload B.
    for (int k0 = 0; k0 < INd; k0 += 32) {
        if (tid < 128) {
            const int rrow = tid;             // 0..127
            const int t = 4 * rrow + s - 2;
            u16x8 h0 = {0,0,0,0,0,0,0,0}, h1 = h0, h2 = h0, h3 = h0;
            u16x8 l0 = h0, l1 = h0, l2 = h0, l3 = h0;
            if (t >= 0) {
                const float* xr = X + (size_t)(bofs + t) * INd + k0;
                const float4 f0 = *(const float4*)&xr[0];
                const float4 f1 = *(const float4*)&xr[4];
                const float4 f2 = *(const float4*)&xr[8];
                const float4 f3 = *(const float4*)&xr[12];
                const float4 f4 = *(const float4*)&xr[16];
                const float4 f5 = *(const float4*)&xr[20];
                const float4 f6 = *(const float4*)&xr[24];
                const float4 f7 = *(const float4*)&xr[28];
                split8(f0, f1, h0, l0); split8(f2, f3, h1, l1);
                split8(f4, f5, h2, l2); split8(f6, f7, h3, l3);
            }
            const int sw = (rrow >> 1) & 3;
            u16* dA = buf0 + rrow * 32;
            *(u16x8*)&dA[(0 ^ sw) << 3] = h0;
            *(u16x8*)&dA[(1 ^ sw) << 3] = h1;
            *(u16x8*)&dA[(2 ^ sw) << 3] = h2;
            *(u16x8*)&dA[(3 ^ sw) << 3] = h3;
            u16* dL = buf0 + 4096 + rrow * 32;
            *(u16x8*)&dL[(0 ^ sw) << 3] = l0;
            *(u16x8*)&dL[(1 ^ sw) << 3] = l1;
            *(u16x8*)&dL[(2 ^ sw) << 3] = l2;
            *(u16x8*)&dL[(3 ^ sw) << 3] = l3;
        } else {
            const u16* wpl = (wid == 2) ? WinTh : WinTl;
            u16* ldst = buf0 + wid * 4096;
#pragma unroll
            for (int i = 0; i < 8; ++i) {
                const int r = i * 16 + rl;
                gl_lds16(&wpl[(size_t)(q0 + r) * INd + k0 + csrc], ldst + i * 512);
            }
        }
        __syncthreads();
        MFMA_TILE(buf0);
        __syncthreads();
    }

    // epilogue via LDS: all global I/O is coalesced u16x8.
    for (int h = 0; h < 2; ++h) {
        __syncthreads();
        if (wm == h) {
#pragma unroll
            for (int i = 0; i < 4; ++i)
#pragma unroll
                for (int j = 0; j < 4; ++j)
#pragma unroll
                    for (int rg = 0; rg < 4; ++rg)
                        Cf[(i * 16 + quad * 4 + rg) * 128 + wn * 64 + j * 16 + l15]
                            = acc[i][j][rg];
        }
        __syncthreads();
#pragma unroll
        for (int pass = 0; pass < 4; ++pass) {
            const int r  = (tid >> 4) + pass * 16;      // 0..63
            const int c0 = (tid & 15) * 8;              // 0..120
            const int wrow = h * 64 + r;
            const float4 v0 = *(const float4*)&Cf[r * 128 + c0];
            const float4 v1 = *(const float4*)&Cf[r * 128 + c0 + 4];
            float vv[8] = {v0.x, v0.y, v0.z, v0.w, v1.x, v1.y, v1.z, v1.w};
            u16x8 ph, pl;
            if (s > 0) {
                const size_t prow = (size_t)(bofs + 4 * wrow + cin) * RES + q0 + c0;
                ph = *(const u16x8*)&Sh[prow];
                pl = *(const u16x8*)&Sl[prow];
            }
            u16x8 oh, ol;
#pragma unroll
            for (int e = 0; e < 8; ++e) {
                float prev = (s > 0) ? (bf2f(ph[e]) + bf2f(pl[e])) : 0.f;
                float v = 0.7f * prev + 0.3f * sinf(vv[e]);
                u16 hh, ll; splitf(v, hh, ll);
                oh[e] = hh; ol[e] = ll;
            }
            const size_t orow = (size_t)(bofs + 4 * wrow + cout) * RES + q0 + c0;
            *(u16x8*)&Sh[orow] = oh;
            *(u16x8*)&Sl[orow] = ol;
        }
    }
}

// Gram on bf16 planes: A[b] = (Sh+Sl)(Sh+Sl)^T + ones + reg*I, bf16x3.
// v2: same global_load_lds double-buffered staging as step_mfma.
__global__ __launch_bounds__(256)
void gram_mfma_kernel(const u16* __restrict__ Sh, const u16* __restrict__ Sl,
                      float* __restrict__ A, const float* __restrict__ lam)
{
    __shared__ u16 LB[2 * 16384];
    u16* buf0 = LB;
    u16* buf1 = LB + 16384;
    float* Cf = (float*)LB;                   // 64 x 132 f32 = 33.8 KB

    const int tid = threadIdx.x;
    const int bt  = blockIdx.y;
    int ti = 0, rem = (int)blockIdx.x;
    while (rem >= 4 - ti) { rem -= 4 - ti; ++ti; }
    const int tj = ti + rem;
    const int n0 = ti * 128, m0 = tj * 128;
    const int bofs = bt * Tt;

    const int wid = tid >> 6, lane = tid & 63;
    const int wm = wid & 1, wn = wid >> 1;
    const int l15 = lane & 15, quad = lane >> 4;

    f32x4 acc[4][4];
    const f32x4 zz = {0.f, 0.f, 0.f, 0.f};
#pragma unroll
    for (int i = 0; i < 4; ++i)
#pragma unroll
        for (int j = 0; j < 4; ++j) acc[i][j] = zz;

    const int rl    = lane >> 2;
    const int csrc  = (((lane & 3) ^ ((lane >> 3) & 3)) << 3);
    const u16* plane = (wid & 1) ? Sl : Sh;
    const int rbase  = (wid < 2) ? n0 : m0;

    auto stage = [&](u16* buf, int k0) {
        u16* ldst = buf + wid * 4096;
#pragma unroll
        for (int i = 0; i < 8; ++i) {
            const int r = i * 16 + rl;
            gl_lds16(&plane[(size_t)(bofs + rbase + r) * RES + k0 + csrc],
                     ldst + i * 512);
        }
    };

    stage(buf0, 0);
    __syncthreads();
    for (int k0 = 0; k0 < RES; k0 += 32) {
        u16* cur = (k0 & 32) ? buf1 : buf0;
        u16* nxt = (k0 & 32) ? buf0 : buf1;
        if (k0 + 32 < RES) stage(nxt, k0 + 32);
        MFMA_TILE(cur);
        __syncthreads();
    }

    const float reg = log1pf(expf(lam[0]));
    float* Ab = A + (size_t)bt * 512 * 512;
    for (int h = 0; h < 2; ++h) {
        __syncthreads();
        if (wm == h) {
#pragma unroll
            for (int i = 0; i < 4; ++i)
#pragma unroll
                for (int j = 0; j < 4; ++j)
#pragma unroll
                    for (int rg = 0; rg < 4; ++rg)
                        Cf[(i * 16 + quad * 4 + rg) * 132 + wn * 64 + j * 16 + l15]
                            = acc[i][j][rg];
        }
        __syncthreads();
        // row-major half: rows nn = n0+h*64+r, cols m0..m0+127
#pragma unroll
        for (int pass = 0; pass < 4; ++pass) {
            const int r  = (tid >> 4) + pass * 16;
            const int c0 = (tid & 15) * 8;
            const int nn = n0 + h * 64 + r;
            float o[8];
#pragma unroll
            for (int e = 0; e < 8; ++e) {
                const int mm = m0 + c0 + e;
                float v = Cf[r * 132 + c0 + e] + 1.0f;
                if (nn == mm) v += reg;
                o[e] = v;
            }
            float* dst = Ab + (size_t)nn * 512 + m0 + c0;
            *(float4*)&dst[0] = make_float4(o[0], o[1], o[2], o[3]);
            *(float4*)&dst[4] = make_float4(o[4], o[5], o[6], o[7]);
        }
        // transposed half: rows mm = m0+rt, cols n0+h*64 .. +63
#pragma unroll
        for (int pass = 0; pass < 4; ++pass) {
            const int rt  = (tid >> 3) + pass * 32;     // 0..127
            const int c0t = (tid & 7) * 8;              // 0..56
            const int mm  = m0 + rt;
            float o[8];
#pragma unroll
            for (int e = 0; e < 8; ++e) {
                const int nn = n0 + h * 64 + c0t + e;
                float v = Cf[(c0t + e) * 132 + rt] + 1.0f;
                if (nn == mm) v += reg;
                o[e] = v;
            }
            float* dst = Ab + (size_t)mm * 512 + n0 + h * 64 + c0t;
            *(float4*)&dst[0] = make_float4(o[0], o[1], o[2], o[3]);
            *(float4*)&dst[4] = make_float4(o[4], o[5], o[6], o[7]);
        }
    }
}

// Diag-block Cholesky (64x64) + inverse, v2: 256 threads / 4 waves per batch.
// Same math & summation order as the 1-wave version, but rank-1 / column-sweep
// parallelized across all 256 threads (thread = (row r, 16-col strip q)):
// pipelined conflict-free LDS reads instead of serial latency-exposed chains.
__global__ __launch_bounds__(256)
void chol_diag_inv_kernel(float* __restrict__ Aall, float* __restrict__ Winv,
                          float* __restrict__ WinvT, int k)
{
    __shared__ float P[64][65];
    __shared__ float W[64][65];
    const int b = blockIdx.x, tid = threadIdx.x;
    float* A = Aall + (size_t)b * 512 * 512;
    const int j0 = 64 * k;
    const int r = tid & 63;          // row (factor) / RHS column (inverse)
    const int q = tid >> 6;          // 16-wide column strip

    // load 64x64 (each thread 16 floats)
    {
        const int lr = tid >> 2, lc = (tid & 3) * 16;
#pragma unroll
        for (int i = 0; i < 4; ++i) {
            const float4 v = *(const float4*)(A + (size_t)(j0 + lr) * 512 + j0 + lc + 4*i);
            P[lr][lc + 4*i + 0] = v.x; P[lr][lc + 4*i + 1] = v.y;
            P[lr][lc + 4*i + 2] = v.z; P[lr][lc + 4*i + 3] = v.w;
        }
    }
    __syncthreads();

    // ---- factor: P -> L (lower), columns j ascending ----
    for (int j = 0; j < 64; ++j) {
        if (tid < 64) {
            const float d = sqrtf(P[j][j]);
            if (tid == j)      P[j][j]   = d;
            else if (tid > j)  P[tid][j] = P[tid][j] / d;
        }
        __syncthreads();
        // rank-1 update on strip q: P[r][m] -= P[r][j]*P[m][j], j < m <= r
        const float prj = P[r][j];
        float pm[16];
#pragma unroll
        for (int i = 0; i < 16; ++i) pm[i] = P[q * 16 + i][j];
#pragma unroll
        for (int i = 0; i < 16; ++i) {
            const int m = q * 16 + i;
            if (m > j && m <= r) P[r][m] -= prj * pm[i];
        }
        __syncthreads();
    }

    // ---- invert: W = L^{-1}, column-sweep forward substitution ----
    for (int t = tid; t < 4096; t += 256)
        W[t >> 6][t & 63] = ((t >> 6) == (t & 63)) ? 1.f : 0.f;
    __syncthreads();
    for (int j = 0; j < 64; ++j) {
        if (tid < 64) W[j][tid] = W[j][tid] / P[j][j];
        __syncthreads();
        // W[m][r] -= P[m][j] * W[j][r]  for m > j (strip q)
        const float wjc = W[j][r];
        float pm[16];
#pragma unroll
        for (int i = 0; i < 16; ++i) pm[i] = P[q * 16 + i][j];
#pragma unroll
        for (int i = 0; i < 16; ++i) {
            const int m = q * 16 + i;
            if (m > j) W[m][r] -= pm[i] * wjc;
        }
        __syncthreads();
    }

    // write back L (full rows; upper triangle untouched = original A values)
    {
        const int lr = tid >> 2, lc = (tid & 3) * 16;
#pragma unroll
        for (int i = 0; i < 4; ++i)
            *(float4*)(A + (size_t)(j0 + lr) * 512 + j0 + lc + 4*i) =
                make_float4(P[lr][lc + 4*i + 0], P[lr][lc + 4*i + 1],
                            P[lr][lc + 4*i + 2], P[lr][lc + 4*i + 3]);
    }
    float* Wo  = Winv  + ((size_t)b * 8 + k) * 64 * 64;
    float* WoT = WinvT + ((size_t)b * 8 + k) * 64 * 64;
    for (int t = tid; t < 4096; t += 256) {
        Wo[t]  = W[t >> 6][t & 63];
        WoT[t] = W[t & 63][t >> 6];
    }
}

// Panel TRSM via inverse: L[i0.., k] = A[i0.., k] @ W^T
__global__ __launch_bounds__(256)
void trsm_kernel(float* __restrict__ Aall, const float* __restrict__ WinvT, int k)
{
    __shared__ float St[BK][BM + 4];
    __shared__ float Wt[BK][BN + 4];
    float* A = Aall + (size_t)blockIdx.y * 512 * 512;
    const float* WT = WinvT + ((size_t)blockIdx.y * 8 + k) * 64 * 64;
    const int i0 = (k + 1 + blockIdx.x) * 64, p0 = k * 64;
    const int tid = threadIdx.x;
    const int li = tid >> 2, lk = (tid & 3) << 2;
    const int wk = tid >> 4, wq = (tid & 15) << 2;
    const int ty = tid >> 4, tx = tid & 15;
    float acc[4][4] = {};
    for (int k0 = 0; k0 < 64; k0 += BK) {
        const float4 u = *(const float4*)(A + (size_t)(i0 + li) * 512 + p0 + k0 + lk);
        St[lk + 0][li] = u.x; St[lk + 1][li] = u.y;
        St[lk + 2][li] = u.z; St[lk + 3][li] = u.w;
        *(float4*)&Wt[wk][wq] = *(const float4*)(WT + (size_t)(k0 + wk) * 64 + wq);
        __syncthreads();
        MICRO(St, Wt);
        __syncthreads();
    }
#pragma unroll
    for (int a = 0; a < 4; ++a) {
        const int r = i0 + (ty << 2) + a;
        *(float4*)(A + (size_t)r * 512 + p0 + (tx << 2)) =
            make_float4(acc[a][0], acc[a][1], acc[a][2], acc[a][3]);
    }
}

// Trailing update: A[ti,tj] -= L[ti,k] L[tj,k]^T
__global__ __launch_bounds__(256)
void chol_trailing_kernel(float* __restrict__ Aall, int k)
{
    __shared__ float Ut[BK][BM + 4];
    __shared__ float Vt[BK][BN + 4];
    float* A = Aall + (size_t)blockIdx.y * 512 * 512;
    const int tid = threadIdx.x;
    int a = 0, rem = (int)blockIdx.x;
    while (rem >= a + 1) { rem -= a + 1; ++a; }
    const int ti = k + 1 + a, tj = k + 1 + rem;
    const int i0 = ti * 64, j0c = tj * 64, p0 = k * 64;

    const int li = tid >> 2, lk = (tid & 3) << 2;
    const int ty = tid >> 4, tx = tid & 15;
    float acc[4][4] = {};

    for (int k0 = 0; k0 < 64; k0 += BK) {
        const float4 u = *(const float4*)(A + (size_t)(i0 + li) * 512 + p0 + k0 + lk);
        const float4 v = *(const float4*)(A + (size_t)(j0c + li) * 512 + p0 + k0 + lk);
        Ut[lk + 0][li] = u.x; Ut[lk + 1][li] = u.y;
        Ut[lk + 2][li] = u.z; Ut[lk + 3][li] = u.w;
        Vt[lk + 0][li] = v.x; Vt[lk + 1][li] = v.y;
        Vt[lk + 2][li] = v.z; Vt[lk + 3][li] = v.w;
        __syncthreads();
        MICRO(Ut, Vt);
        __syncthreads();
    }
#pragma unroll
    for (int aa = 0; aa < 4; ++aa) {
        const int r = i0 + (ty << 2) + aa;
        float* crow = A + (size_t)r * 512 + j0c + (tx << 2);
        float4 cv = *(const float4*)crow;
        cv.x -= acc[aa][0]; cv.y -= acc[aa][1];
        cv.z -= acc[aa][2]; cv.w -= acc[aa][3];
        *(float4*)crow = cv;
    }
}

// Blocked fwd+bwd solve, v3: 256 blocks (32 batches x 8 col-splits of 8 cols),
// ONE wave per block. V panel (512x8) lives in LDS with broadcast-only b64
// reads (stride 10 -> conflict-free); A / Winv operands stream global->regs
// in double-buffered 16-k chunks. Accumulation order per output element
// identical to fb_solve2 -> same numerics.
__global__ __launch_bounds__(64, 1)
void fb_solve3_kernel(const float* __restrict__ Aall,
                      const float* __restrict__ Winv,
                      const float* __restrict__ WinvT,
                      const float* __restrict__ Y, float* __restrict__ Zall)
{
    __shared__ float V[512][10];   // 8 used cols + 2 pad (bank spread)
    __shared__ float U[64][10];
    const int tid = threadIdx.x;
    const int b   = (int)blockIdx.x >> 3;
    const int c0  = ((int)blockIdx.x & 7) * 8;
    const int ty  = tid >> 2;            // 0..15 -> rows 4*ty..4*ty+3
    const int tx  = tid & 3;             // 0..3  -> cols 2*tx..2*tx+1
    const float* A   = Aall + (size_t)b * 512 * 512;
    const float* Yb  = Y    + (size_t)b * 512 * OUTd + c0;
    float*       Zb  = Zall + (size_t)b * 512 * OUTd + c0;
    const float* Wb  = Winv  + (size_t)b * 8 * 64 * 64 + 4 * ty;
    const float* WbT = WinvT + (size_t)b * 8 * 64 * 64 + 4 * ty;

    for (int t = tid; t < 512 * 4; t += 64) {
        const int row = t >> 2, p = (t & 3) * 2;
        *(float2*)&V[row][p] = *(const float2*)&Yb[(size_t)row * OUTd + p];
    }
    __syncthreads();

    float acc[4][2];
    f32x4 pa[4][4], pb[4][4];

#define LDA_F(dst, kk0)                                                         \
    { _Pragma("unroll") for (int r_ = 0; r_ < 4; ++r_)                          \
      _Pragma("unroll") for (int q_ = 0; q_ < 4; ++q_)                          \
        dst[r_][q_] = *(const f32x4*)&A[(size_t)(r0 + 4 * ty + r_) * 512 + (kk0) + 4 * q_]; }

#define CMP_F(P, kbase)                                                         \
    { _Pragma("unroll") for (int q_ = 0; q_ < 16; ++q_) {                       \
        const float2 v_ = *(const float2*)&V[(kbase) + q_][2 * tx];             \
        _Pragma("unroll") for (int r_ = 0; r_ < 4; ++r_) {                      \
          acc[r_][0] += P[r_][q_ >> 2][q_ & 3] * v_.x;                          \
          acc[r_][1] += P[r_][q_ >> 2][q_ & 3] * v_.y; } } }

#define LDA_K(dst, base, row0, S)                                               \
    { _Pragma("unroll") for (int i_ = 0; i_ < 16; ++i_)                         \
        dst[i_ >> 2][i_ & 3] = *(const f32x4*)&(base)[(size_t)((row0) + i_) * (S)]; }

#define CMP_K(P, ARR, kbase)                                                    \
    { _Pragma("unroll") for (int i_ = 0; i_ < 16; ++i_) {                       \
        const float2 v_ = *(const float2*)&ARR[(kbase) + i_][2 * tx];           \
        _Pragma("unroll") for (int r_ = 0; r_ < 4; ++r_) {                      \
          acc[r_][0] += P[i_ >> 2][i_ & 3][r_] * v_.x;                          \
          acc[r_][1] += P[i_ >> 2][i_ & 3][r_] * v_.y; } } }

#define ZACC                                                                    \
    { _Pragma("unroll") for (int r_ = 0; r_ < 4; ++r_) {                        \
        acc[r_][0] = 0.f; acc[r_][1] = 0.f; } }

#define URES(R0)                                                                \
    { _Pragma("unroll") for (int r_ = 0; r_ < 4; ++r_)                          \
      _Pragma("unroll") for (int c_ = 0; c_ < 2; ++c_)                          \
        U[4 * ty + r_][2 * tx + c_] =                                           \
            V[(R0) + 4 * ty + r_][2 * tx + c_] - acc[r_][c_]; }

#define VOUT(R0)                                                                \
    { _Pragma("unroll") for (int r_ = 0; r_ < 4; ++r_)                          \
      _Pragma("unroll") for (int c_ = 0; c_ < 2; ++c_)                          \
        V[(R0) + 4 * ty + r_][2 * tx + c_] = acc[r_][c_]; }

#define DIAG(Wp)                                                                \
    { ZACC; LDA_K(pa, Wp, 0, 64); LDA_K(pb, Wp, 16, 64);                        \
      CMP_K(pa, U, 0);  LDA_K(pa, Wp, 32, 64);                                  \
      CMP_K(pb, U, 16); LDA_K(pb, Wp, 48, 64);                                  \
      CMP_K(pa, U, 32); CMP_K(pb, U, 48); }

    // ---- forward: V_k = W_k (Y_k - L[k, 0:64k] @ V) ----
    for (int k = 0; k < 8; ++k) {
        const int r0 = k * 64;
        ZACC;
        if (r0 > 0) {
            LDA_F(pa, 0);
            for (int k0 = 0; k0 < r0; k0 += 32) {
                LDA_F(pb, k0 + 16);
                CMP_F(pa, k0);
                if (k0 + 32 < r0) LDA_F(pa, k0 + 32);
                CMP_F(pb, k0 + 16);
            }
        }
        URES(r0);
        __syncthreads();
        DIAG(WbT + (size_t)k * 4096);
        VOUT(r0);
        __syncthreads();
    }

    // ---- backward: Z_k = W_k^T (V_k - L[64(k+1):, k]^T @ Z) ----
    for (int k = 7; k >= 0; --k) {
        const int r0 = k * 64;
        ZACC;
        if (r0 + 64 < 512) {
            const float* Ac = A + r0 + 4 * ty;
            LDA_K(pa, Ac, r0 + 64, 512);
            for (int m0 = r0 + 64; m0 < 512; m0 += 32) {
                LDA_K(pb, Ac, m0 + 16, 512);
                CMP_K(pa, V, m0);
                if (m0 + 32 < 512) LDA_K(pa, Ac, m0 + 32, 512);
                CMP_K(pb, V, m0 + 16);
            }
        }
        URES(r0);
        __syncthreads();
        DIAG(Wb + (size_t)k * 4096);
        VOUT(r0);
        __syncthreads();
    }

    for (int t = tid; t < 512 * 4; t += 64) {
        const int row = t >> 2, p = (t & 3) * 2;
        *(float2*)&Zb[(size_t)row * OUTd + p] = *(const float2*)&V[row][p];
    }
#undef LDA_F
#undef CMP_F
#undef LDA_K
#undef CMP_K
#undef ZACC
#undef URES
#undef VOUT
#undef DIAG
}

// w[b] = RS_b^T @ Z_b, RS reconstructed as h+l.
__global__ __launch_bounds__(256)
void out_kernel(const u16* __restrict__ Sh, const u16* __restrict__ Sl,
                const float* __restrict__ Z, float* __restrict__ Wout)
{
    __shared__ float Rt[BK][64 + 4];
    __shared__ float Zt[BK][64 + 4];
    const int tid = threadIdx.x;
    const int b   = blockIdx.y;
    const int d0  = blockIdx.x * 64;
    const int kk  = tid >> 4, cq = (tid & 15) << 2;
    const int ty  = tid >> 4, tx = tid & 15;
    float acc[4][4] = {};

    for (int k0 = 0; k0 < Tt; k0 += BK) {
        const size_t ri = (size_t)(b * Tt + k0 + kk) * RES + d0 + cq;
        const u16x4 hv = *(const u16x4*)&Sh[ri];
        const u16x4 lv = *(const u16x4*)&Sl[ri];
        Rt[kk][cq + 0] = bf2f(hv[0]) + bf2f(lv[0]);
        Rt[kk][cq + 1] = bf2f(hv[1]) + bf2f(lv[1]);
        Rt[kk][cq + 2] = bf2f(hv[2]) + bf2f(lv[2]);
        Rt[kk][cq + 3] = bf2f(hv[3]) + bf2f(lv[3]);
        *(float4*)&Zt[kk][cq] =
            *(const float4*)(Z + ((size_t)b * Tt + k0 + kk) * OUTd + cq);
        __syncthreads();
        MICRO(Rt, Zt);
        __syncthreads();
    }
#pragma unroll
    for (int a = 0; a < 4; ++a) {
        const int d = d0 + (ty << 2) + a;
        *(float4*)(Wout + ((size_t)b * RES + d) * OUTd + (tx << 2)) =
            make_float4(acc[a][0], acc[a][1], acc[a][2], acc[a][3]);
    }
}

__global__ __launch_bounds__(64)
void bias_kernel(const float* __restrict__ Z, float* __restrict__ Bout)
{
    const int b = blockIdx.x, o = threadIdx.x;
    const float* Zb = Z + (size_t)b * Tt * OUTd;
    float s = 0.f;
    for (int n = 0; n < Tt; ++n) s += Zb[(size_t)n * OUTd + o];
    Bout[(size_t)b * OUTd + o] = s;
}

extern "C" void kernel_launch(void* const* d_in, const int* in_sizes, int n_in,
                              void* d_out, int out_size, void* d_ws, size_t ws_size,
                              hipStream_t stream)
{
    const float* X    = (const float*)d_in[0];   // (32,512,128)
    const float* Y    = (const float*)d_in[1];   // (32,512,64)
    const float* Wres = (const float*)d_in[2];   // (2048,2048)
    const float* Win  = (const float*)d_in[3];   // (128,2048)
    const float* lam  = (const float*)d_in[4];   // scalar

    float* out  = (float*)d_out;
    float* Wout = out;
    float* Bout = out + (size_t)Bb * RES * OUTd;

    // ws: Sh 64 | Sl 64 | WTh 8 | WTl 8 | WinTh .5 | WinTl .5 | A 32 | Z 4 | Wi 4 | WiT 4 = 189 MB
    char* p = (char*)d_ws;
    u16* Sh    = (u16*)p;   p += (size_t)Bb * Tt * RES * 2;
    u16* Sl    = (u16*)p;   p += (size_t)Bb * Tt * RES * 2;
    u16* WTh   = (u16*)p;   p += (size_t)RES * RES * 2;
    u16* WTl   = (u16*)p;   p += (size_t)RES * RES * 2;
    u16* WinTh = (u16*)p;   p += (size_t)INd * RES * 2;
    u16* WinTl = (u16*)p;   p += (size_t)INd * RES * 2;
    float* A   = (float*)p; p += (size_t)Bb * 512 * 512 * 4;
    float* Z   = (float*)p; p += (size_t)Bb * Tt * OUTd * 4;
    float* Wi  = (float*)p; p += (size_t)Bb * 8 * 64 * 64 * 4;
    float* WiT = (float*)p;

    const dim3 blk(256);
    tconv_kernel<<<dim3(RES / 64, RES / 64), blk, 0, stream>>>(Wres, WTh, WTl, RES, RES);
    tconv_kernel<<<dim3(RES / 64, INd / 64), blk, 0, stream>>>(Win, WinTh, WinTl, INd, RES);

    // classes: s:(cin->cout) 0:(-,2) 1:(2,1) 2:(1,0) 3:(0,1) 4:(1,2) 5:(2,3)
    const dim3 sgrid(RES / 128, Bb);
    step_mfma_kernel<<<sgrid, blk, 0, stream>>>(Sh, Sl, X, WTh, WTl, WinTh, WinTl, 0, 2, 0);
    step_mfma_kernel<<<sgrid, blk, 0, stream>>>(Sh, Sl, X, WTh, WTl, WinTh, WinTl, 2, 1, 1);
    step_mfma_kernel<<<sgrid, blk, 0, stream>>>(Sh, Sl, X, WTh, WTl, WinTh, WinTl, 1, 0, 2);
    step_mfma_kernel<<<sgrid, blk, 0, stream>>>(Sh, Sl, X, WTh, WTl, WinTh, WinTl, 0, 1, 3);
    step_mfma_kernel<<<sgrid, blk, 0, stream>>>(Sh, Sl, X, WTh, WTl, WinTh, WinTl, 1, 2, 4);
    step_mfma_kernel<<<sgrid, blk, 0, stream>>>(Sh, Sl, X, WTh, WTl, WinTh, WinTl, 2, 3, 5);

    gram_mfma_kernel<<<dim3(10, Bb), blk, 0, stream>>>(Sh, Sl, A, lam);

    for (int k = 0; k < 8; ++k) {
        chol_diag_inv_kernel<<<dim3(Bb), dim3(256), 0, stream>>>(A, Wi, WiT, k);
        if (k < 7) {
            trsm_kernel<<<dim3(7 - k, Bb), blk, 0, stream>>>(A, WiT, k);
            const int m = 7 - k;
            chol_trailing_kernel<<<dim3(m * (m + 1) / 2, Bb), blk, 0, stream>>>(A, k);
        }
    }
    fb_solve3_kernel<<<dim3(Bb * 8), dim3(64), 0, stream>>>(A, Wi, WiT, Y, Z);

    out_kernel<<<dim3(RES / 64, Bb), blk, 0, stream>>>(Sh, Sl, Z, Wout);
    bias_kernel<<<dim3(Bb), dim3(OUTd), 0, stream>>>(Z, Bout);
}

// Round 4
// 2132.566 us; speedup vs baseline: 1.3258x; 1.0020x over previous
//
#include <hip/hip_runtime.h>
#include <cmath>

#define Bb   32
#define Tt   512
#define INd  128
#define RES  2048
#define OUTd 64

#define BM 64
#define BN 64
#define BK 16

typedef unsigned short u16;
typedef __attribute__((ext_vector_type(4))) unsigned short u16x4;
typedef __attribute__((ext_vector_type(8))) unsigned short u16x8;
typedef __attribute__((ext_vector_type(8))) short bf8;
typedef __attribute__((ext_vector_type(4))) float f32x4;

// fp32 = bf16 hi (RNE) + bf16 lo (trunc residual); |err| <= 2^-17 |a|
__device__ __forceinline__ void splitf(float a, u16& h, u16& l) {
    unsigned u = __float_as_uint(a);
    unsigned r = (u + 0x7fffu + ((u >> 16) & 1u)) & 0xffff0000u;
    h = (u16)(r >> 16);
    float d = a - __uint_as_float(r);
    l = (u16)(__float_as_uint(d) >> 16);
}
__device__ __forceinline__ float bf2f(u16 h) {
    return __uint_as_float((unsigned)h << 16);
}
__device__ __forceinline__ void split8(const float4& a, const float4& b,
                                       u16x8& h, u16x8& l) {
    u16 hh, ll;
    splitf(a.x, hh, ll); h[0] = hh; l[0] = ll;
    splitf(a.y, hh, ll); h[1] = hh; l[1] = ll;
    splitf(a.z, hh, ll); h[2] = hh; l[2] = ll;
    splitf(a.w, hh, ll); h[3] = hh; l[3] = ll;
    splitf(b.x, hh, ll); h[4] = hh; l[4] = ll;
    splitf(b.y, hh, ll); h[5] = hh; l[5] = ll;
    splitf(b.z, hh, ll); h[6] = hh; l[6] = ll;
    splitf(b.w, hh, ll); h[7] = hh; l[7] = ll;
}

// async global->LDS, 16B per lane. LDS dest is wave-uniform base + lane*16;
// global src is per-lane (carries the chunk swizzle).
__device__ __forceinline__ void gl_lds16(const u16* g, u16* l) {
    __builtin_amdgcn_global_load_lds(
        (const __attribute__((address_space(1))) unsigned int*)g,
        (__attribute__((address_space(3))) unsigned int*)l,
        16, 0, 0);
}

#define MICRO(SA, SB)                                                           \
  do {                                                                          \
    _Pragma("unroll")                                                           \
    for (int kk = 0; kk < BK; ++kk) {                                           \
      const float4 a4 = *(const float4*)&SA[kk][ty << 2];                       \
      const float4 b4 = *(const float4*)&SB[kk][tx << 2];                       \
      acc[0][0] += a4.x*b4.x; acc[0][1] += a4.x*b4.y;                           \
      acc[0][2] += a4.x*b4.z; acc[0][3] += a4.x*b4.w;                           \
      acc[1][0] += a4.y*b4.x; acc[1][1] += a4.y*b4.y;                           \
      acc[1][2] += a4.y*b4.z; acc[1][3] += a4.y*b4.w;                           \
      acc[2][0] += a4.z*b4.x; acc[2][1] += a4.z*b4.y;                           \
      acc[2][2] += a4.z*b4.z; acc[2][3] += a4.z*b4.w;                           \
      acc[3][0] += a4.w*b4.x; acc[3][1] += a4.w*b4.y;                           \
      acc[3][2] += a4.w*b4.z; acc[3][3] += a4.w*b4.w;                           \
    }                                                                           \
  } while (0)

// 128x128 tile, K=32 slice, bf16x3. Linear LDS rows of 32 u16 (64 B) with
// 16B-chunk XOR swizzle c' = c ^ ((row>>1)&3)  ->  max 2-way bank alias (free).
// Buffer layout (u16 offsets): Ah 0 | Al 4096 | Bh 8192 | Bl 12288.
#define MFMA_TILE(BUF)                                                           \
  do {                                                                           \
    bf8 aH[4], aL[4], bH[4], bL[4];                                              \
    const int qd = (quad ^ ((l15 >> 1) & 3)) << 3;                               \
    _Pragma("unroll")                                                            \
    for (int i = 0; i < 4; ++i) {                                                \
      const int ar = (wm*64 + i*16 + l15)*32 + qd;                               \
      const int br = (wn*64 + i*16 + l15)*32 + qd;                               \
      aH[i] = *(const bf8*)&(BUF)[ar];                                           \
      aL[i] = *(const bf8*)&(BUF)[4096 + ar];                                    \
      bH[i] = *(const bf8*)&(BUF)[8192 + br];                                    \
      bL[i] = *(const bf8*)&(BUF)[12288 + br];                                   \
    }                                                                            \
    _Pragma("unroll")                                                            \
    for (int i = 0; i < 4; ++i)                                                  \
      _Pragma("unroll")                                                          \
      for (int j = 0; j < 4; ++j) {                                              \
        acc[i][j] = __builtin_amdgcn_mfma_f32_16x16x32_bf16(aH[i], bH[j], acc[i][j], 0, 0, 0); \
        acc[i][j] = __builtin_amdgcn_mfma_f32_16x16x32_bf16(aH[i], bL[j], acc[i][j], 0, 0, 0); \
        acc[i][j] = __builtin_amdgcn_mfma_f32_16x16x32_bf16(aL[i], bH[j], acc[i][j], 0, 0, 0); \
      }                                                                          \
  } while (0)

// Transpose + split weights: in (K x N fp32) -> outH/outL (N x K bf16).
__global__ __launch_bounds__(256)
void tconv_kernel(const float* __restrict__ in, u16* __restrict__ outH,
                  u16* __restrict__ outL, int K, int N)
{
    __shared__ float T[64][65];
    const int n0 = blockIdx.x * 64, k0 = blockIdx.y * 64;
    const int t = threadIdx.x;
    const int r = t >> 2, c0 = (t & 3) * 16;
#pragma unroll
    for (int i = 0; i < 4; ++i) {
        const float4 v = *(const float4*)&in[(size_t)(k0 + r) * N + n0 + c0 + 4*i];
        T[r][c0 + 4*i + 0] = v.x; T[r][c0 + 4*i + 1] = v.y;
        T[r][c0 + 4*i + 2] = v.z; T[r][c0 + 4*i + 3] = v.w;
    }
    __syncthreads();
    const int n = t >> 2, ck = (t & 3) * 16;
    u16x8 h0, h1, l0, l1;
#pragma unroll
    for (int i = 0; i < 8; ++i) { u16 h, l; splitf(T[ck + i][n], h, l); h0[i] = h; l0[i] = l; }
#pragma unroll
    for (int i = 0; i < 8; ++i) { u16 h, l; splitf(T[ck + 8 + i][n], h, l); h1[i] = h; l1[i] = l; }
    const size_t ob = (size_t)(n0 + n) * K + k0 + ck;
    *(u16x8*)&outH[ob] = h0; *(u16x8*)&outH[ob + 8] = h1;
    *(u16x8*)&outL[ob] = l0; *(u16x8*)&outL[ob + 8] = l1;
}

// Reservoir step on bf16 hi/lo state planes (row = b*512 + 4w + class).
// v2: global_load_lds staging (width 16) into double-buffered 32-KB slice
// buffers; ONE barrier per K-slice. Epilogue via LDS (coalesced u16x8).
__global__ __launch_bounds__(256)
void step_mfma_kernel(u16* __restrict__ Sh, u16* __restrict__ Sl,
                      const float* __restrict__ X,
                      const u16* __restrict__ WTh, const u16* __restrict__ WTl,
                      const u16* __restrict__ WinTh, const u16* __restrict__ WinTl,
                      int cin, int cout, int s)
{
    __shared__ u16 LB[2 * 16384];             // 2 x 32 KB slice buffers
    u16* buf0 = LB;
    u16* buf1 = LB + 16384;
    float* Cf = (float*)LB;                   // 64x128 f32 = 32 KB (epilogue)

    const int tid = threadIdx.x;
    const int q0  = blockIdx.x * 128;         // reservoir-col tile
    const int b   = blockIdx.y;
    const int bofs = b * Tt;
    const int wid = tid >> 6, lane = tid & 63;
    const int wm = wid & 1, wn = wid >> 1;
    const int l15 = lane & 15, quad = lane >> 4;

    f32x4 acc[4][4];
    const f32x4 zz = {0.f, 0.f, 0.f, 0.f};
#pragma unroll
    for (int i = 0; i < 4; ++i)
#pragma unroll
        for (int j = 0; j < 4; ++j) acc[i][j] = zz;

    // per-wave slice staging: wid 0=Ah(Sh) 1=Al(Sl) 2=Bh(WTh) 3=Bl(WTl).
    // lane l covers row r = i*16 + (l>>2), dest chunk l&3; source chunk is
    // pre-swizzled: csrc = (l&3) ^ ((l>>3)&3)  (== (l&3) ^ ((r>>1)&3)).
    const int rl    = lane >> 2;
    const int csrc  = (((lane & 3) ^ ((lane >> 3) & 3)) << 3);
    const u16* plane = (wid == 0) ? (const u16*)Sh
                     : (wid == 1) ? (const u16*)Sl
                     : (wid == 2) ? WTh : WTl;

    auto stage = [&](u16* buf, int k0) {
        u16* ldst = buf + wid * 4096;
#pragma unroll
        for (int i = 0; i < 8; ++i) {
            const int r = i * 16 + rl;
            const size_t grow = (wid < 2) ? (size_t)(bofs + 4 * r + cin)
                                          : (size_t)(q0 + r);
            gl_lds16(&plane[grow * RES + k0 + csrc], ldst + i * 512);
        }
    };

    if (s > 0) {
        stage(buf0, 0);
        __syncthreads();                      // drains vmcnt -> buf0 ready
        for (int k0 = 0; k0 < RES; k0 += 32) {
            u16* cur = (k0 & 32) ? buf1 : buf0;
            u16* nxt = (k0 & 32) ? buf0 : buf1;
            if (k0 + 32 < RES) stage(nxt, k0 + 32);
            MFMA_TILE(cur);
            __syncthreads();                  // nxt staged; cur reads done
        }
    }

    // input projection: K=128 over x[b, 4w+s-2, :] @ Win.
    // waves 0,1: compute A rows (splitf) + swizzled ds_write; waves 2,3: gload B.
    for (int k0 = 0; k0 < INd; k0 += 32) {
        if (tid < 128) {
            const int rrow = tid;             // 0..127
            const int t = 4 * rrow + s - 2;
            u16x8 h0 = {0,0,0,0,0,0,0,0}, h1 = h0, h2 = h0, h3 = h0;
            u16x8 l0 = h0, l1 = h0, l2 = h0, l3 = h0;
            if (t >= 0) {
                const float* xr = X + (size_t)(bofs + t) * INd + k0;
                const float4 f0 = *(const float4*)&xr[0];
                const float4 f1 = *(const float4*)&xr[4];
                const float4 f2 = *(const float4*)&xr[8];
                const float4 f3 = *(const float4*)&xr[12];
                const float4 f4 = *(const float4*)&xr[16];
                const float4 f5 = *(const float4*)&xr[20];
                const float4 f6 = *(const float4*)&xr[24];
                const float4 f7 = *(const float4*)&xr[28];
                split8(f0, f1, h0, l0); split8(f2, f3, h1, l1);
                split8(f4, f5, h2, l2); split8(f6, f7, h3, l3);
            }
            const int sw = (rrow >> 1) & 3;
            u16* dA = buf0 + rrow * 32;
            *(u16x8*)&dA[(0 ^ sw) << 3] = h0;
            *(u16x8*)&dA[(1 ^ sw) << 3] = h1;
            *(u16x8*)&dA[(2 ^ sw) << 3] = h2;
            *(u16x8*)&dA[(3 ^ sw) << 3] = h3;
            u16* dL = buf0 + 4096 + rrow * 32;
            *(u16x8*)&dL[(0 ^ sw) << 3] = l0;
            *(u16x8*)&dL[(1 ^ sw) << 3] = l1;
            *(u16x8*)&dL[(2 ^ sw) << 3] = l2;
            *(u16x8*)&dL[(3 ^ sw) << 3] = l3;
        } else {
            const u16* wpl = (wid == 2) ? WinTh : WinTl;
            u16* ldst = buf0 + wid * 4096;
#pragma unroll
            for (int i = 0; i < 8; ++i) {
                const int r = i * 16 + rl;
                gl_lds16(&wpl[(size_t)(q0 + r) * INd + k0 + csrc], ldst + i * 512);
            }
        }
        __syncthreads();
        MFMA_TILE(buf0);
        __syncthreads();
    }

    // epilogue via LDS: all global I/O is coalesced u16x8.
    for (int h = 0; h < 2; ++h) {
        __syncthreads();
        if (wm == h) {
#pragma unroll
            for (int i = 0; i < 4; ++i)
#pragma unroll
                for (int j = 0; j < 4; ++j)
#pragma unroll
                    for (int rg = 0; rg < 4; ++rg)
                        Cf[(i * 16 + quad * 4 + rg) * 128 + wn * 64 + j * 16 + l15]
                            = acc[i][j][rg];
        }
        __syncthreads();
#pragma unroll
        for (int pass = 0; pass < 4; ++pass) {
            const int r  = (tid >> 4) + pass * 16;      // 0..63
            const int c0 = (tid & 15) * 8;              // 0..120
            const int wrow = h * 64 + r;
            const float4 v0 = *(const float4*)&Cf[r * 128 + c0];
            const float4 v1 = *(const float4*)&Cf[r * 128 + c0 + 4];
            float vv[8] = {v0.x, v0.y, v0.z, v0.w, v1.x, v1.y, v1.z, v1.w};
            u16x8 ph, pl;
            if (s > 0) {
                const size_t prow = (size_t)(bofs + 4 * wrow + cin) * RES + q0 + c0;
                ph = *(const u16x8*)&Sh[prow];
                pl = *(const u16x8*)&Sl[prow];
            }
            u16x8 oh, ol;
#pragma unroll
            for (int e = 0; e < 8; ++e) {
                float prev = (s > 0) ? (bf2f(ph[e]) + bf2f(pl[e])) : 0.f;
                float v = 0.7f * prev + 0.3f * sinf(vv[e]);
                u16 hh, ll; splitf(v, hh, ll);
                oh[e] = hh; ol[e] = ll;
            }
            const size_t orow = (size_t)(bofs + 4 * wrow + cout) * RES + q0 + c0;
            *(u16x8*)&Sh[orow] = oh;
            *(u16x8*)&Sl[orow] = ol;
        }
    }
}

// Gram on bf16 planes: A[b] = (Sh+Sl)(Sh+Sl)^T + ones + reg*I, bf16x3.
// v2: same global_load_lds double-buffered staging as step_mfma.
__global__ __launch_bounds__(256)
void gram_mfma_kernel(const u16* __restrict__ Sh, const u16* __restrict__ Sl,
                      float* __restrict__ A, const float* __restrict__ lam)
{
    __shared__ u16 LB[2 * 16384];
    u16* buf0 = LB;
    u16* buf1 = LB + 16384;
    float* Cf = (float*)LB;                   // 64 x 132 f32 = 33.8 KB

    const int tid = threadIdx.x;
    const int bt  = blockIdx.y;
    int ti = 0, rem = (int)blockIdx.x;
    while (rem >= 4 - ti) { rem -= 4 - ti; ++ti; }
    const int tj = ti + rem;
    const int n0 = ti * 128, m0 = tj * 128;
    const int bofs = bt * Tt;

    const int wid = tid >> 6, lane = tid & 63;
    const int wm = wid & 1, wn = wid >> 1;
    const int l15 = lane & 15, quad = lane >> 4;

    f32x4 acc[4][4];
    const f32x4 zz = {0.f, 0.f, 0.f, 0.f};
#pragma unroll
    for (int i = 0; i < 4; ++i)
#pragma unroll
        for (int j = 0; j < 4; ++j) acc[i][j] = zz;

    const int rl    = lane >> 2;
    const int csrc  = (((lane & 3) ^ ((lane >> 3) & 3)) << 3);
    const u16* plane = (wid & 1) ? Sl : Sh;
    const int rbase  = (wid < 2) ? n0 : m0;

    auto stage = [&](u16* buf, int k0) {
        u16* ldst = buf + wid * 4096;
#pragma unroll
        for (int i = 0; i < 8; ++i) {
            const int r = i * 16 + rl;
            gl_lds16(&plane[(size_t)(bofs + rbase + r) * RES + k0 + csrc],
                     ldst + i * 512);
        }
    };

    stage(buf0, 0);
    __syncthreads();
    for (int k0 = 0; k0 < RES; k0 += 32) {
        u16* cur = (k0 & 32) ? buf1 : buf0;
        u16* nxt = (k0 & 32) ? buf0 : buf1;
        if (k0 + 32 < RES) stage(nxt, k0 + 32);
        MFMA_TILE(cur);
        __syncthreads();
    }

    const float reg = log1pf(expf(lam[0]));
    float* Ab = A + (size_t)bt * 512 * 512;
    for (int h = 0; h < 2; ++h) {
        __syncthreads();
        if (wm == h) {
#pragma unroll
            for (int i = 0; i < 4; ++i)
#pragma unroll
                for (int j = 0; j < 4; ++j)
#pragma unroll
                    for (int rg = 0; rg < 4; ++rg)
                        Cf[(i * 16 + quad * 4 + rg) * 132 + wn * 64 + j * 16 + l15]
                            = acc[i][j][rg];
        }
        __syncthreads();
        // row-major half: rows nn = n0+h*64+r, cols m0..m0+127
#pragma unroll
        for (int pass = 0; pass < 4; ++pass) {
            const int r  = (tid >> 4) + pass * 16;
            const int c0 = (tid & 15) * 8;
            const int nn = n0 + h * 64 + r;
            float o[8];
#pragma unroll
            for (int e = 0; e < 8; ++e) {
                const int mm = m0 + c0 + e;
                float v = Cf[r * 132 + c0 + e] + 1.0f;
                if (nn == mm) v += reg;
                o[e] = v;
            }
            float* dst = Ab + (size_t)nn * 512 + m0 + c0;
            *(float4*)&dst[0] = make_float4(o[0], o[1], o[2], o[3]);
            *(float4*)&dst[4] = make_float4(o[4], o[5], o[6], o[7]);
        }
        // transposed half: rows mm = m0+rt, cols n0+h*64 .. +63
#pragma unroll
        for (int pass = 0; pass < 4; ++pass) {
            const int rt  = (tid >> 3) + pass * 32;     // 0..127
            const int c0t = (tid & 7) * 8;              // 0..56
            const int mm  = m0 + rt;
            float o[8];
#pragma unroll
            for (int e = 0; e < 8; ++e) {
                const int nn = n0 + h * 64 + c0t + e;
                float v = Cf[(c0t + e) * 132 + rt] + 1.0f;
                if (nn == mm) v += reg;
                o[e] = v;
            }
            float* dst = Ab + (size_t)mm * 512 + n0 + h * 64 + c0t;
            *(float4*)&dst[0] = make_float4(o[0], o[1], o[2], o[3]);
            *(float4*)&dst[4] = make_float4(o[4], o[5], o[6], o[7]);
        }
    }
}

// Diag-block Cholesky (64x64) + inverse, v2: 256 threads / 4 waves per batch.
// Same math & summation order as the 1-wave version, but rank-1 / column-sweep
// parallelized across all 256 threads (thread = (row r, 16-col strip q)):
// pipelined conflict-free LDS reads instead of serial latency-exposed chains.
__global__ __launch_bounds__(256)
void chol_diag_inv_kernel(float* __restrict__ Aall, float* __restrict__ Winv,
                          float* __restrict__ WinvT, int k)
{
    __shared__ float P[64][65];
    __shared__ float W[64][65];
    const int b = blockIdx.x, tid = threadIdx.x;
    float* A = Aall + (size_t)b * 512 * 512;
    const int j0 = 64 * k;
    const int r = tid & 63;          // row (factor) / RHS column (inverse)
    const int q = tid >> 6;          // 16-wide column strip

    // load 64x64 (each thread 16 floats)
    {
        const int lr = tid >> 2, lc = (tid & 3) * 16;
#pragma unroll
        for (int i = 0; i < 4; ++i) {
            const float4 v = *(const float4*)(A + (size_t)(j0 + lr) * 512 + j0 + lc + 4*i);
            P[lr][lc + 4*i + 0] = v.x; P[lr][lc + 4*i + 1] = v.y;
            P[lr][lc + 4*i + 2] = v.z; P[lr][lc + 4*i + 3] = v.w;
        }
    }
    __syncthreads();

    // ---- factor: P -> L (lower), columns j ascending ----
    for (int j = 0; j < 64; ++j) {
        if (tid < 64) {
            const float d = sqrtf(P[j][j]);
            if (tid == j)      P[j][j]   = d;
            else if (tid > j)  P[tid][j] = P[tid][j] / d;
        }
        __syncthreads();
        // rank-1 update on strip q: P[r][m] -= P[r][j]*P[m][j], j < m <= r
        const float prj = P[r][j];
        float pm[16];
#pragma unroll
        for (int i = 0; i < 16; ++i) pm[i] = P[q * 16 + i][j];
#pragma unroll
        for (int i = 0; i < 16; ++i) {
            const int m = q * 16 + i;
            if (m > j && m <= r) P[r][m] -= prj * pm[i];
        }
        __syncthreads();
    }

    // ---- invert: W = L^{-1}, column-sweep forward substitution ----
    for (int t = tid; t < 4096; t += 256)
        W[t >> 6][t & 63] = ((t >> 6) == (t & 63)) ? 1.f : 0.f;
    __syncthreads();
    for (int j = 0; j < 64; ++j) {
        if (tid < 64) W[j][tid] = W[j][tid] / P[j][j];
        __syncthreads();
        // W[m][r] -= P[m][j] * W[j][r]  for m > j (strip q)
        const float wjc = W[j][r];
        float pm[16];
#pragma unroll
        for (int i = 0; i < 16; ++i) pm[i] = P[q * 16 + i][j];
#pragma unroll
        for (int i = 0; i < 16; ++i) {
            const int m = q * 16 + i;
            if (m > j) W[m][r] -= pm[i] * wjc;
        }
        __syncthreads();
    }

    // write back L (full rows; upper triangle untouched = original A values)
    {
        const int lr = tid >> 2, lc = (tid & 3) * 16;
#pragma unroll
        for (int i = 0; i < 4; ++i)
            *(float4*)(A + (size_t)(j0 + lr) * 512 + j0 + lc + 4*i) =
                make_float4(P[lr][lc + 4*i + 0], P[lr][lc + 4*i + 1],
                            P[lr][lc + 4*i + 2], P[lr][lc + 4*i + 3]);
    }
    float* Wo  = Winv  + ((size_t)b * 8 + k) * 64 * 64;
    float* WoT = WinvT + ((size_t)b * 8 + k) * 64 * 64;
    for (int t = tid; t < 4096; t += 256) {
        Wo[t]  = W[t >> 6][t & 63];
        WoT[t] = W[t & 63][t >> 6];
    }
}

// Panel TRSM via inverse: L[i0.., k] = A[i0.., k] @ W^T
__global__ __launch_bounds__(256)
void trsm_kernel(float* __restrict__ Aall, const float* __restrict__ WinvT, int k)
{
    __shared__ float St[BK][BM + 4];
    __shared__ float Wt[BK][BN + 4];
    float* A = Aall + (size_t)blockIdx.y * 512 * 512;
    const float* WT = WinvT + ((size_t)blockIdx.y * 8 + k) * 64 * 64;
    const int i0 = (k + 1 + blockIdx.x) * 64, p0 = k * 64;
    const int tid = threadIdx.x;
    const int li = tid >> 2, lk = (tid & 3) << 2;
    const int wk = tid >> 4, wq = (tid & 15) << 2;
    const int ty = tid >> 4, tx = tid & 15;
    float acc[4][4] = {};
    for (int k0 = 0; k0 < 64; k0 += BK) {
        const float4 u = *(const float4*)(A + (size_t)(i0 + li) * 512 + p0 + k0 + lk);
        St[lk + 0][li] = u.x; St[lk + 1][li] = u.y;
        St[lk + 2][li] = u.z; St[lk + 3][li] = u.w;
        *(float4*)&Wt[wk][wq] = *(const float4*)(WT + (size_t)(k0 + wk) * 64 + wq);
        __syncthreads();
        MICRO(St, Wt);
        __syncthreads();
    }
#pragma unroll
    for (int a = 0; a < 4; ++a) {
        const int r = i0 + (ty << 2) + a;
        *(float4*)(A + (size_t)r * 512 + p0 + (tx << 2)) =
            make_float4(acc[a][0], acc[a][1], acc[a][2], acc[a][3]);
    }
}

// Trailing update: A[ti,tj] -= L[ti,k] L[tj,k]^T
__global__ __launch_bounds__(256)
void chol_trailing_kernel(float* __restrict__ Aall, int k)
{
    __shared__ float Ut[BK][BM + 4];
    __shared__ float Vt[BK][BN + 4];
    float* A = Aall + (size_t)blockIdx.y * 512 * 512;
    const int tid = threadIdx.x;
    int a = 0, rem = (int)blockIdx.x;
    while (rem >= a + 1) { rem -= a + 1; ++a; }
    const int ti = k + 1 + a, tj = k + 1 + rem;
    const int i0 = ti * 64, j0c = tj * 64, p0 = k * 64;

    const int li = tid >> 2, lk = (tid & 3) << 2;
    const int ty = tid >> 4, tx = tid & 15;
    float acc[4][4] = {};

    for (int k0 = 0; k0 < 64; k0 += BK) {
        const float4 u = *(const float4*)(A + (size_t)(i0 + li) * 512 + p0 + k0 + lk);
        const float4 v = *(const float4*)(A + (size_t)(j0c + li) * 512 + p0 + k0 + lk);
        Ut[lk + 0][li] = u.x; Ut[lk + 1][li] = u.y;
        Ut[lk + 2][li] = u.z; Ut[lk + 3][li] = u.w;
        Vt[lk + 0][li] = v.x; Vt[lk + 1][li] = v.y;
        Vt[lk + 2][li] = v.z; Vt[lk + 3][li] = v.w;
        __syncthreads();
        MICRO(Ut, Vt);
        __syncthreads();
    }
#pragma unroll
    for (int aa = 0; aa < 4; ++aa) {
        const int r = i0 + (ty << 2) + aa;
        float* crow = A + (size_t)r * 512 + j0c + (tx << 2);
        float4 cv = *(const float4*)crow;
        cv.x -= acc[aa][0]; cv.y -= acc[aa][1];
        cv.z -= acc[aa][2]; cv.w -= acc[aa][3];
        *(float4*)crow = cv;
    }
}

// Blocked fwd+bwd solve, v4: 256 blocks (32 batches x 8 col-splits of 8 cols),
// ONE wave per block, XCD-colocated: same-batch col-split blocks are placed at
// indices congruent mod 8 (b = blk&31, c = blk>>5) so all 8 land on the SAME
// XCD and share its L2 for the A/Winv panels (per-XCD working set ~3.2 MB
// < 4 MB L2). Removes the 8x cross-XCD HBM duplication seen as 150 MB FETCH.
// Accumulation order per output element unchanged -> same numerics.
__global__ __launch_bounds__(64, 1)
void fb_solve3_kernel(const float* __restrict__ Aall,
                      const float* __restrict__ Winv,
                      const float* __restrict__ WinvT,
                      const float* __restrict__ Y, float* __restrict__ Zall)
{
    __shared__ float V[512][10];   // 8 used cols + 2 pad (bank spread)
    __shared__ float U[64][10];
    const int tid = threadIdx.x;
    const int b   = (int)blockIdx.x & 31;          // batch -> XCD (b mod 8)
    const int c0  = ((int)blockIdx.x >> 5) * 8;    // col-split
    const int ty  = tid >> 2;            // 0..15 -> rows 4*ty..4*ty+3
    const int tx  = tid & 3;             // 0..3  -> cols 2*tx..2*tx+1
    const float* A   = Aall + (size_t)b * 512 * 512;
    const float* Yb  = Y    + (size_t)b * 512 * OUTd + c0;
    float*       Zb  = Zall + (size_t)b * 512 * OUTd + c0;
    const float* Wb  = Winv  + (size_t)b * 8 * 64 * 64 + 4 * ty;
    const float* WbT = WinvT + (size_t)b * 8 * 64 * 64 + 4 * ty;

    for (int t = tid; t < 512 * 4; t += 64) {
        const int row = t >> 2, p = (t & 3) * 2;
        *(float2*)&V[row][p] = *(const float2*)&Yb[(size_t)row * OUTd + p];
    }
    __syncthreads();

    float acc[4][2];
    f32x4 pa[4][4], pb[4][4];

#define LDA_F(dst, kk0)                                                         \
    { _Pragma("unroll") for (int r_ = 0; r_ < 4; ++r_)                          \
      _Pragma("unroll") for (int q_ = 0; q_ < 4; ++q_)                          \
        dst[r_][q_] = *(const f32x4*)&A[(size_t)(r0 + 4 * ty + r_) * 512 + (kk0) + 4 * q_]; }

#define CMP_F(P, kbase)                                                         \
    { _Pragma("unroll") for (int q_ = 0; q_ < 16; ++q_) {                       \
        const float2 v_ = *(const float2*)&V[(kbase) + q_][2 * tx];             \
        _Pragma("unroll") for (int r_ = 0; r_ < 4; ++r_) {                      \
          acc[r_][0] += P[r_][q_ >> 2][q_ & 3] * v_.x;                          \
          acc[r_][1] += P[r_][q_ >> 2][q_ & 3] * v_.y; } } }

#define LDA_K(dst, base, row0, S)                                               \
    { _Pragma("unroll") for (int i_ = 0; i_ < 16; ++i_)                         \
        dst[i_ >> 2][i_ & 3] = *(const f32x4*)&(base)[(size_t)((row0) + i_) * (S)]; }

#define CMP_K(P, ARR, kbase)                                                    \
    { _Pragma("unroll") for (int i_ = 0; i_ < 16; ++i_) {                       \
        const float2 v_ = *(const float2*)&ARR[(kbase) + i_][2 * tx];           \
        _Pragma("unroll") for (int r_ = 0; r_ < 4; ++r_) {                      \
          acc[r_][0] += P[i_ >> 2][i_ & 3][r_] * v_.x;                          \
          acc[r_][1] += P[i_ >> 2][i_ & 3][r_] * v_.y; } } }

#define ZACC                                                                    \
    { _Pragma("unroll") for (int r_ = 0; r_ < 4; ++r_) {                        \
        acc[r_][0] = 0.f; acc[r_][1] = 0.f; } }

#define URES(R0)                                                                \
    { _Pragma("unroll") for (int r_ = 0; r_ < 4; ++r_)                          \
      _Pragma("unroll") for (int c_ = 0; c_ < 2; ++c_)                          \
        U[4 * ty + r_][2 * tx + c_] =                                           \
            V[(R0) + 4 * ty + r_][2 * tx + c_] - acc[r_][c_]; }

#define VOUT(R0)                                                                \
    { _Pragma("unroll") for (int r_ = 0; r_ < 4; ++r_)                          \
      _Pragma("unroll") for (int c_ = 0; c_ < 2; ++c_)                          \
        V[(R0) + 4 * ty + r_][2 * tx + c_] = acc[r_][c_]; }

#define DIAG(Wp)                                                                \
    { ZACC; LDA_K(pa, Wp, 0, 64); LDA_K(pb, Wp, 16, 64);                        \
      CMP_K(pa, U, 0);  LDA_K(pa, Wp, 32, 64);                                  \
      CMP_K(pb, U, 16); LDA_K(pb, Wp, 48, 64);                                  \
      CMP_K(pa, U, 32); CMP_K(pb, U, 48); }

    // ---- forward: V_k = W_k (Y_k - L[k, 0:64k] @ V) ----
    for (int k = 0; k < 8; ++k) {
        const int r0 = k * 64;
        ZACC;
        if (r0 > 0) {
            LDA_F(pa, 0);
            for (int k0 = 0; k0 < r0; k0 += 32) {
                LDA_F(pb, k0 + 16);
                CMP_F(pa, k0);
                if (k0 + 32 < r0) LDA_F(pa, k0 + 32);
                CMP_F(pb, k0 + 16);
            }
        }
        URES(r0);
        __syncthreads();
        DIAG(WbT + (size_t)k * 4096);
        VOUT(r0);
        __syncthreads();
    }

    // ---- backward: Z_k = W_k^T (V_k - L[64(k+1):, k]^T @ Z) ----
    for (int k = 7; k >= 0; --k) {
        const int r0 = k * 64;
        ZACC;
        if (r0 + 64 < 512) {
            const float* Ac = A + r0 + 4 * ty;
            LDA_K(pa, Ac, r0 + 64, 512);
            for (int m0 = r0 + 64; m0 < 512; m0 += 32) {
                LDA_K(pb, Ac, m0 + 16, 512);
                CMP_K(pa, V, m0);
                if (m0 + 32 < 512) LDA_K(pa, Ac, m0 + 32, 512);
                CMP_K(pb, V, m0 + 16);
            }
        }
        URES(r0);
        __syncthreads();
        DIAG(Wb + (size_t)k * 4096);
        VOUT(r0);
        __syncthreads();
    }

    for (int t = tid; t < 512 * 4; t += 64) {
        const int row = t >> 2, p = (t & 3) * 2;
        *(float2*)&Zb[(size_t)row * OUTd + p] = *(const float2*)&V[row][p];
    }
#undef LDA_F
#undef CMP_F
#undef LDA_K
#undef CMP_K
#undef ZACC
#undef URES
#undef VOUT
#undef DIAG
}

// w[b] = RS_b^T @ Z_b, RS reconstructed as h+l.
__global__ __launch_bounds__(256)
void out_kernel(const u16* __restrict__ Sh, const u16* __restrict__ Sl,
                const float* __restrict__ Z, float* __restrict__ Wout)
{
    __shared__ float Rt[BK][64 + 4];
    __shared__ float Zt[BK][64 + 4];
    const int tid = threadIdx.x;
    const int b   = blockIdx.y;
    const int d0  = blockIdx.x * 64;
    const int kk  = tid >> 4, cq = (tid & 15) << 2;
    const int ty  = tid >> 4, tx = tid & 15;
    float acc[4][4] = {};

    for (int k0 = 0; k0 < Tt; k0 += BK) {
        const size_t ri = (size_t)(b * Tt + k0 + kk) * RES + d0 + cq;
        const u16x4 hv = *(const u16x4*)&Sh[ri];
        const u16x4 lv = *(const u16x4*)&Sl[ri];
        Rt[kk][cq + 0] = bf2f(hv[0]) + bf2f(lv[0]);
        Rt[kk][cq + 1] = bf2f(hv[1]) + bf2f(lv[1]);
        Rt[kk][cq + 2] = bf2f(hv[2]) + bf2f(lv[2]);
        Rt[kk][cq + 3] = bf2f(hv[3]) + bf2f(lv[3]);
        *(float4*)&Zt[kk][cq] =
            *(const float4*)(Z + ((size_t)b * Tt + k0 + kk) * OUTd + cq);
        __syncthreads();
        MICRO(Rt, Zt);
        __syncthreads();
    }
#pragma unroll
    for (int a = 0; a < 4; ++a) {
        const int d = d0 + (ty << 2) + a;
        *(float4*)(Wout + ((size_t)b * RES + d) * OUTd + (tx << 2)) =
            make_float4(acc[a][0], acc[a][1], acc[a][2], acc[a][3]);
    }
}

__global__ __launch_bounds__(64)
void bias_kernel(const float* __restrict__ Z, float* __restrict__ Bout)
{
    const int b = blockIdx.x, o = threadIdx.x;
    const float* Zb = Z + (size_t)b * Tt * OUTd;
    float s = 0.f;
    for (int n = 0; n < Tt; ++n) s += Zb[(size_t)n * OUTd + o];
    Bout[(size_t)b * OUTd + o] = s;
}

extern "C" void kernel_launch(void* const* d_in, const int* in_sizes, int n_in,
                              void* d_out, int out_size, void* d_ws, size_t ws_size,
                              hipStream_t stream)
{
    const float* X    = (const float*)d_in[0];   // (32,512,128)
    const float* Y    = (const float*)d_in[1];   // (32,512,64)
    const float* Wres = (const float*)d_in[2];   // (2048,2048)
    const float* Win  = (const float*)d_in[3];   // (128,2048)
    const float* lam  = (const float*)d_in[4];   // scalar

    float* out  = (float*)d_out;
    float* Wout = out;
    float* Bout = out + (size_t)Bb * RES * OUTd;

    // ws: Sh 64 | Sl 64 | WTh 8 | WTl 8 | WinTh .5 | WinTl .5 | A 32 | Z 4 | Wi 4 | WiT 4 = 189 MB
    char* p = (char*)d_ws;
    u16* Sh    = (u16*)p;   p += (size_t)Bb * Tt * RES * 2;
    u16* Sl    = (u16*)p;   p += (size_t)Bb * Tt * RES * 2;
    u16* WTh   = (u16*)p;   p += (size_t)RES * RES * 2;
    u16* WTl   = (u16*)p;   p += (size_t)RES * RES * 2;
    u16* WinTh = (u16*)p;   p += (size_t)INd * RES * 2;
    u16* WinTl = (u16*)p;   p += (size_t)INd * RES * 2;
    float* A   = (float*)p; p += (size_t)Bb * 512 * 512 * 4;
    float* Z   = (float*)p; p += (size_t)Bb * Tt * OUTd * 4;
    float* Wi  = (float*)p; p += (size_t)Bb * 8 * 64 * 64 * 4;
    float* WiT = (float*)p;

    const dim3 blk(256);
    tconv_kernel<<<dim3(RES / 64, RES / 64), blk, 0, stream>>>(Wres, WTh, WTl, RES, RES);
    tconv_kernel<<<dim3(RES / 64, INd / 64), blk, 0, stream>>>(Win, WinTh, WinTl, INd, RES);

    // classes: s:(cin->cout) 0:(-,2) 1:(2,1) 2:(1,0) 3:(0,1) 4:(1,2) 5:(2,3)
    const dim3 sgrid(RES / 128, Bb);
    step_mfma_kernel<<<sgrid, blk, 0, stream>>>(Sh, Sl, X, WTh, WTl, WinTh, WinTl, 0, 2, 0);
    step_mfma_kernel<<<sgrid, blk, 0, stream>>>(Sh, Sl, X, WTh, WTl, WinTh, WinTl, 2, 1, 1);
    step_mfma_kernel<<<sgrid, blk, 0, stream>>>(Sh, Sl, X, WTh, WTl, WinTh, WinTl, 1, 0, 2);
    step_mfma_kernel<<<sgrid, blk, 0, stream>>>(Sh, Sl, X, WTh, WTl, WinTh, WinTl, 0, 1, 3);
    step_mfma_kernel<<<sgrid, blk, 0, stream>>>(Sh, Sl, X, WTh, WTl, WinTh, WinTl, 1, 2, 4);
    step_mfma_kernel<<<sgrid, blk, 0, stream>>>(Sh, Sl, X, WTh, WTl, WinTh, WinTl, 2, 3, 5);

    gram_mfma_kernel<<<dim3(10, Bb), blk, 0, stream>>>(Sh, Sl, A, lam);

    for (int k = 0; k < 8; ++k) {
        chol_diag_inv_kernel<<<dim3(Bb), dim3(256), 0, stream>>>(A, Wi, WiT, k);
        if (k < 7) {
            trsm_kernel<<<dim3(7 - k, Bb), blk, 0, stream>>>(A, WiT, k);
            const int m = 7 - k;
            chol_trailing_kernel<<<dim3(m * (m + 1) / 2, Bb), blk, 0, stream>>>(A, k);
        }
    }
    fb_solve3_kernel<<<dim3(Bb * 8), dim3(64), 0, stream>>>(A, Wi, WiT, Y, Z);

    out_kernel<<<dim3(RES / 64, Bb), blk, 0, stream>>>(Sh, Sl, Z, Wout);
    bias_kernel<<<dim3(Bb), dim3(OUTd), 0, stream>>>(Z, Bout);
}

// Round 6
// 2112.039 us; speedup vs baseline: 1.3387x; 1.0097x over previous
//
#include <hip/hip_runtime.h>
#include <cmath>

#define Bb   32
#define Tt   512
#define INd  128
#define RES  2048
#define OUTd 64

#define BM 64
#define BN 64
#define BK 16

typedef unsigned short u16;
typedef __attribute__((ext_vector_type(4))) unsigned short u16x4;
typedef __attribute__((ext_vector_type(8))) unsigned short u16x8;
typedef __attribute__((ext_vector_type(8))) short bf8;
typedef __attribute__((ext_vector_type(4))) float f32x4;

// fp32 = bf16 hi (RNE) + bf16 lo (trunc residual); |err| <= 2^-17 |a|
__device__ __forceinline__ void splitf(float a, u16& h, u16& l) {
    unsigned u = __float_as_uint(a);
    unsigned r = (u + 0x7fffu + ((u >> 16) & 1u)) & 0xffff0000u;
    h = (u16)(r >> 16);
    float d = a - __uint_as_float(r);
    l = (u16)(__float_as_uint(d) >> 16);
}
__device__ __forceinline__ float bf2f(u16 h) {
    return __uint_as_float((unsigned)h << 16);
}
__device__ __forceinline__ void split8(const float4& a, const float4& b,
                                       u16x8& h, u16x8& l) {
    u16 hh, ll;
    splitf(a.x, hh, ll); h[0] = hh; l[0] = ll;
    splitf(a.y, hh, ll); h[1] = hh; l[1] = ll;
    splitf(a.z, hh, ll); h[2] = hh; l[2] = ll;
    splitf(a.w, hh, ll); h[3] = hh; l[3] = ll;
    splitf(b.x, hh, ll); h[4] = hh; l[4] = ll;
    splitf(b.y, hh, ll); h[5] = hh; l[5] = ll;
    splitf(b.z, hh, ll); h[6] = hh; l[6] = ll;
    splitf(b.w, hh, ll); h[7] = hh; l[7] = ll;
}

// async global->LDS, 16B per lane. LDS dest is wave-uniform base + lane*16;
// global src is per-lane (carries the chunk swizzle).
__device__ __forceinline__ void gl_lds16(const u16* g, u16* l) {
    __builtin_amdgcn_global_load_lds(
        (const __attribute__((address_space(1))) unsigned int*)g,
        (__attribute__((address_space(3))) unsigned int*)l,
        16, 0, 0);
}

#define MICRO(SA, SB)                                                           \
  do {                                                                          \
    _Pragma("unroll")                                                           \
    for (int kk = 0; kk < BK; ++kk) {                                           \
      const float4 a4 = *(const float4*)&SA[kk][ty << 2];                       \
      const float4 b4 = *(const float4*)&SB[kk][tx << 2];                       \
      acc[0][0] += a4.x*b4.x; acc[0][1] += a4.x*b4.y;                           \
      acc[0][2] += a4.x*b4.z; acc[0][3] += a4.x*b4.w;                           \
      acc[1][0] += a4.y*b4.x; acc[1][1] += a4.y*b4.y;                           \
      acc[1][2] += a4.y*b4.z; acc[1][3] += a4.y*b4.w;                           \
      acc[2][0] += a4.z*b4.x; acc[2][1] += a4.z*b4.y;                           \
      acc[2][2] += a4.z*b4.z; acc[2][3] += a4.z*b4.w;                           \
      acc[3][0] += a4.w*b4.x; acc[3][1] += a4.w*b4.y;                           \
      acc[3][2] += a4.w*b4.z; acc[3][3] += a4.w*b4.w;                           \
    }                                                                           \
  } while (0)

// 128x128 tile, K=32 slice, bf16x3. Linear LDS rows of 32 u16 (64 B) with
// 16B-chunk XOR swizzle c' = c ^ ((row>>1)&3)  ->  max 2-way bank alias (free).
// Buffer layout (u16 offsets): Ah 0 | Al 4096 | Bh 8192 | Bl 12288.
#define MFMA_TILE(BUF)                                                           \
  do {                                                                           \
    bf8 aH[4], aL[4], bH[4], bL[4];                                              \
    const int qd = (quad ^ ((l15 >> 1) & 3)) << 3;                               \
    _Pragma("unroll")                                                            \
    for (int i = 0; i < 4; ++i) {                                                \
      const int ar = (wm*64 + i*16 + l15)*32 + qd;                               \
      const int br = (wn*64 + i*16 + l15)*32 + qd;                               \
      aH[i] = *(const bf8*)&(BUF)[ar];                                           \
      aL[i] = *(const bf8*)&(BUF)[4096 + ar];                                    \
      bH[i] = *(const bf8*)&(BUF)[8192 + br];                                    \
      bL[i] = *(const bf8*)&(BUF)[12288 + br];                                   \
    }                                                                            \
    _Pragma("unroll")                                                            \
    for (int i = 0; i < 4; ++i)                                                  \
      _Pragma("unroll")                                                          \
      for (int j = 0; j < 4; ++j) {                                              \
        acc[i][j] = __builtin_amdgcn_mfma_f32_16x16x32_bf16(aH[i], bH[j], acc[i][j], 0, 0, 0); \
        acc[i][j] = __builtin_amdgcn_mfma_f32_16x16x32_bf16(aH[i], bL[j], acc[i][j], 0, 0, 0); \
        acc[i][j] = __builtin_amdgcn_mfma_f32_16x16x32_bf16(aL[i], bH[j], acc[i][j], 0, 0, 0); \
      }                                                                          \
  } while (0)

// Transpose + split weights: in (K x N fp32) -> outH/outL (N x K bf16).
__global__ __launch_bounds__(256)
void tconv_kernel(const float* __restrict__ in, u16* __restrict__ outH,
                  u16* __restrict__ outL, int K, int N)
{
    __shared__ float T[64][65];
    const int n0 = blockIdx.x * 64, k0 = blockIdx.y * 64;
    const int t = threadIdx.x;
    const int r = t >> 2, c0 = (t & 3) * 16;
#pragma unroll
    for (int i = 0; i < 4; ++i) {
        const float4 v = *(const float4*)&in[(size_t)(k0 + r) * N + n0 + c0 + 4*i];
        T[r][c0 + 4*i + 0] = v.x; T[r][c0 + 4*i + 1] = v.y;
        T[r][c0 + 4*i + 2] = v.z; T[r][c0 + 4*i + 3] = v.w;
    }
    __syncthreads();
    const int n = t >> 2, ck = (t & 3) * 16;
    u16x8 h0, h1, l0, l1;
#pragma unroll
    for (int i = 0; i < 8; ++i) { u16 h, l; splitf(T[ck + i][n], h, l); h0[i] = h; l0[i] = l; }
#pragma unroll
    for (int i = 0; i < 8; ++i) { u16 h, l; splitf(T[ck + 8 + i][n], h, l); h1[i] = h; l1[i] = l; }
    const size_t ob = (size_t)(n0 + n) * K + k0 + ck;
    *(u16x8*)&outH[ob] = h0; *(u16x8*)&outH[ob + 8] = h1;
    *(u16x8*)&outL[ob] = l0; *(u16x8*)&outL[ob + 8] = l1;
}

// Reservoir step on bf16 hi/lo state planes (row = b*512 + 4w + class).
// v2: global_load_lds staging (width 16) into double-buffered 32-KB slice
// buffers; ONE barrier per K-slice. Epilogue via LDS (coalesced u16x8).
__global__ __launch_bounds__(256)
void step_mfma_kernel(u16* __restrict__ Sh, u16* __restrict__ Sl,
                      const float* __restrict__ X,
                      const u16* __restrict__ WTh, const u16* __restrict__ WTl,
                      const u16* __restrict__ WinTh, const u16* __restrict__ WinTl,
                      int cin, int cout, int s)
{
    __shared__ u16 LB[2 * 16384];             // 2 x 32 KB slice buffers
    u16* buf0 = LB;
    u16* buf1 = LB + 16384;
    float* Cf = (float*)LB;                   // 64x128 f32 = 32 KB (epilogue)

    const int tid = threadIdx.x;
    const int q0  = blockIdx.x * 128;         // reservoir-col tile
    const int b   = blockIdx.y;
    const int bofs = b * Tt;
    const int wid = tid >> 6, lane = tid & 63;
    const int wm = wid & 1, wn = wid >> 1;
    const int l15 = lane & 15, quad = lane >> 4;

    f32x4 acc[4][4];
    const f32x4 zz = {0.f, 0.f, 0.f, 0.f};
#pragma unroll
    for (int i = 0; i < 4; ++i)
#pragma unroll
        for (int j = 0; j < 4; ++j) acc[i][j] = zz;

    // per-wave slice staging: wid 0=Ah(Sh) 1=Al(Sl) 2=Bh(WTh) 3=Bl(WTl).
    // lane l covers row r = i*16 + (l>>2), dest chunk l&3; source chunk is
    // pre-swizzled: csrc = (l&3) ^ ((l>>3)&3)  (== (l&3) ^ ((r>>1)&3)).
    const int rl    = lane >> 2;
    const int csrc  = (((lane & 3) ^ ((lane >> 3) & 3)) << 3);
    const u16* plane = (wid == 0) ? (const u16*)Sh
                     : (wid == 1) ? (const u16*)Sl
                     : (wid == 2) ? WTh : WTl;

    auto stage = [&](u16* buf, int k0) {
        u16* ldst = buf + wid * 4096;
#pragma unroll
        for (int i = 0; i < 8; ++i) {
            const int r = i * 16 + rl;
            const size_t grow = (wid < 2) ? (size_t)(bofs + 4 * r + cin)
                                          : (size_t)(q0 + r);
            gl_lds16(&plane[grow * RES + k0 + csrc], ldst + i * 512);
        }
    };

    if (s > 0) {
        stage(buf0, 0);
        __syncthreads();                      // drains vmcnt -> buf0 ready
        for (int k0 = 0; k0 < RES; k0 += 32) {
            u16* cur = (k0 & 32) ? buf1 : buf0;
            u16* nxt = (k0 & 32) ? buf0 : buf1;
            if (k0 + 32 < RES) stage(nxt, k0 + 32);
            MFMA_TILE(cur);
            __syncthreads();                  // nxt staged; cur reads done
        }
    }

    // input projection: K=128 over x[b, 4w+s-2, :] @ Win.
    // waves 0,1: compute A rows (splitf) + swizzled ds_write; waves 2,3: gload B.
    for (int k0 = 0; k0 < INd; k0 += 32) {
        if (tid < 128) {
            const int rrow = tid;             // 0..127
            const int t = 4 * rrow + s - 2;
            u16x8 h0 = {0,0,0,0,0,0,0,0}, h1 = h0, h2 = h0, h3 = h0;
            u16x8 l0 = h0, l1 = h0, l2 = h0, l3 = h0;
            if (t >= 0) {
                const float* xr = X + (size_t)(bofs + t) * INd + k0;
                const float4 f0 = *(const float4*)&xr[0];
                const float4 f1 = *(const float4*)&xr[4];
                const float4 f2 = *(const float4*)&xr[8];
                const float4 f3 = *(const float4*)&xr[12];
                const float4 f4 = *(const float4*)&xr[16];
                const float4 f5 = *(const float4*)&xr[20];
                const float4 f6 = *(const float4*)&xr[24];
                const float4 f7 = *(const float4*)&xr[28];
                split8(f0, f1, h0, l0); split8(f2, f3, h1, l1);
                split8(f4, f5, h2, l2); split8(f6, f7, h3, l3);
            }
            const int sw = (rrow >> 1) & 3;
            u16* dA = buf0 + rrow * 32;
            *(u16x8*)&dA[(0 ^ sw) << 3] = h0;
            *(u16x8*)&dA[(1 ^ sw) << 3] = h1;
            *(u16x8*)&dA[(2 ^ sw) << 3] = h2;
            *(u16x8*)&dA[(3 ^ sw) << 3] = h3;
            u16* dL = buf0 + 4096 + rrow * 32;
            *(u16x8*)&dL[(0 ^ sw) << 3] = l0;
            *(u16x8*)&dL[(1 ^ sw) << 3] = l1;
            *(u16x8*)&dL[(2 ^ sw) << 3] = l2;
            *(u16x8*)&dL[(3 ^ sw) << 3] = l3;
        } else {
            const u16* wpl = (wid == 2) ? WinTh : WinTl;
            u16* ldst = buf0 + wid * 4096;
#pragma unroll
            for (int i = 0; i < 8; ++i) {
                const int r = i * 16 + rl;
                gl_lds16(&wpl[(size_t)(q0 + r) * INd + k0 + csrc], ldst + i * 512);
            }
        }
        __syncthreads();
        MFMA_TILE(buf0);
        __syncthreads();
    }

    // epilogue via LDS: all global I/O is coalesced u16x8.
    for (int h = 0; h < 2; ++h) {
        __syncthreads();
        if (wm == h) {
#pragma unroll
            for (int i = 0; i < 4; ++i)
#pragma unroll
                for (int j = 0; j < 4; ++j)
#pragma unroll
                    for (int rg = 0; rg < 4; ++rg)
                        Cf[(i * 16 + quad * 4 + rg) * 128 + wn * 64 + j * 16 + l15]
                            = acc[i][j][rg];
        }
        __syncthreads();
#pragma unroll
        for (int pass = 0; pass < 4; ++pass) {
            const int r  = (tid >> 4) + pass * 16;      // 0..63
            const int c0 = (tid & 15) * 8;              // 0..120
            const int wrow = h * 64 + r;
            const float4 v0 = *(const float4*)&Cf[r * 128 + c0];
            const float4 v1 = *(const float4*)&Cf[r * 128 + c0 + 4];
            float vv[8] = {v0.x, v0.y, v0.z, v0.w, v1.x, v1.y, v1.z, v1.w};
            u16x8 ph, pl;
            if (s > 0) {
                const size_t prow = (size_t)(bofs + 4 * wrow + cin) * RES + q0 + c0;
                ph = *(const u16x8*)&Sh[prow];
                pl = *(const u16x8*)&Sl[prow];
            }
            u16x8 oh, ol;
#pragma unroll
            for (int e = 0; e < 8; ++e) {
                float prev = (s > 0) ? (bf2f(ph[e]) + bf2f(pl[e])) : 0.f;
                float v = 0.7f * prev + 0.3f * sinf(vv[e]);
                u16 hh, ll; splitf(v, hh, ll);
                oh[e] = hh; ol[e] = ll;
            }
            const size_t orow = (size_t)(bofs + 4 * wrow + cout) * RES + q0 + c0;
            *(u16x8*)&Sh[orow] = oh;
            *(u16x8*)&Sl[orow] = ol;
        }
    }
}

// Gram on bf16 planes: A[b] = (Sh+Sl)(Sh+Sl)^T + ones + reg*I, bf16x3.
// v2: same global_load_lds double-buffered staging as step_mfma.
__global__ __launch_bounds__(256)
void gram_mfma_kernel(const u16* __restrict__ Sh, const u16* __restrict__ Sl,
                      float* __restrict__ A, const float* __restrict__ lam)
{
    __shared__ u16 LB[2 * 16384];
    u16* buf0 = LB;
    u16* buf1 = LB + 16384;
    float* Cf = (float*)LB;                   // 64 x 132 f32 = 33.8 KB

    const int tid = threadIdx.x;
    const int bt  = blockIdx.y;
    int ti = 0, rem = (int)blockIdx.x;
    while (rem >= 4 - ti) { rem -= 4 - ti; ++ti; }
    const int tj = ti + rem;
    const int n0 = ti * 128, m0 = tj * 128;
    const int bofs = bt * Tt;

    const int wid = tid >> 6, lane = tid & 63;
    const int wm = wid & 1, wn = wid >> 1;
    const int l15 = lane & 15, quad = lane >> 4;

    f32x4 acc[4][4];
    const f32x4 zz = {0.f, 0.f, 0.f, 0.f};
#pragma unroll
    for (int i = 0; i < 4; ++i)
#pragma unroll
        for (int j = 0; j < 4; ++j) acc[i][j] = zz;

    const int rl    = lane >> 2;
    const int csrc  = (((lane & 3) ^ ((lane >> 3) & 3)) << 3);
    const u16* plane = (wid & 1) ? Sl : Sh;
    const int rbase  = (wid < 2) ? n0 : m0;

    auto stage = [&](u16* buf, int k0) {
        u16* ldst = buf + wid * 4096;
#pragma unroll
        for (int i = 0; i < 8; ++i) {
            const int r = i * 16 + rl;
            gl_lds16(&plane[(size_t)(bofs + rbase + r) * RES + k0 + csrc],
                     ldst + i * 512);
        }
    };

    stage(buf0, 0);
    __syncthreads();
    for (int k0 = 0; k0 < RES; k0 += 32) {
        u16* cur = (k0 & 32) ? buf1 : buf0;
        u16* nxt = (k0 & 32) ? buf0 : buf1;
        if (k0 + 32 < RES) stage(nxt, k0 + 32);
        MFMA_TILE(cur);
        __syncthreads();
    }

    const float reg = log1pf(expf(lam[0]));
    float* Ab = A + (size_t)bt * 512 * 512;
    for (int h = 0; h < 2; ++h) {
        __syncthreads();
        if (wm == h) {
#pragma unroll
            for (int i = 0; i < 4; ++i)
#pragma unroll
                for (int j = 0; j < 4; ++j)
#pragma unroll
                    for (int rg = 0; rg < 4; ++rg)
                        Cf[(i * 16 + quad * 4 + rg) * 132 + wn * 64 + j * 16 + l15]
                            = acc[i][j][rg];
        }
        __syncthreads();
        // row-major half: rows nn = n0+h*64+r, cols m0..m0+127
#pragma unroll
        for (int pass = 0; pass < 4; ++pass) {
            const int r  = (tid >> 4) + pass * 16;
            const int c0 = (tid & 15) * 8;
            const int nn = n0 + h * 64 + r;
            float o[8];
#pragma unroll
            for (int e = 0; e < 8; ++e) {
                const int mm = m0 + c0 + e;
                float v = Cf[r * 132 + c0 + e] + 1.0f;
                if (nn == mm) v += reg;
                o[e] = v;
            }
            float* dst = Ab + (size_t)nn * 512 + m0 + c0;
            *(float4*)&dst[0] = make_float4(o[0], o[1], o[2], o[3]);
            *(float4*)&dst[4] = make_float4(o[4], o[5], o[6], o[7]);
        }
        // transposed half: rows mm = m0+rt, cols n0+h*64 .. +63
#pragma unroll
        for (int pass = 0; pass < 4; ++pass) {
            const int rt  = (tid >> 3) + pass * 32;     // 0..127
            const int c0t = (tid & 7) * 8;              // 0..56
            const int mm  = m0 + rt;
            float o[8];
#pragma unroll
            for (int e = 0; e < 8; ++e) {
                const int nn = n0 + h * 64 + c0t + e;
                float v = Cf[(c0t + e) * 132 + rt] + 1.0f;
                if (nn == mm) v += reg;
                o[e] = v;
            }
            float* dst = Ab + (size_t)mm * 512 + n0 + h * 64 + c0t;
            *(float4*)&dst[0] = make_float4(o[0], o[1], o[2], o[3]);
            *(float4*)&dst[4] = make_float4(o[4], o[5], o[6], o[7]);
        }
    }
}

// Diag-block Cholesky (64x64) + inverse, v2: 256 threads / 4 waves per batch.
// Same math & summation order as the 1-wave version, but rank-1 / column-sweep
// parallelized across all 256 threads (thread = (row r, 16-col strip q)):
// pipelined conflict-free LDS reads instead of serial latency-exposed chains.
__global__ __launch_bounds__(256)
void chol_diag_inv_kernel(float* __restrict__ Aall, float* __restrict__ Winv,
                          float* __restrict__ WinvT, int k)
{
    __shared__ float P[64][65];
    __shared__ float W[64][65];
    const int b = blockIdx.x, tid = threadIdx.x;
    float* A = Aall + (size_t)b * 512 * 512;
    const int j0 = 64 * k;
    const int r = tid & 63;          // row (factor) / RHS column (inverse)
    const int q = tid >> 6;          // 16-wide column strip

    // load 64x64 (each thread 16 floats)
    {
        const int lr = tid >> 2, lc = (tid & 3) * 16;
#pragma unroll
        for (int i = 0; i < 4; ++i) {
            const float4 v = *(const float4*)(A + (size_t)(j0 + lr) * 512 + j0 + lc + 4*i);
            P[lr][lc + 4*i + 0] = v.x; P[lr][lc + 4*i + 1] = v.y;
            P[lr][lc + 4*i + 2] = v.z; P[lr][lc + 4*i + 3] = v.w;
        }
    }
    __syncthreads();

    // ---- factor: P -> L (lower), columns j ascending ----
    for (int j = 0; j < 64; ++j) {
        if (tid < 64) {
            const float d = sqrtf(P[j][j]);
            if (tid == j)      P[j][j]   = d;
            else if (tid > j)  P[tid][j] = P[tid][j] / d;
        }
        __syncthreads();
        // rank-1 update on strip q: P[r][m] -= P[r][j]*P[m][j], j < m <= r
        const float prj = P[r][j];
        float pm[16];
#pragma unroll
        for (int i = 0; i < 16; ++i) pm[i] = P[q * 16 + i][j];
#pragma unroll
        for (int i = 0; i < 16; ++i) {
            const int m = q * 16 + i;
            if (m > j && m <= r) P[r][m] -= prj * pm[i];
        }
        __syncthreads();
    }

    // ---- invert: W = L^{-1}, column-sweep forward substitution ----
    for (int t = tid; t < 4096; t += 256)
        W[t >> 6][t & 63] = ((t >> 6) == (t & 63)) ? 1.f : 0.f;
    __syncthreads();
    for (int j = 0; j < 64; ++j) {
        if (tid < 64) W[j][tid] = W[j][tid] / P[j][j];
        __syncthreads();
        // W[m][r] -= P[m][j] * W[j][r]  for m > j (strip q)
        const float wjc = W[j][r];
        float pm[16];
#pragma unroll
        for (int i = 0; i < 16; ++i) pm[i] = P[q * 16 + i][j];
#pragma unroll
        for (int i = 0; i < 16; ++i) {
            const int m = q * 16 + i;
            if (m > j) W[m][r] -= pm[i] * wjc;
        }
        __syncthreads();
    }

    // write back L (full rows; upper triangle untouched = original A values)
    {
        const int lr = tid >> 2, lc = (tid & 3) * 16;
#pragma unroll
        for (int i = 0; i < 4; ++i)
            *(float4*)(A + (size_t)(j0 + lr) * 512 + j0 + lc + 4*i) =
                make_float4(P[lr][lc + 4*i + 0], P[lr][lc + 4*i + 1],
                            P[lr][lc + 4*i + 2], P[lr][lc + 4*i + 3]);
    }
    float* Wo  = Winv  + ((size_t)b * 8 + k) * 64 * 64;
    float* WoT = WinvT + ((size_t)b * 8 + k) * 64 * 64;
    for (int t = tid; t < 4096; t += 256) {
        Wo[t]  = W[t >> 6][t & 63];
        WoT[t] = W[t & 63][t >> 6];
    }
}

// Panel TRSM via inverse: L[i0.., k] = A[i0.., k] @ W^T
__global__ __launch_bounds__(256)
void trsm_kernel(float* __restrict__ Aall, const float* __restrict__ WinvT, int k)
{
    __shared__ float St[BK][BM + 4];
    __shared__ float Wt[BK][BN + 4];
    float* A = Aall + (size_t)blockIdx.y * 512 * 512;
    const float* WT = WinvT + ((size_t)blockIdx.y * 8 + k) * 64 * 64;
    const int i0 = (k + 1 + blockIdx.x) * 64, p0 = k * 64;
    const int tid = threadIdx.x;
    const int li = tid >> 2, lk = (tid & 3) << 2;
    const int wk = tid >> 4, wq = (tid & 15) << 2;
    const int ty = tid >> 4, tx = tid & 15;
    float acc[4][4] = {};
    for (int k0 = 0; k0 < 64; k0 += BK) {
        const float4 u = *(const float4*)(A + (size_t)(i0 + li) * 512 + p0 + k0 + lk);
        St[lk + 0][li] = u.x; St[lk + 1][li] = u.y;
        St[lk + 2][li] = u.z; St[lk + 3][li] = u.w;
        *(float4*)&Wt[wk][wq] = *(const float4*)(WT + (size_t)(k0 + wk) * 64 + wq);
        __syncthreads();
        MICRO(St, Wt);
        __syncthreads();
    }
#pragma unroll
    for (int a = 0; a < 4; ++a) {
        const int r = i0 + (ty << 2) + a;
        *(float4*)(A + (size_t)r * 512 + p0 + (tx << 2)) =
            make_float4(acc[a][0], acc[a][1], acc[a][2], acc[a][3]);
    }
}

// Trailing update: A[ti,tj] -= L[ti,k] L[tj,k]^T
__global__ __launch_bounds__(256)
void chol_trailing_kernel(float* __restrict__ Aall, int k)
{
    __shared__ float Ut[BK][BM + 4];
    __shared__ float Vt[BK][BN + 4];
    float* A = Aall + (size_t)blockIdx.y * 512 * 512;
    const int tid = threadIdx.x;
    int a = 0, rem = (int)blockIdx.x;
    while (rem >= a + 1) { rem -= a + 1; ++a; }
    const int ti = k + 1 + a, tj = k + 1 + rem;
    const int i0 = ti * 64, j0c = tj * 64, p0 = k * 64;

    const int li = tid >> 2, lk = (tid & 3) << 2;
    const int ty = tid >> 4, tx = tid & 15;
    float acc[4][4] = {};

    for (int k0 = 0; k0 < 64; k0 += BK) {
        const float4 u = *(const float4*)(A + (size_t)(i0 + li) * 512 + p0 + k0 + lk);
        const float4 v = *(const float4*)(A + (size_t)(j0c + li) * 512 + p0 + k0 + lk);
        Ut[lk + 0][li] = u.x; Ut[lk + 1][li] = u.y;
        Ut[lk + 2][li] = u.z; Ut[lk + 3][li] = u.w;
        Vt[lk + 0][li] = v.x; Vt[lk + 1][li] = v.y;
        Vt[lk + 2][li] = v.z; Vt[lk + 3][li] = v.w;
        __syncthreads();
        MICRO(Ut, Vt);
        __syncthreads();
    }
#pragma unroll
    for (int aa = 0; aa < 4; ++aa) {
        const int r = i0 + (ty << 2) + aa;
        float* crow = A + (size_t)r * 512 + j0c + (tx << 2);
        float4 cv = *(const float4*)crow;
        cv.x -= acc[aa][0]; cv.y -= acc[aa][1];
        cv.z -= acc[aa][2]; cv.w -= acc[aa][3];
        *(float4*)crow = cv;
    }
}

// Blocked fwd+bwd solve, v4b: 256 blocks (32 batches x 8 col-splits), 256
// THREADS per block (thread = 1 output row x 2 cols), XCD-colocated (b = blk
// & 31). Every GEMV segment is software-pipelined 4 chunks deep with NAMED
// buffers p0..p3 (static indexing; all segment chunk counts are multiples of
// 4). FIX vs v4: diag solves use CONTIGUOUS rows, so fwd needs Winv rows
// (W[ty][m]) and bwd needs WinvT rows (W[m][ty]) -- v4 had them swapped.
// Per-element accumulation order identical to v3 -> same numerics.
__global__ __launch_bounds__(256, 1)
void fb_solve4_kernel(const float* __restrict__ Aall,
                      const float* __restrict__ Winv,
                      const float* __restrict__ WinvT,
                      const float* __restrict__ Y, float* __restrict__ Zall)
{
    __shared__ float V[512][10];   // 8 used cols + 2 pad
    __shared__ float U[64][10];
    const int tid = threadIdx.x;
    const int b   = (int)blockIdx.x & 31;          // batch -> XCD (b mod 8)
    const int c0  = ((int)blockIdx.x >> 5) * 8;    // col-split
    const int ty  = tid >> 2;            // 0..63: output row within k-block
    const int tx  = tid & 3;             // col pair: cols 2tx, 2tx+1
    const float* A   = Aall + (size_t)b * 512 * 512;
    const float* Yb  = Y    + (size_t)b * 512 * OUTd + c0;
    float*       Zb  = Zall + (size_t)b * 512 * OUTd + c0;
    const float* Wb  = Winv  + (size_t)b * 8 * 4096 + (size_t)ty * 64;
    const float* WbT = WinvT + (size_t)b * 8 * 4096 + (size_t)ty * 64;

    for (int t = tid; t < 512 * 4; t += 256) {
        const int row = t >> 2, p = (t & 3) * 2;
        *(float2*)&V[row][p] = *(const float2*)&Yb[(size_t)row * OUTd + p];
    }
    __syncthreads();

    float acc0, acc1;
    f32x4 p0[4], p1[4], p2[4], p3[4];

// fwd chunk c (16 k-values) from row (r0+ty): contiguous f32x4 loads.
#define LDF(P, c, G)                                                            \
    { const int cc_ = ((c) < (G)) ? (c) : (G) - 1;                              \
      _Pragma("unroll") for (int j_ = 0; j_ < 4; ++j_)                          \
        P[j_] = *(const f32x4*)&Arow[16 * cc_ + 4 * j_]; }

// bwd chunk c: column (r0+ty) of rows m1+16c.. (scalar strided loads).
#define LDB(P, c, G)                                                            \
    { const int cc_ = ((c) < (G)) ? (c) : (G) - 1;                              \
      _Pragma("unroll") for (int j_ = 0; j_ < 16; ++j_)                         \
        P[j_ >> 2][j_ & 3] = Acol[(size_t)(m1 + 16 * cc_ + j_) * 512]; }

// acc += P . V[kb .. kb+15][2tx..2tx+1]
#define CMPV(P, kb)                                                             \
    { _Pragma("unroll") for (int q_ = 0; q_ < 16; ++q_) {                       \
        const float a_ = P[q_ >> 2][q_ & 3];                                    \
        const float2 v_ = *(const float2*)&V[(kb) + q_][2 * tx];                \
        acc0 += a_ * v_.x; acc1 += a_ * v_.y; } }

// acc += P . U[kb .. kb+15][2tx..2tx+1]
#define CMPU(P, kb)                                                             \
    { _Pragma("unroll") for (int q_ = 0; q_ < 16; ++q_) {                       \
        const float a_ = P[q_ >> 2][q_ & 3];                                    \
        const float2 v_ = *(const float2*)&U[(kb) + q_][2 * tx];                \
        acc0 += a_ * v_.x; acc1 += a_ * v_.y; } }

// diag solve: out[ty][c] = sum_m Wrow[m] * U[m][c], m ascending (4 chunks)
#define DIAG(Wrow)                                                              \
    { acc0 = 0.f; acc1 = 0.f;                                                   \
      _Pragma("unroll") for (int j_ = 0; j_ < 4; ++j_) {                        \
        p0[j_] = *(const f32x4*)&(Wrow)[ 0 + 4 * j_];                           \
        p1[j_] = *(const f32x4*)&(Wrow)[16 + 4 * j_];                           \
        p2[j_] = *(const f32x4*)&(Wrow)[32 + 4 * j_];                           \
        p3[j_] = *(const f32x4*)&(Wrow)[48 + 4 * j_]; }                         \
      CMPU(p0, 0); CMPU(p1, 16); CMPU(p2, 32); CMPU(p3, 48); }

    // ---- forward: V_k = W_k (Y_k - L[k, 0:64k] @ V) ----
    for (int k = 0; k < 8; ++k) {
        const int r0 = k * 64;
        const float* Arow = A + (size_t)(r0 + ty) * 512;
        acc0 = 0.f; acc1 = 0.f;
        const int G = r0 >> 4;                   // chunks; multiple of 4
        if (G) {
            LDF(p0, 0, G); LDF(p1, 1, G); LDF(p2, 2, G); LDF(p3, 3, G);
            for (int g = 0; g < G; g += 4) {
                CMPV(p0, 16 * g);      LDF(p0, g + 4, G);
                CMPV(p1, 16 * g + 16); LDF(p1, g + 5, G);
                CMPV(p2, 16 * g + 32); LDF(p2, g + 6, G);
                CMPV(p3, 16 * g + 48); LDF(p3, g + 7, G);
            }
        }
        U[ty][2 * tx]     = V[r0 + ty][2 * tx]     - acc0;
        U[ty][2 * tx + 1] = V[r0 + ty][2 * tx + 1] - acc1;
        __syncthreads();
        DIAG(Wb + (size_t)k * 4096);             // Winv row ty = W[ty][m]
        V[r0 + ty][2 * tx]     = acc0;
        V[r0 + ty][2 * tx + 1] = acc1;
        __syncthreads();
    }

    // ---- backward: Z_k = W_k^T (V_k - L[64(k+1):, k]^T @ Z) ----
    for (int k = 7; k >= 0; --k) {
        const int r0 = k * 64;
        const float* Acol = A + r0 + ty;
        const int m1 = r0 + 64;
        acc0 = 0.f; acc1 = 0.f;
        const int G = (448 - r0) >> 4;           // chunks; multiple of 4
        if (G) {
            LDB(p0, 0, G); LDB(p1, 1, G); LDB(p2, 2, G); LDB(p3, 3, G);
            for (int g = 0; g < G; g += 4) {
                CMPV(p0, m1 + 16 * g);      LDB(p0, g + 4, G);
                CMPV(p1, m1 + 16 * g + 16); LDB(p1, g + 5, G);
                CMPV(p2, m1 + 16 * g + 32); LDB(p2, g + 6, G);
                CMPV(p3, m1 + 16 * g + 48); LDB(p3, g + 7, G);
            }
        }
        U[ty][2 * tx]     = V[r0 + ty][2 * tx]     - acc0;
        U[ty][2 * tx + 1] = V[r0 + ty][2 * tx + 1] - acc1;
        __syncthreads();
        DIAG(WbT + (size_t)k * 4096);            // WinvT row ty = W[m][ty]
        V[r0 + ty][2 * tx]     = acc0;
        V[r0 + ty][2 * tx + 1] = acc1;
        __syncthreads();
    }

    for (int t = tid; t < 512 * 4; t += 256) {
        const int row = t >> 2, p = (t & 3) * 2;
        *(float2*)&Zb[(size_t)row * OUTd + p] = *(const float2*)&V[row][p];
    }
#undef LDF
#undef LDB
#undef CMPV
#undef CMPU
#undef DIAG
}

// w[b] = RS_b^T @ Z_b, RS reconstructed as h+l.
__global__ __launch_bounds__(256)
void out_kernel(const u16* __restrict__ Sh, const u16* __restrict__ Sl,
                const float* __restrict__ Z, float* __restrict__ Wout)
{
    __shared__ float Rt[BK][64 + 4];
    __shared__ float Zt[BK][64 + 4];
    const int tid = threadIdx.x;
    const int b   = blockIdx.y;
    const int d0  = blockIdx.x * 64;
    const int kk  = tid >> 4, cq = (tid & 15) << 2;
    const int ty  = tid >> 4, tx = tid & 15;
    float acc[4][4] = {};

    for (int k0 = 0; k0 < Tt; k0 += BK) {
        const size_t ri = (size_t)(b * Tt + k0 + kk) * RES + d0 + cq;
        const u16x4 hv = *(const u16x4*)&Sh[ri];
        const u16x4 lv = *(const u16x4*)&Sl[ri];
        Rt[kk][cq + 0] = bf2f(hv[0]) + bf2f(lv[0]);
        Rt[kk][cq + 1] = bf2f(hv[1]) + bf2f(lv[1]);
        Rt[kk][cq + 2] = bf2f(hv[2]) + bf2f(lv[2]);
        Rt[kk][cq + 3] = bf2f(hv[3]) + bf2f(lv[3]);
        *(float4*)&Zt[kk][cq] =
            *(const float4*)(Z + ((size_t)b * Tt + k0 + kk) * OUTd + cq);
        __syncthreads();
        MICRO(Rt, Zt);
        __syncthreads();
    }
#pragma unroll
    for (int a = 0; a < 4; ++a) {
        const int d = d0 + (ty << 2) + a;
        *(float4*)(Wout + ((size_t)b * RES + d) * OUTd + (tx << 2)) =
            make_float4(acc[a][0], acc[a][1], acc[a][2], acc[a][3]);
    }
}

__global__ __launch_bounds__(64)
void bias_kernel(const float* __restrict__ Z, float* __restrict__ Bout)
{
    const int b = blockIdx.x, o = threadIdx.x;
    const float* Zb = Z + (size_t)b * Tt * OUTd;
    float s = 0.f;
    for (int n = 0; n < Tt; ++n) s += Zb[(size_t)n * OUTd + o];
    Bout[(size_t)b * OUTd + o] = s;
}

extern "C" void kernel_launch(void* const* d_in, const int* in_sizes, int n_in,
                              void* d_out, int out_size, void* d_ws, size_t ws_size,
                              hipStream_t stream)
{
    const float* X    = (const float*)d_in[0];   // (32,512,128)
    const float* Y    = (const float*)d_in[1];   // (32,512,64)
    const float* Wres = (const float*)d_in[2];   // (2048,2048)
    const float* Win  = (const float*)d_in[3];   // (128,2048)
    const float* lam  = (const float*)d_in[4];   // scalar

    float* out  = (float*)d_out;
    float* Wout = out;
    float* Bout = out + (size_t)Bb * RES * OUTd;

    // ws: Sh 64 | Sl 64 | WTh 8 | WTl 8 | WinTh .5 | WinTl .5 | A 32 | Z 4 | Wi 4 | WiT 4 = 189 MB
    char* p = (char*)d_ws;
    u16* Sh    = (u16*)p;   p += (size_t)Bb * Tt * RES * 2;
    u16* Sl    = (u16*)p;   p += (size_t)Bb * Tt * RES * 2;
    u16* WTh   = (u16*)p;   p += (size_t)RES * RES * 2;
    u16* WTl   = (u16*)p;   p += (size_t)RES * RES * 2;
    u16* WinTh = (u16*)p;   p += (size_t)INd * RES * 2;
    u16* WinTl = (u16*)p;   p += (size_t)INd * RES * 2;
    float* A   = (float*)p; p += (size_t)Bb * 512 * 512 * 4;
    float* Z   = (float*)p; p += (size_t)Bb * Tt * OUTd * 4;
    float* Wi  = (float*)p; p += (size_t)Bb * 8 * 64 * 64 * 4;
    float* WiT = (float*)p;

    const dim3 blk(256);
    tconv_kernel<<<dim3(RES / 64, RES / 64), blk, 0, stream>>>(Wres, WTh, WTl, RES, RES);
    tconv_kernel<<<dim3(RES / 64, INd / 64), blk, 0, stream>>>(Win, WinTh, WinTl, INd, RES);

    // classes: s:(cin->cout) 0:(-,2) 1:(2,1) 2:(1,0) 3:(0,1) 4:(1,2) 5:(2,3)
    const dim3 sgrid(RES / 128, Bb);
    step_mfma_kernel<<<sgrid, blk, 0, stream>>>(Sh, Sl, X, WTh, WTl, WinTh, WinTl, 0, 2, 0);
    step_mfma_kernel<<<sgrid, blk, 0, stream>>>(Sh, Sl, X, WTh, WTl, WinTh, WinTl, 2, 1, 1);
    step_mfma_kernel<<<sgrid, blk, 0, stream>>>(Sh, Sl, X, WTh, WTl, WinTh, WinTl, 1, 0, 2);
    step_mfma_kernel<<<sgrid, blk, 0, stream>>>(Sh, Sl, X, WTh, WTl, WinTh, WinTl, 0, 1, 3);
    step_mfma_kernel<<<sgrid, blk, 0, stream>>>(Sh, Sl, X, WTh, WTl, WinTh, WinTl, 1, 2, 4);
    step_mfma_kernel<<<sgrid, blk, 0, stream>>>(Sh, Sl, X, WTh, WTl, WinTh, WinTl, 2, 3, 5);

    gram_mfma_kernel<<<dim3(10, Bb), blk, 0, stream>>>(Sh, Sl, A, lam);

    for (int k = 0; k < 8; ++k) {
        chol_diag_inv_kernel<<<dim3(Bb), dim3(256), 0, stream>>>(A, Wi, WiT, k);
        if (k < 7) {
            trsm_kernel<<<dim3(7 - k, Bb), blk, 0, stream>>>(A, WiT, k);
            const int m = 7 - k;
            chol_trailing_kernel<<<dim3(m * (m + 1) / 2, Bb), blk, 0, stream>>>(A, k);
        }
    }
    fb_solve4_kernel<<<dim3(Bb * 8), dim3(256), 0, stream>>>(A, Wi, WiT, Y, Z);

    out_kernel<<<dim3(RES / 64, Bb), blk, 0, stream>>>(Sh, Sl, Z, Wout);
    bias_kernel<<<dim3(Bb), dim3(OUTd), 0, stream>>>(Z, Bout);
}

// Round 9
// 2043.668 us; speedup vs baseline: 1.3834x; 1.0335x over previous
//
#include <hip/hip_runtime.h>
#include <cmath>

#define Bb   32
#define Tt   512
#define INd  128
#define RES  2048
#define OUTd 64

#define BM 64
#define BN 64
#define BK 16

typedef unsigned short u16;
typedef __attribute__((ext_vector_type(4))) unsigned short u16x4;
typedef __attribute__((ext_vector_type(8))) unsigned short u16x8;
typedef __attribute__((ext_vector_type(8))) short bf8;
typedef __attribute__((ext_vector_type(4))) float f32x4;

// fp32 = bf16 hi (RNE) + bf16 lo (trunc residual); |err| <= 2^-17 |a|
__device__ __forceinline__ void splitf(float a, u16& h, u16& l) {
    unsigned u = __float_as_uint(a);
    unsigned r = (u + 0x7fffu + ((u >> 16) & 1u)) & 0xffff0000u;
    h = (u16)(r >> 16);
    float d = a - __uint_as_float(r);
    l = (u16)(__float_as_uint(d) >> 16);
}
__device__ __forceinline__ float bf2f(u16 h) {
    return __uint_as_float((unsigned)h << 16);
}
__device__ __forceinline__ void split8(const float4& a, const float4& b,
                                       u16x8& h, u16x8& l) {
    u16 hh, ll;
    splitf(a.x, hh, ll); h[0] = hh; l[0] = ll;
    splitf(a.y, hh, ll); h[1] = hh; l[1] = ll;
    splitf(a.z, hh, ll); h[2] = hh; l[2] = ll;
    splitf(a.w, hh, ll); h[3] = hh; l[3] = ll;
    splitf(b.x, hh, ll); h[4] = hh; l[4] = ll;
    splitf(b.y, hh, ll); h[5] = hh; l[5] = ll;
    splitf(b.z, hh, ll); h[6] = hh; l[6] = ll;
    splitf(b.w, hh, ll); h[7] = hh; l[7] = ll;
}

// async global->LDS, 16B per lane. LDS dest is wave-uniform base + lane*16;
// global src is per-lane (carries the chunk swizzle).
__device__ __forceinline__ void gl_lds16(const u16* g, u16* l) {
    __builtin_amdgcn_global_load_lds(
        (const __attribute__((address_space(1))) unsigned int*)g,
        (__attribute__((address_space(3))) unsigned int*)l,
        16, 0, 0);
}

#define MICRO(SA, SB)                                                           \
  do {                                                                          \
    _Pragma("unroll")                                                           \
    for (int kk = 0; kk < BK; ++kk) {                                           \
      const float4 a4 = *(const float4*)&SA[kk][ty << 2];                       \
      const float4 b4 = *(const float4*)&SB[kk][tx << 2];                       \
      acc[0][0] += a4.x*b4.x; acc[0][1] += a4.x*b4.y;                           \
      acc[0][2] += a4.x*b4.z; acc[0][3] += a4.x*b4.w;                           \
      acc[1][0] += a4.y*b4.x; acc[1][1] += a4.y*b4.y;                           \
      acc[1][2] += a4.y*b4.z; acc[1][3] += a4.y*b4.w;                           \
      acc[2][0] += a4.z*b4.x; acc[2][1] += a4.z*b4.y;                           \
      acc[2][2] += a4.z*b4.z; acc[2][3] += a4.z*b4.w;                           \
      acc[3][0] += a4.w*b4.x; acc[3][1] += a4.w*b4.y;                           \
      acc[3][2] += a4.w*b4.z; acc[3][3] += a4.w*b4.w;                           \
    }                                                                           \
  } while (0)

// 128x128 tile, K=32 slice, bf16x3. Linear LDS rows of 32 u16 (64 B) with
// 16B-chunk XOR swizzle c' = c ^ ((row>>1)&3)  ->  max 2-way bank alias (free).
// Buffer layout (u16 offsets): Ah 0 | Al 4096 | Bh 8192 | Bl 12288.
#define MFMA_TILE(BUF)                                                           \
  do {                                                                           \
    bf8 aH[4], aL[4], bH[4], bL[4];                                              \
    const int qd = (quad ^ ((l15 >> 1) & 3)) << 3;                               \
    _Pragma("unroll")                                                            \
    for (int i = 0; i < 4; ++i) {                                                \
      const int ar = (wm*64 + i*16 + l15)*32 + qd;                               \
      const int br = (wn*64 + i*16 + l15)*32 + qd;                               \
      aH[i] = *(const bf8*)&(BUF)[ar];                                           \
      aL[i] = *(const bf8*)&(BUF)[4096 + ar];                                    \
      bH[i] = *(const bf8*)&(BUF)[8192 + br];                                    \
      bL[i] = *(const bf8*)&(BUF)[12288 + br];                                   \
    }                                                                            \
    _Pragma("unroll")                                                            \
    for (int i = 0; i < 4; ++i)                                                  \
      _Pragma("unroll")                                                          \
      for (int j = 0; j < 4; ++j) {                                              \
        acc[i][j] = __builtin_amdgcn_mfma_f32_16x16x32_bf16(aH[i], bH[j], acc[i][j], 0, 0, 0); \
        acc[i][j] = __builtin_amdgcn_mfma_f32_16x16x32_bf16(aH[i], bL[j], acc[i][j], 0, 0, 0); \
        acc[i][j] = __builtin_amdgcn_mfma_f32_16x16x32_bf16(aL[i], bH[j], acc[i][j], 0, 0, 0); \
      }                                                                          \
  } while (0)

// Transpose + split weights: in (K x N fp32) -> outH/outL (N x K bf16).
__global__ __launch_bounds__(256)
void tconv_kernel(const float* __restrict__ in, u16* __restrict__ outH,
                  u16* __restrict__ outL, int K, int N)
{
    __shared__ float T[64][65];
    const int n0 = blockIdx.x * 64, k0 = blockIdx.y * 64;
    const int t = threadIdx.x;
    const int r = t >> 2, c0 = (t & 3) * 16;
#pragma unroll
    for (int i = 0; i < 4; ++i) {
        const float4 v = *(const float4*)&in[(size_t)(k0 + r) * N + n0 + c0 + 4*i];
        T[r][c0 + 4*i + 0] = v.x; T[r][c0 + 4*i + 1] = v.y;
        T[r][c0 + 4*i + 2] = v.z; T[r][c0 + 4*i + 3] = v.w;
    }
    __syncthreads();
    const int n = t >> 2, ck = (t & 3) * 16;
    u16x8 h0, h1, l0, l1;
#pragma unroll
    for (int i = 0; i < 8; ++i) { u16 h, l; splitf(T[ck + i][n], h, l); h0[i] = h; l0[i] = l; }
#pragma unroll
    for (int i = 0; i < 8; ++i) { u16 h, l; splitf(T[ck + 8 + i][n], h, l); h1[i] = h; l1[i] = l; }
    const size_t ob = (size_t)(n0 + n) * K + k0 + ck;
    *(u16x8*)&outH[ob] = h0; *(u16x8*)&outH[ob + 8] = h1;
    *(u16x8*)&outL[ob] = l0; *(u16x8*)&outL[ob + 8] = l1;
}

// Reservoir step on bf16 hi/lo state planes (row = b*512 + 4w + class).
// v2 (replay-verified) staging: global_load_lds into double-buffered 32-KB
// slice buffers, __syncthreads-delimited (raw-barrier pipeline REVERTED:
// raced under graph replay, R8). NEW: bijective XCD block swizzle -- flat id
// bits {b0,b3,b4,b5}->col-tile, {b1,b2,b6,b7,b8}->batch, so XCD (flat%8) is
// (tile bit0, batch bits0-1): state-panel duplication drops 8x->2x, W-tile
// duplication 1x->4x; net FETCH ~286MB -> ~150MB per dispatch.
__global__ __launch_bounds__(256)
void step_mfma_kernel(u16* __restrict__ Sh, u16* __restrict__ Sl,
                      const float* __restrict__ X,
                      const u16* __restrict__ WTh, const u16* __restrict__ WTl,
                      const u16* __restrict__ WinTh, const u16* __restrict__ WinTl,
                      int cin, int cout, int s)
{
    __shared__ u16 LB[2 * 16384];             // 2 x 32 KB slice buffers
    u16* buf0 = LB;
    u16* buf1 = LB + 16384;
    float* Cf = (float*)LB;                   // 64x128 f32 = 32 KB (epilogue)

    const int tid = threadIdx.x;
    // bijective 9-bit remap of (blockIdx.x, blockIdx.y) = (16, 32)
    const int f  = (int)blockIdx.x + ((int)blockIdx.y << 4);
    const int bx = (f & 1) | (((f >> 3) & 7) << 1);          // 0..15
    const int by = ((f >> 1) & 3) | (((f >> 6) & 7) << 2);   // 0..31
    const int q0  = bx * 128;                 // reservoir-col tile
    const int b   = by;
    const int bofs = b * Tt;
    const int wid = tid >> 6, lane = tid & 63;
    const int wm = wid & 1, wn = wid >> 1;
    const int l15 = lane & 15, quad = lane >> 4;

    f32x4 acc[4][4];
    const f32x4 zz = {0.f, 0.f, 0.f, 0.f};
#pragma unroll
    for (int i = 0; i < 4; ++i)
#pragma unroll
        for (int j = 0; j < 4; ++j) acc[i][j] = zz;

    // per-wave slice staging: wid 0=Ah(Sh) 1=Al(Sl) 2=Bh(WTh) 3=Bl(WTl).
    // lane l covers row r = i*16 + (l>>2), dest chunk l&3; source chunk is
    // pre-swizzled: csrc = (l&3) ^ ((l>>3)&3)  (== (l&3) ^ ((r>>1)&3)).
    const int rl    = lane >> 2;
    const int csrc  = (((lane & 3) ^ ((lane >> 3) & 3)) << 3);
    const u16* plane = (wid == 0) ? (const u16*)Sh
                     : (wid == 1) ? (const u16*)Sl
                     : (wid == 2) ? WTh : WTl;

    auto stage = [&](u16* buf, int k0) {
        u16* ldst = buf + wid * 4096;
#pragma unroll
        for (int i = 0; i < 8; ++i) {
            const int r = i * 16 + rl;
            const size_t grow = (wid < 2) ? (size_t)(bofs + 4 * r + cin)
                                          : (size_t)(q0 + r);
            gl_lds16(&plane[grow * RES + k0 + csrc], ldst + i * 512);
        }
    };

    if (s > 0) {
        stage(buf0, 0);
        __syncthreads();                      // drains vmcnt -> buf0 ready
        for (int k0 = 0; k0 < RES; k0 += 32) {
            u16* cur = (k0 & 32) ? buf1 : buf0;
            u16* nxt = (k0 & 32) ? buf0 : buf1;
            if (k0 + 32 < RES) stage(nxt, k0 + 32);
            MFMA_TILE(cur);
            __syncthreads();                  // nxt staged; cur reads done
        }
    }

    // input projection: K=128 over x[b, 4w+s-2, :] @ Win.
    // waves 0,1: compute A rows (splitf) + swizzled ds_write; waves 2,3: gload B.
    for (int k0 = 0; k0 < INd; k0 += 32) {
        if (tid < 128) {
            const int rrow = tid;             // 0..127
            const int t = 4 * rrow + s - 2;
            u16x8 h0 = {0,0,0,0,0,0,0,0}, h1 = h0, h2 = h0, h3 = h0;
            u16x8 l0 = h0, l1 = h0, l2 = h0, l3 = h0;
            if (t >= 0) {
                const float* xr = X + (size_t)(bofs + t) * INd + k0;
                const float4 f0 = *(const float4*)&xr[0];
                const float4 f1 = *(const float4*)&xr[4];
                const float4 f2 = *(const float4*)&xr[8];
                const float4 f3 = *(const float4*)&xr[12];
                const float4 f4 = *(const float4*)&xr[16];
                const float4 f5 = *(const float4*)&xr[20];
                const float4 f6 = *(const float4*)&xr[24];
                const float4 f7 = *(const float4*)&xr[28];
                split8(f0, f1, h0, l0); split8(f2, f3, h1, l1);
                split8(f4, f5, h2, l2); split8(f6, f7, h3, l3);
            }
            const int sw = (rrow >> 1) & 3;
            u16* dA = buf0 + rrow * 32;
            *(u16x8*)&dA[(0 ^ sw) << 3] = h0;
            *(u16x8*)&dA[(1 ^ sw) << 3] = h1;
            *(u16x8*)&dA[(2 ^ sw) << 3] = h2;
            *(u16x8*)&dA[(3 ^ sw) << 3] = h3;
            u16* dL = buf0 + 4096 + rrow * 32;
            *(u16x8*)&dL[(0 ^ sw) << 3] = l0;
            *(u16x8*)&dL[(1 ^ sw) << 3] = l1;
            *(u16x8*)&dL[(2 ^ sw) << 3] = l2;
            *(u16x8*)&dL[(3 ^ sw) << 3] = l3;
        } else {
            const u16* wpl = (wid == 2) ? WinTh : WinTl;
            u16* ldst = buf0 + wid * 4096;
#pragma unroll
            for (int i = 0; i < 8; ++i) {
                const int r = i * 16 + rl;
                gl_lds16(&wpl[(size_t)(q0 + r) * INd + k0 + csrc], ldst + i * 512);
            }
        }
        __syncthreads();
        MFMA_TILE(buf0);
        __syncthreads();
    }

    // epilogue via LDS: all global I/O is coalesced u16x8.
    for (int h = 0; h < 2; ++h) {
        __syncthreads();
        if (wm == h) {
#pragma unroll
            for (int i = 0; i < 4; ++i)
#pragma unroll
                for (int j = 0; j < 4; ++j)
#pragma unroll
                    for (int rg = 0; rg < 4; ++rg)
                        Cf[(i * 16 + quad * 4 + rg) * 128 + wn * 64 + j * 16 + l15]
                            = acc[i][j][rg];
        }
        __syncthreads();
#pragma unroll
        for (int pass = 0; pass < 4; ++pass) {
            const int r  = (tid >> 4) + pass * 16;      // 0..63
            const int c0 = (tid & 15) * 8;              // 0..120
            const int wrow = h * 64 + r;
            const float4 v0 = *(const float4*)&Cf[r * 128 + c0];
            const float4 v1 = *(const float4*)&Cf[r * 128 + c0 + 4];
            float vv[8] = {v0.x, v0.y, v0.z, v0.w, v1.x, v1.y, v1.z, v1.w};
            u16x8 ph, pl;
            if (s > 0) {
                const size_t prow = (size_t)(bofs + 4 * wrow + cin) * RES + q0 + c0;
                ph = *(const u16x8*)&Sh[prow];
                pl = *(const u16x8*)&Sl[prow];
            }
            u16x8 oh, ol;
#pragma unroll
            for (int e = 0; e < 8; ++e) {
                float prev = (s > 0) ? (bf2f(ph[e]) + bf2f(pl[e])) : 0.f;
                float v = 0.7f * prev + 0.3f * sinf(vv[e]);
                u16 hh, ll; splitf(v, hh, ll);
                oh[e] = hh; ol[e] = ll;
            }
            const size_t orow = (size_t)(bofs + 4 * wrow + cout) * RES + q0 + c0;
            *(u16x8*)&Sh[orow] = oh;
            *(u16x8*)&Sl[orow] = ol;
        }
    }
}

// Gram on bf16 planes: A[b] = (Sh+Sl)(Sh+Sl)^T + ones + reg*I, bf16x3.
// v2 (replay-verified): __syncthreads-delimited double-buffered staging.
__global__ __launch_bounds__(256)
void gram_mfma_kernel(const u16* __restrict__ Sh, const u16* __restrict__ Sl,
                      float* __restrict__ A, const float* __restrict__ lam)
{
    __shared__ u16 LB[2 * 16384];
    u16* buf0 = LB;
    u16* buf1 = LB + 16384;
    float* Cf = (float*)LB;                   // 64 x 132 f32 = 33.8 KB

    const int tid = threadIdx.x;
    const int bt  = blockIdx.y;
    int ti = 0, rem = (int)blockIdx.x;
    while (rem >= 4 - ti) { rem -= 4 - ti; ++ti; }
    const int tj = ti + rem;
    const int n0 = ti * 128, m0 = tj * 128;
    const int bofs = bt * Tt;

    const int wid = tid >> 6, lane = tid & 63;
    const int wm = wid & 1, wn = wid >> 1;
    const int l15 = lane & 15, quad = lane >> 4;

    f32x4 acc[4][4];
    const f32x4 zz = {0.f, 0.f, 0.f, 0.f};
#pragma unroll
    for (int i = 0; i < 4; ++i)
#pragma unroll
        for (int j = 0; j < 4; ++j) acc[i][j] = zz;

    const int rl    = lane >> 2;
    const int csrc  = (((lane & 3) ^ ((lane >> 3) & 3)) << 3);
    const u16* plane = (wid & 1) ? Sl : Sh;
    const int rbase  = (wid < 2) ? n0 : m0;

    auto stage = [&](u16* buf, int k0) {
        u16* ldst = buf + wid * 4096;
#pragma unroll
        for (int i = 0; i < 8; ++i) {
            const int r = i * 16 + rl;
            gl_lds16(&plane[(size_t)(bofs + rbase + r) * RES + k0 + csrc],
                     ldst + i * 512);
        }
    };

    stage(buf0, 0);
    __syncthreads();
    for (int k0 = 0; k0 < RES; k0 += 32) {
        u16* cur = (k0 & 32) ? buf1 : buf0;
        u16* nxt = (k0 & 32) ? buf0 : buf1;
        if (k0 + 32 < RES) stage(nxt, k0 + 32);
        MFMA_TILE(cur);
        __syncthreads();
    }

    const float reg = log1pf(expf(lam[0]));
    float* Ab = A + (size_t)bt * 512 * 512;
    for (int h = 0; h < 2; ++h) {
        __syncthreads();
        if (wm == h) {
#pragma unroll
            for (int i = 0; i < 4; ++i)
#pragma unroll
                for (int j = 0; j < 4; ++j)
#pragma unroll
                    for (int rg = 0; rg < 4; ++rg)
                        Cf[(i * 16 + quad * 4 + rg) * 132 + wn * 64 + j * 16 + l15]
                            = acc[i][j][rg];
        }
        __syncthreads();
        // row-major half: rows nn = n0+h*64+r, cols m0..m0+127
#pragma unroll
        for (int pass = 0; pass < 4; ++pass) {
            const int r  = (tid >> 4) + pass * 16;
            const int c0 = (tid & 15) * 8;
            const int nn = n0 + h * 64 + r;
            float o[8];
#pragma unroll
            for (int e = 0; e < 8; ++e) {
                const int mm = m0 + c0 + e;
                float v = Cf[r * 132 + c0 + e] + 1.0f;
                if (nn == mm) v += reg;
                o[e] = v;
            }
            float* dst = Ab + (size_t)nn * 512 + m0 + c0;
            *(float4*)&dst[0] = make_float4(o[0], o[1], o[2], o[3]);
            *(float4*)&dst[4] = make_float4(o[4], o[5], o[6], o[7]);
        }
        // transposed half: rows mm = m0+rt, cols n0+h*64 .. +63
#pragma unroll
        for (int pass = 0; pass < 4; ++pass) {
            const int rt  = (tid >> 3) + pass * 32;     // 0..127
            const int c0t = (tid & 7) * 8;              // 0..56
            const int mm  = m0 + rt;
            float o[8];
#pragma unroll
            for (int e = 0; e < 8; ++e) {
                const int nn = n0 + h * 64 + c0t + e;
                float v = Cf[(c0t + e) * 132 + rt] + 1.0f;
                if (nn == mm) v += reg;
                o[e] = v;
            }
            float* dst = Ab + (size_t)mm * 512 + n0 + h * 64 + c0t;
            *(float4*)&dst[0] = make_float4(o[0], o[1], o[2], o[3]);
            *(float4*)&dst[4] = make_float4(o[4], o[5], o[6], o[7]);
        }
    }
}

// Diag-block Cholesky (64x64) + inverse, v2: 256 threads / 4 waves per batch.
__global__ __launch_bounds__(256)
void chol_diag_inv_kernel(float* __restrict__ Aall, float* __restrict__ Winv,
                          float* __restrict__ WinvT, int k)
{
    __shared__ float P[64][65];
    __shared__ float W[64][65];
    const int b = blockIdx.x, tid = threadIdx.x;
    float* A = Aall + (size_t)b * 512 * 512;
    const int j0 = 64 * k;
    const int r = tid & 63;          // row (factor) / RHS column (inverse)
    const int q = tid >> 6;          // 16-wide column strip

    // load 64x64 (each thread 16 floats)
    {
        const int lr = tid >> 2, lc = (tid & 3) * 16;
#pragma unroll
        for (int i = 0; i < 4; ++i) {
            const float4 v = *(const float4*)(A + (size_t)(j0 + lr) * 512 + j0 + lc + 4*i);
            P[lr][lc + 4*i + 0] = v.x; P[lr][lc + 4*i + 1] = v.y;
            P[lr][lc + 4*i + 2] = v.z; P[lr][lc + 4*i + 3] = v.w;
        }
    }
    __syncthreads();

    // ---- factor: P -> L (lower), columns j ascending ----
    for (int j = 0; j < 64; ++j) {
        if (tid < 64) {
            const float d = sqrtf(P[j][j]);
            if (tid == j)      P[j][j]   = d;
            else if (tid > j)  P[tid][j] = P[tid][j] / d;
        }
        __syncthreads();
        // rank-1 update on strip q: P[r][m] -= P[r][j]*P[m][j], j < m <= r
        const float prj = P[r][j];
        float pm[16];
#pragma unroll
        for (int i = 0; i < 16; ++i) pm[i] = P[q * 16 + i][j];
#pragma unroll
        for (int i = 0; i < 16; ++i) {
            const int m = q * 16 + i;
            if (m > j && m <= r) P[r][m] -= prj * pm[i];
        }
        __syncthreads();
    }

    // ---- invert: W = L^{-1}, column-sweep forward substitution ----
    for (int t = tid; t < 4096; t += 256)
        W[t >> 6][t & 63] = ((t >> 6) == (t & 63)) ? 1.f : 0.f;
    __syncthreads();
    for (int j = 0; j < 64; ++j) {
        if (tid < 64) W[j][tid] = W[j][tid] / P[j][j];
        __syncthreads();
        // W[m][r] -= P[m][j] * W[j][r]  for m > j (strip q)
        const float wjc = W[j][r];
        float pm[16];
#pragma unroll
        for (int i = 0; i < 16; ++i) pm[i] = P[q * 16 + i][j];
#pragma unroll
        for (int i = 0; i < 16; ++i) {
            const int m = q * 16 + i;
            if (m > j) W[m][r] -= pm[i] * wjc;
        }
        __syncthreads();
    }

    // write back L (full rows; upper triangle untouched = original A values)
    {
        const int lr = tid >> 2, lc = (tid & 3) * 16;
#pragma unroll
        for (int i = 0; i < 4; ++i)
            *(float4*)(A + (size_t)(j0 + lr) * 512 + j0 + lc + 4*i) =
                make_float4(P[lr][lc + 4*i + 0], P[lr][lc + 4*i + 1],
                            P[lr][lc + 4*i + 2], P[lr][lc + 4*i + 3]);
    }
    float* Wo  = Winv  + ((size_t)b * 8 + k) * 64 * 64;
    float* WoT = WinvT + ((size_t)b * 8 + k) * 64 * 64;
    for (int t = tid; t < 4096; t += 256) {
        Wo[t]  = W[t >> 6][t & 63];
        WoT[t] = W[t & 63][t >> 6];
    }
}

// Panel TRSM via inverse: L[i0.., k] = A[i0.., k] @ W^T
__global__ __launch_bounds__(256)
void trsm_kernel(float* __restrict__ Aall, const float* __restrict__ WinvT, int k)
{
    __shared__ float St[BK][BM + 4];
    __shared__ float Wt[BK][BN + 4];
    float* A = Aall + (size_t)blockIdx.y * 512 * 512;
    const float* WT = WinvT + ((size_t)blockIdx.y * 8 + k) * 64 * 64;
    const int i0 = (k + 1 + blockIdx.x) * 64, p0 = k * 64;
    const int tid = threadIdx.x;
    const int li = tid >> 2, lk = (tid & 3) << 2;
    const int wk = tid >> 4, wq = (tid & 15) << 2;
    const int ty = tid >> 4, tx = tid & 15;
    float acc[4][4] = {};
    for (int k0 = 0; k0 < 64; k0 += BK) {
        const float4 u = *(const float4*)(A + (size_t)(i0 + li) * 512 + p0 + k0 + lk);
        St[lk + 0][li] = u.x; St[lk + 1][li] = u.y;
        St[lk + 2][li] = u.z; St[lk + 3][li] = u.w;
        *(float4*)&Wt[wk][wq] = *(const float4*)(WT + (size_t)(k0 + wk) * 64 + wq);
        __syncthreads();
        MICRO(St, Wt);
        __syncthreads();
    }
#pragma unroll
    for (int a = 0; a < 4; ++a) {
        const int r = i0 + (ty << 2) + a;
        *(float4*)(A + (size_t)r * 512 + p0 + (tx << 2)) =
            make_float4(acc[a][0], acc[a][1], acc[a][2], acc[a][3]);
    }
}

// Trailing update: A[ti,tj] -= L[ti,k] L[tj,k]^T
__global__ __launch_bounds__(256)
void chol_trailing_kernel(float* __restrict__ Aall, int k)
{
    __shared__ float Ut[BK][BM + 4];
    __shared__ float Vt[BK][BN + 4];
    float* A = Aall + (size_t)blockIdx.y * 512 * 512;
    const int tid = threadIdx.x;
    int a = 0, rem = (int)blockIdx.x;
    while (rem >= a + 1) { rem -= a + 1; ++a; }
    const int ti = k + 1 + a, tj = k + 1 + rem;
    const int i0 = ti * 64, j0c = tj * 64, p0 = k * 64;

    const int li = tid >> 2, lk = (tid & 3) << 2;
    const int ty = tid >> 4, tx = tid & 15;
    float acc[4][4] = {};

    for (int k0 = 0; k0 < 64; k0 += BK) {
        const float4 u = *(const float4*)(A + (size_t)(i0 + li) * 512 + p0 + k0 + lk);
        const float4 v = *(const float4*)(A + (size_t)(j0c + li) * 512 + p0 + k0 + lk);
        Ut[lk + 0][li] = u.x; Ut[lk + 1][li] = u.y;
        Ut[lk + 2][li] = u.z; Ut[lk + 3][li] = u.w;
        Vt[lk + 0][li] = v.x; Vt[lk + 1][li] = v.y;
        Vt[lk + 2][li] = v.z; Vt[lk + 3][li] = v.w;
        __syncthreads();
        MICRO(Ut, Vt);
        __syncthreads();
    }
#pragma unroll
    for (int aa = 0; aa < 4; ++aa) {
        const int r = i0 + (ty << 2) + aa;
        float* crow = A + (size_t)r * 512 + j0c + (tx << 2);
        float4 cv = *(const float4*)crow;
        cv.x -= acc[aa][0]; cv.y -= acc[aa][1];
        cv.z -= acc[aa][2]; cv.w -= acc[aa][3];
        *(float4*)crow = cv;
    }
}

// Blocked fwd+bwd solve, v4b: 256 blocks (32 batches x 8 col-splits), 256
// threads (thread = 1 output row x 2 cols), XCD-colocated, 4-deep static
// software pipeline with named buffers p0..p3. Replay-verified in R5.
__global__ __launch_bounds__(256, 1)
void fb_solve4_kernel(const float* __restrict__ Aall,
                      const float* __restrict__ Winv,
                      const float* __restrict__ WinvT,
                      const float* __restrict__ Y, float* __restrict__ Zall)
{
    __shared__ float V[512][10];   // 8 used cols + 2 pad
    __shared__ float U[64][10];
    const int tid = threadIdx.x;
    const int b   = (int)blockIdx.x & 31;          // batch -> XCD (b mod 8)
    const int c0  = ((int)blockIdx.x >> 5) * 8;    // col-split
    const int ty  = tid >> 2;            // 0..63: output row within k-block
    const int tx  = tid & 3;             // col pair: cols 2tx, 2tx+1
    const float* A   = Aall + (size_t)b * 512 * 512;
    const float* Yb  = Y    + (size_t)b * 512 * OUTd + c0;
    float*       Zb  = Zall + (size_t)b * 512 * OUTd + c0;
    const float* Wb  = Winv  + (size_t)b * 8 * 4096 + (size_t)ty * 64;
    const float* WbT = WinvT + (size_t)b * 8 * 4096 + (size_t)ty * 64;

    for (int t = tid; t < 512 * 4; t += 256) {
        const int row = t >> 2, p = (t & 3) * 2;
        *(float2*)&V[row][p] = *(const float2*)&Yb[(size_t)row * OUTd + p];
    }
    __syncthreads();

    float acc0, acc1;
    f32x4 p0[4], p1[4], p2[4], p3[4];

#define LDF(P, c, G)                                                            \
    { const int cc_ = ((c) < (G)) ? (c) : (G) - 1;                              \
      _Pragma("unroll") for (int j_ = 0; j_ < 4; ++j_)                          \
        P[j_] = *(const f32x4*)&Arow[16 * cc_ + 4 * j_]; }

#define LDB(P, c, G)                                                            \
    { const int cc_ = ((c) < (G)) ? (c) : (G) - 1;                              \
      _Pragma("unroll") for (int j_ = 0; j_ < 16; ++j_)                         \
        P[j_ >> 2][j_ & 3] = Acol[(size_t)(m1 + 16 * cc_ + j_) * 512]; }

#define CMPV(P, kb)                                                             \
    { _Pragma("unroll") for (int q_ = 0; q_ < 16; ++q_) {                       \
        const float a_ = P[q_ >> 2][q_ & 3];                                    \
        const float2 v_ = *(const float2*)&V[(kb) + q_][2 * tx];                \
        acc0 += a_ * v_.x; acc1 += a_ * v_.y; } }

#define CMPU(P, kb)                                                             \
    { _Pragma("unroll") for (int q_ = 0; q_ < 16; ++q_) {                       \
        const float a_ = P[q_ >> 2][q_ & 3];                                    \
        const float2 v_ = *(const float2*)&U[(kb) + q_][2 * tx];                \
        acc0 += a_ * v_.x; acc1 += a_ * v_.y; } }

#define DIAG(Wrow)                                                              \
    { acc0 = 0.f; acc1 = 0.f;                                                   \
      _Pragma("unroll") for (int j_ = 0; j_ < 4; ++j_) {                        \
        p0[j_] = *(const f32x4*)&(Wrow)[ 0 + 4 * j_];                           \
        p1[j_] = *(const f32x4*)&(Wrow)[16 + 4 * j_];                           \
        p2[j_] = *(const f32x4*)&(Wrow)[32 + 4 * j_];                           \
        p3[j_] = *(const f32x4*)&(Wrow)[48 + 4 * j_]; }                         \
      CMPU(p0, 0); CMPU(p1, 16); CMPU(p2, 32); CMPU(p3, 48); }

    // ---- forward: V_k = W_k (Y_k - L[k, 0:64k] @ V) ----
    for (int k = 0; k < 8; ++k) {
        const int r0 = k * 64;
        const float* Arow = A + (size_t)(r0 + ty) * 512;
        acc0 = 0.f; acc1 = 0.f;
        const int G = r0 >> 4;                   // chunks; multiple of 4
        if (G) {
            LDF(p0, 0, G); LDF(p1, 1, G); LDF(p2, 2, G); LDF(p3, 3, G);
            for (int g = 0; g < G; g += 4) {
                CMPV(p0, 16 * g);      LDF(p0, g + 4, G);
                CMPV(p1, 16 * g + 16); LDF(p1, g + 5, G);
                CMPV(p2, 16 * g + 32); LDF(p2, g + 6, G);
                CMPV(p3, 16 * g + 48); LDF(p3, g + 7, G);
            }
        }
        U[ty][2 * tx]     = V[r0 + ty][2 * tx]     - acc0;
        U[ty][2 * tx + 1] = V[r0 + ty][2 * tx + 1] - acc1;
        __syncthreads();
        DIAG(Wb + (size_t)k * 4096);             // Winv row ty = W[ty][m]
        V[r0 + ty][2 * tx]     = acc0;
        V[r0 + ty][2 * tx + 1] = acc1;
        __syncthreads();
    }

    // ---- backward: Z_k = W_k^T (V_k - L[64(k+1):, k]^T @ Z) ----
    for (int k = 7; k >= 0; --k) {
        const int r0 = k * 64;
        const float* Acol = A + r0 + ty;
        const int m1 = r0 + 64;
        acc0 = 0.f; acc1 = 0.f;
        const int G = (448 - r0) >> 4;           // chunks; multiple of 4
        if (G) {
            LDB(p0, 0, G); LDB(p1, 1, G); LDB(p2, 2, G); LDB(p3, 3, G);
            for (int g = 0; g < G; g += 4) {
                CMPV(p0, m1 + 16 * g);      LDB(p0, g + 4, G);
                CMPV(p1, m1 + 16 * g + 16); LDB(p1, g + 5, G);
                CMPV(p2, m1 + 16 * g + 32); LDB(p2, g + 6, G);
                CMPV(p3, m1 + 16 * g + 48); LDB(p3, g + 7, G);
            }
        }
        U[ty][2 * tx]     = V[r0 + ty][2 * tx]     - acc0;
        U[ty][2 * tx + 1] = V[r0 + ty][2 * tx + 1] - acc1;
        __syncthreads();
        DIAG(WbT + (size_t)k * 4096);            // WinvT row ty = W[m][ty]
        V[r0 + ty][2 * tx]     = acc0;
        V[r0 + ty][2 * tx + 1] = acc1;
        __syncthreads();
    }

    for (int t = tid; t < 512 * 4; t += 256) {
        const int row = t >> 2, p = (t & 3) * 2;
        *(float2*)&Zb[(size_t)row * OUTd + p] = *(const float2*)&V[row][p];
    }
#undef LDF
#undef LDB
#undef CMPV
#undef CMPU
#undef DIAG
}

// w[b] = RS_b^T @ Z_b, RS reconstructed as h+l.
__global__ __launch_bounds__(256)
void out_kernel(const u16* __restrict__ Sh, const u16* __restrict__ Sl,
                const float* __restrict__ Z, float* __restrict__ Wout)
{
    __shared__ float Rt[BK][64 + 4];
    __shared__ float Zt[BK][64 + 4];
    const int tid = threadIdx.x;
    const int b   = blockIdx.y;
    const int d0  = blockIdx.x * 64;
    const int kk  = tid >> 4, cq = (tid & 15) << 2;
    const int ty  = tid >> 4, tx = tid & 15;
    float acc[4][4] = {};

    for (int k0 = 0; k0 < Tt; k0 += BK) {
        const size_t ri = (size_t)(b * Tt + k0 + kk) * RES + d0 + cq;
        const u16x4 hv = *(const u16x4*)&Sh[ri];
        const u16x4 lv = *(const u16x4*)&Sl[ri];
        Rt[kk][cq + 0] = bf2f(hv[0]) + bf2f(lv[0]);
        Rt[kk][cq + 1] = bf2f(hv[1]) + bf2f(lv[1]);
        Rt[kk][cq + 2] = bf2f(hv[2]) + bf2f(lv[2]);
        Rt[kk][cq + 3] = bf2f(hv[3]) + bf2f(lv[3]);
        *(float4*)&Zt[kk][cq] =
            *(const float4*)(Z + ((size_t)b * Tt + k0 + kk) * OUTd + cq);
        __syncthreads();
        MICRO(Rt, Zt);
        __syncthreads();
    }
#pragma unroll
    for (int a = 0; a < 4; ++a) {
        const int d = d0 + (ty << 2) + a;
        *(float4*)(Wout + ((size_t)b * RES + d) * OUTd + (tx << 2)) =
            make_float4(acc[a][0], acc[a][1], acc[a][2], acc[a][3]);
    }
}

// bias: 256 threads/batch, 4 partial sums of 128 rows each + LDS reduce.
__global__ __launch_bounds__(256)
void bias_kernel(const float* __restrict__ Z, float* __restrict__ Bout)
{
    __shared__ float S[4][64];
    const int b = blockIdx.x;
    const int o = threadIdx.x & 63, g = threadIdx.x >> 6;
    const float* Zb = Z + (size_t)b * Tt * OUTd;
    float s = 0.f;
    for (int n = g * 128; n < (g + 1) * 128; ++n) s += Zb[(size_t)n * OUTd + o];
    S[g][o] = s;
    __syncthreads();
    if (threadIdx.x < 64)
        Bout[(size_t)b * OUTd + o] = ((S[0][o] + S[1][o]) + S[2][o]) + S[3][o];
}

extern "C" void kernel_launch(void* const* d_in, const int* in_sizes, int n_in,
                              void* d_out, int out_size, void* d_ws, size_t ws_size,
                              hipStream_t stream)
{
    const float* X    = (const float*)d_in[0];   // (32,512,128)
    const float* Y    = (const float*)d_in[1];   // (32,512,64)
    const float* Wres = (const float*)d_in[2];   // (2048,2048)
    const float* Win  = (const float*)d_in[3];   // (128,2048)
    const float* lam  = (const float*)d_in[4];   // scalar

    float* out  = (float*)d_out;
    float* Wout = out;
    float* Bout = out + (size_t)Bb * RES * OUTd;

    // ws: Sh 64 | Sl 64 | WTh 8 | WTl 8 | WinTh .5 | WinTl .5 | A 32 | Z 4 | Wi 4 | WiT 4 = 189 MB
    char* p = (char*)d_ws;
    u16* Sh    = (u16*)p;   p += (size_t)Bb * Tt * RES * 2;
    u16* Sl    = (u16*)p;   p += (size_t)Bb * Tt * RES * 2;
    u16* WTh   = (u16*)p;   p += (size_t)RES * RES * 2;
    u16* WTl   = (u16*)p;   p += (size_t)RES * RES * 2;
    u16* WinTh = (u16*)p;   p += (size_t)INd * RES * 2;
    u16* WinTl = (u16*)p;   p += (size_t)INd * RES * 2;
    float* A   = (float*)p; p += (size_t)Bb * 512 * 512 * 4;
    float* Z   = (float*)p; p += (size_t)Bb * Tt * OUTd * 4;
    float* Wi  = (float*)p; p += (size_t)Bb * 8 * 64 * 64 * 4;
    float* WiT = (float*)p;

    const dim3 blk(256);
    tconv_kernel<<<dim3(RES / 64, RES / 64), blk, 0, stream>>>(Wres, WTh, WTl, RES, RES);
    tconv_kernel<<<dim3(RES / 64, INd / 64), blk, 0, stream>>>(Win, WinTh, WinTl, INd, RES);

    // classes: s:(cin->cout) 0:(-,2) 1:(2,1) 2:(1,0) 3:(0,1) 4:(1,2) 5:(2,3)
    const dim3 sgrid(RES / 128, Bb);
    step_mfma_kernel<<<sgrid, blk, 0, stream>>>(Sh, Sl, X, WTh, WTl, WinTh, WinTl, 0, 2, 0);
    step_mfma_kernel<<<sgrid, blk, 0, stream>>>(Sh, Sl, X, WTh, WTl, WinTh, WinTl, 2, 1, 1);
    step_mfma_kernel<<<sgrid, blk, 0, stream>>>(Sh, Sl, X, WTh, WTl, WinTh, WinTl, 1, 0, 2);
    step_mfma_kernel<<<sgrid, blk, 0, stream>>>(Sh, Sl, X, WTh, WTl, WinTh, WinTl, 0, 1, 3);
    step_mfma_kernel<<<sgrid, blk, 0, stream>>>(Sh, Sl, X, WTh, WTl, WinTh, WinTl, 1, 2, 4);
    step_mfma_kernel<<<sgrid, blk, 0, stream>>>(Sh, Sl, X, WTh, WTl, WinTh, WinTl, 2, 3, 5);

    gram_mfma_kernel<<<dim3(10, Bb), blk, 0, stream>>>(Sh, Sl, A, lam);

    for (int k = 0; k < 8; ++k) {
        chol_diag_inv_kernel<<<dim3(Bb), dim3(256), 0, stream>>>(A, Wi, WiT, k);
        if (k < 7) {
            trsm_kernel<<<dim3(7 - k, Bb), blk, 0, stream>>>(A, WiT, k);
            const int m = 7 - k;
            chol_trailing_kernel<<<dim3(m * (m + 1) / 2, Bb), blk, 0, stream>>>(A, k);
        }
    }
    fb_solve4_kernel<<<dim3(Bb * 8), dim3(256), 0, stream>>>(A, Wi, WiT, Y, Z);

    out_kernel<<<dim3(RES / 64, Bb), blk, 0, stream>>>(Sh, Sl, Z, Wout);
    bias_kernel<<<dim3(Bb), dim3(256), 0, stream>>>(Z, Bout);
}

// Round 10
// 1928.855 us; speedup vs baseline: 1.4658x; 1.0595x over previous
//
#include <hip/hip_runtime.h>
#include <cmath>

#define Bb   32
#define Tt   512
#define INd  128
#define RES  2048
#define OUTd 64

#define BM 64
#define BN 64
#define BK 16

typedef unsigned short u16;
typedef __attribute__((ext_vector_type(4))) unsigned short u16x4;
typedef __attribute__((ext_vector_type(8))) unsigned short u16x8;
typedef __attribute__((ext_vector_type(8))) short bf8;
typedef __attribute__((ext_vector_type(4))) float f32x4;

// fp32 = bf16 hi (RNE) + bf16 lo (trunc residual); |err| <= 2^-17 |a|
__device__ __forceinline__ void splitf(float a, u16& h, u16& l) {
    unsigned u = __float_as_uint(a);
    unsigned r = (u + 0x7fffu + ((u >> 16) & 1u)) & 0xffff0000u;
    h = (u16)(r >> 16);
    float d = a - __uint_as_float(r);
    l = (u16)(__float_as_uint(d) >> 16);
}
__device__ __forceinline__ float bf2f(u16 h) {
    return __uint_as_float((unsigned)h << 16);
}
__device__ __forceinline__ void split8(const float4& a, const float4& b,
                                       u16x8& h, u16x8& l) {
    u16 hh, ll;
    splitf(a.x, hh, ll); h[0] = hh; l[0] = ll;
    splitf(a.y, hh, ll); h[1] = hh; l[1] = ll;
    splitf(a.z, hh, ll); h[2] = hh; l[2] = ll;
    splitf(a.w, hh, ll); h[3] = hh; l[3] = ll;
    splitf(b.x, hh, ll); h[4] = hh; l[4] = ll;
    splitf(b.y, hh, ll); h[5] = hh; l[5] = ll;
    splitf(b.z, hh, ll); h[6] = hh; l[6] = ll;
    splitf(b.w, hh, ll); h[7] = hh; l[7] = ll;
}

// async global->LDS, 16B per lane. LDS dest is wave-uniform base + lane*16;
// global src is per-lane (carries the chunk swizzle).
__device__ __forceinline__ void gl_lds16(const u16* g, u16* l) {
    __builtin_amdgcn_global_load_lds(
        (const __attribute__((address_space(1))) unsigned int*)g,
        (__attribute__((address_space(3))) unsigned int*)l,
        16, 0, 0);
}

#define MICRO(SA, SB)                                                           \
  do {                                                                          \
    _Pragma("unroll")                                                           \
    for (int kk = 0; kk < BK; ++kk) {                                           \
      const float4 a4 = *(const float4*)&SA[kk][ty << 2];                       \
      const float4 b4 = *(const float4*)&SB[kk][tx << 2];                       \
      acc[0][0] += a4.x*b4.x; acc[0][1] += a4.x*b4.y;                           \
      acc[0][2] += a4.x*b4.z; acc[0][3] += a4.x*b4.w;                           \
      acc[1][0] += a4.y*b4.x; acc[1][1] += a4.y*b4.y;                           \
      acc[1][2] += a4.y*b4.z; acc[1][3] += a4.y*b4.w;                           \
      acc[2][0] += a4.z*b4.x; acc[2][1] += a4.z*b4.y;                           \
      acc[2][2] += a4.z*b4.z; acc[2][3] += a4.z*b4.w;                           \
      acc[3][0] += a4.w*b4.x; acc[3][1] += a4.w*b4.y;                           \
      acc[3][2] += a4.w*b4.z; acc[3][3] += a4.w*b4.w;                           \
    }                                                                           \
  } while (0)

// 128x128 tile, K=32 slice, bf16x3. Linear LDS rows of 32 u16 (64 B) with
// 16B-chunk XOR swizzle c' = c ^ ((row>>1)&3)  ->  max 2-way bank alias (free).
// Buffer layout (u16 offsets): Ah 0 | Al 4096 | Bh 8192 | Bl 12288.
#define MFMA_TILE(BUF)                                                           \
  do {                                                                           \
    bf8 aH[4], aL[4], bH[4], bL[4];                                              \
    const int qd = (quad ^ ((l15 >> 1) & 3)) << 3;                               \
    _Pragma("unroll")                                                            \
    for (int i = 0; i < 4; ++i) {                                                \
      const int ar = (wm*64 + i*16 + l15)*32 + qd;                               \
      const int br = (wn*64 + i*16 + l15)*32 + qd;                               \
      aH[i] = *(const bf8*)&(BUF)[ar];                                           \
      aL[i] = *(const bf8*)&(BUF)[4096 + ar];                                    \
      bH[i] = *(const bf8*)&(BUF)[8192 + br];                                    \
      bL[i] = *(const bf8*)&(BUF)[12288 + br];                                   \
    }                                                                            \
    _Pragma("unroll")                                                            \
    for (int i = 0; i < 4; ++i)                                                  \
      _Pragma("unroll")                                                          \
      for (int j = 0; j < 4; ++j) {                                              \
        acc[i][j] = __builtin_amdgcn_mfma_f32_16x16x32_bf16(aH[i], bH[j], acc[i][j], 0, 0, 0); \
        acc[i][j] = __builtin_amdgcn_mfma_f32_16x16x32_bf16(aH[i], bL[j], acc[i][j], 0, 0, 0); \
        acc[i][j] = __builtin_amdgcn_mfma_f32_16x16x32_bf16(aL[i], bH[j], acc[i][j], 0, 0, 0); \
      }                                                                          \
  } while (0)

// Transpose + split weights: in (K x N fp32) -> outH/outL (N x K bf16).
__global__ __launch_bounds__(256)
void tconv_kernel(const float* __restrict__ in, u16* __restrict__ outH,
                  u16* __restrict__ outL, int K, int N)
{
    __shared__ float T[64][65];
    const int n0 = blockIdx.x * 64, k0 = blockIdx.y * 64;
    const int t = threadIdx.x;
    const int r = t >> 2, c0 = (t & 3) * 16;
#pragma unroll
    for (int i = 0; i < 4; ++i) {
        const float4 v = *(const float4*)&in[(size_t)(k0 + r) * N + n0 + c0 + 4*i];
        T[r][c0 + 4*i + 0] = v.x; T[r][c0 + 4*i + 1] = v.y;
        T[r][c0 + 4*i + 2] = v.z; T[r][c0 + 4*i + 3] = v.w;
    }
    __syncthreads();
    const int n = t >> 2, ck = (t & 3) * 16;
    u16x8 h0, h1, l0, l1;
#pragma unroll
    for (int i = 0; i < 8; ++i) { u16 h, l; splitf(T[ck + i][n], h, l); h0[i] = h; l0[i] = l; }
#pragma unroll
    for (int i = 0; i < 8; ++i) { u16 h, l; splitf(T[ck + 8 + i][n], h, l); h1[i] = h; l1[i] = l; }
    const size_t ob = (size_t)(n0 + n) * K + k0 + ck;
    *(u16x8*)&outH[ob] = h0; *(u16x8*)&outH[ob + 8] = h1;
    *(u16x8*)&outL[ob] = l0; *(u16x8*)&outL[ob + 8] = l1;
}

// Reservoir step on bf16 hi/lo state planes (row = b*512 + 4w + class).
// Replay-verified staging + bijective XCD block swizzle.
__global__ __launch_bounds__(256)
void step_mfma_kernel(u16* __restrict__ Sh, u16* __restrict__ Sl,
                      const float* __restrict__ X,
                      const u16* __restrict__ WTh, const u16* __restrict__ WTl,
                      const u16* __restrict__ WinTh, const u16* __restrict__ WinTl,
                      int cin, int cout, int s)
{
    __shared__ u16 LB[2 * 16384];             // 2 x 32 KB slice buffers
    u16* buf0 = LB;
    u16* buf1 = LB + 16384;
    float* Cf = (float*)LB;                   // 64x128 f32 = 32 KB (epilogue)

    const int tid = threadIdx.x;
    // bijective 9-bit remap of (blockIdx.x, blockIdx.y) = (16, 32)
    const int f  = (int)blockIdx.x + ((int)blockIdx.y << 4);
    const int bx = (f & 1) | (((f >> 3) & 7) << 1);          // 0..15
    const int by = ((f >> 1) & 3) | (((f >> 6) & 7) << 2);   // 0..31
    const int q0  = bx * 128;                 // reservoir-col tile
    const int b   = by;
    const int bofs = b * Tt;
    const int wid = tid >> 6, lane = tid & 63;
    const int wm = wid & 1, wn = wid >> 1;
    const int l15 = lane & 15, quad = lane >> 4;

    f32x4 acc[4][4];
    const f32x4 zz = {0.f, 0.f, 0.f, 0.f};
#pragma unroll
    for (int i = 0; i < 4; ++i)
#pragma unroll
        for (int j = 0; j < 4; ++j) acc[i][j] = zz;

    // per-wave slice staging: wid 0=Ah(Sh) 1=Al(Sl) 2=Bh(WTh) 3=Bl(WTl).
    const int rl    = lane >> 2;
    const int csrc  = (((lane & 3) ^ ((lane >> 3) & 3)) << 3);
    const u16* plane = (wid == 0) ? (const u16*)Sh
                     : (wid == 1) ? (const u16*)Sl
                     : (wid == 2) ? WTh : WTl;

    auto stage = [&](u16* buf, int k0) {
        u16* ldst = buf + wid * 4096;
#pragma unroll
        for (int i = 0; i < 8; ++i) {
            const int r = i * 16 + rl;
            const size_t grow = (wid < 2) ? (size_t)(bofs + 4 * r + cin)
                                          : (size_t)(q0 + r);
            gl_lds16(&plane[grow * RES + k0 + csrc], ldst + i * 512);
        }
    };

    if (s > 0) {
        stage(buf0, 0);
        __syncthreads();                      // drains vmcnt -> buf0 ready
        for (int k0 = 0; k0 < RES; k0 += 32) {
            u16* cur = (k0 & 32) ? buf1 : buf0;
            u16* nxt = (k0 & 32) ? buf0 : buf1;
            if (k0 + 32 < RES) stage(nxt, k0 + 32);
            MFMA_TILE(cur);
            __syncthreads();                  // nxt staged; cur reads done
        }
    }

    // input projection: K=128 over x[b, 4w+s-2, :] @ Win.
    for (int k0 = 0; k0 < INd; k0 += 32) {
        if (tid < 128) {
            const int rrow = tid;             // 0..127
            const int t = 4 * rrow + s - 2;
            u16x8 h0 = {0,0,0,0,0,0,0,0}, h1 = h0, h2 = h0, h3 = h0;
            u16x8 l0 = h0, l1 = h0, l2 = h0, l3 = h0;
            if (t >= 0) {
                const float* xr = X + (size_t)(bofs + t) * INd + k0;
                const float4 f0 = *(const float4*)&xr[0];
                const float4 f1 = *(const float4*)&xr[4];
                const float4 f2 = *(const float4*)&xr[8];
                const float4 f3 = *(const float4*)&xr[12];
                const float4 f4 = *(const float4*)&xr[16];
                const float4 f5 = *(const float4*)&xr[20];
                const float4 f6 = *(const float4*)&xr[24];
                const float4 f7 = *(const float4*)&xr[28];
                split8(f0, f1, h0, l0); split8(f2, f3, h1, l1);
                split8(f4, f5, h2, l2); split8(f6, f7, h3, l3);
            }
            const int sw = (rrow >> 1) & 3;
            u16* dA = buf0 + rrow * 32;
            *(u16x8*)&dA[(0 ^ sw) << 3] = h0;
            *(u16x8*)&dA[(1 ^ sw) << 3] = h1;
            *(u16x8*)&dA[(2 ^ sw) << 3] = h2;
            *(u16x8*)&dA[(3 ^ sw) << 3] = h3;
            u16* dL = buf0 + 4096 + rrow * 32;
            *(u16x8*)&dL[(0 ^ sw) << 3] = l0;
            *(u16x8*)&dL[(1 ^ sw) << 3] = l1;
            *(u16x8*)&dL[(2 ^ sw) << 3] = l2;
            *(u16x8*)&dL[(3 ^ sw) << 3] = l3;
        } else {
            const u16* wpl = (wid == 2) ? WinTh : WinTl;
            u16* ldst = buf0 + wid * 4096;
#pragma unroll
            for (int i = 0; i < 8; ++i) {
                const int r = i * 16 + rl;
                gl_lds16(&wpl[(size_t)(q0 + r) * INd + k0 + csrc], ldst + i * 512);
            }
        }
        __syncthreads();
        MFMA_TILE(buf0);
        __syncthreads();
    }

    // epilogue via LDS: all global I/O is coalesced u16x8.
    for (int h = 0; h < 2; ++h) {
        __syncthreads();
        if (wm == h) {
#pragma unroll
            for (int i = 0; i < 4; ++i)
#pragma unroll
                for (int j = 0; j < 4; ++j)
#pragma unroll
                    for (int rg = 0; rg < 4; ++rg)
                        Cf[(i * 16 + quad * 4 + rg) * 128 + wn * 64 + j * 16 + l15]
                            = acc[i][j][rg];
        }
        __syncthreads();
#pragma unroll
        for (int pass = 0; pass < 4; ++pass) {
            const int r  = (tid >> 4) + pass * 16;      // 0..63
            const int c0 = (tid & 15) * 8;              // 0..120
            const int wrow = h * 64 + r;
            const float4 v0 = *(const float4*)&Cf[r * 128 + c0];
            const float4 v1 = *(const float4*)&Cf[r * 128 + c0 + 4];
            float vv[8] = {v0.x, v0.y, v0.z, v0.w, v1.x, v1.y, v1.z, v1.w};
            u16x8 ph, pl;
            if (s > 0) {
                const size_t prow = (size_t)(bofs + 4 * wrow + cin) * RES + q0 + c0;
                ph = *(const u16x8*)&Sh[prow];
                pl = *(const u16x8*)&Sl[prow];
            }
            u16x8 oh, ol;
#pragma unroll
            for (int e = 0; e < 8; ++e) {
                float prev = (s > 0) ? (bf2f(ph[e]) + bf2f(pl[e])) : 0.f;
                float v = 0.7f * prev + 0.3f * sinf(vv[e]);
                u16 hh, ll; splitf(v, hh, ll);
                oh[e] = hh; ol[e] = ll;
            }
            const size_t orow = (size_t)(bofs + 4 * wrow + cout) * RES + q0 + c0;
            *(u16x8*)&Sh[orow] = oh;
            *(u16x8*)&Sl[orow] = ol;
        }
    }
}

// Gram on bf16 planes: A[b] = (Sh+Sl)(Sh+Sl)^T + ones + reg*I, bf16x3.
__global__ __launch_bounds__(256)
void gram_mfma_kernel(const u16* __restrict__ Sh, const u16* __restrict__ Sl,
                      float* __restrict__ A, const float* __restrict__ lam)
{
    __shared__ u16 LB[2 * 16384];
    u16* buf0 = LB;
    u16* buf1 = LB + 16384;
    float* Cf = (float*)LB;                   // 64 x 132 f32 = 33.8 KB

    const int tid = threadIdx.x;
    const int bt  = blockIdx.y;
    int ti = 0, rem = (int)blockIdx.x;
    while (rem >= 4 - ti) { rem -= 4 - ti; ++ti; }
    const int tj = ti + rem;
    const int n0 = ti * 128, m0 = tj * 128;
    const int bofs = bt * Tt;

    const int wid = tid >> 6, lane = tid & 63;
    const int wm = wid & 1, wn = wid >> 1;
    const int l15 = lane & 15, quad = lane >> 4;

    f32x4 acc[4][4];
    const f32x4 zz = {0.f, 0.f, 0.f, 0.f};
#pragma unroll
    for (int i = 0; i < 4; ++i)
#pragma unroll
        for (int j = 0; j < 4; ++j) acc[i][j] = zz;

    const int rl    = lane >> 2;
    const int csrc  = (((lane & 3) ^ ((lane >> 3) & 3)) << 3);
    const u16* plane = (wid & 1) ? Sl : Sh;
    const int rbase  = (wid < 2) ? n0 : m0;

    auto stage = [&](u16* buf, int k0) {
        u16* ldst = buf + wid * 4096;
#pragma unroll
        for (int i = 0; i < 8; ++i) {
            const int r = i * 16 + rl;
            gl_lds16(&plane[(size_t)(bofs + rbase + r) * RES + k0 + csrc],
                     ldst + i * 512);
        }
    };

    stage(buf0, 0);
    __syncthreads();
    for (int k0 = 0; k0 < RES; k0 += 32) {
        u16* cur = (k0 & 32) ? buf1 : buf0;
        u16* nxt = (k0 & 32) ? buf0 : buf1;
        if (k0 + 32 < RES) stage(nxt, k0 + 32);
        MFMA_TILE(cur);
        __syncthreads();
    }

    const float reg = log1pf(expf(lam[0]));
    float* Ab = A + (size_t)bt * 512 * 512;
    for (int h = 0; h < 2; ++h) {
        __syncthreads();
        if (wm == h) {
#pragma unroll
            for (int i = 0; i < 4; ++i)
#pragma unroll
                for (int j = 0; j < 4; ++j)
#pragma unroll
                    for (int rg = 0; rg < 4; ++rg)
                        Cf[(i * 16 + quad * 4 + rg) * 132 + wn * 64 + j * 16 + l15]
                            = acc[i][j][rg];
        }
        __syncthreads();
        // row-major half: rows nn = n0+h*64+r, cols m0..m0+127
#pragma unroll
        for (int pass = 0; pass < 4; ++pass) {
            const int r  = (tid >> 4) + pass * 16;
            const int c0 = (tid & 15) * 8;
            const int nn = n0 + h * 64 + r;
            float o[8];
#pragma unroll
            for (int e = 0; e < 8; ++e) {
                const int mm = m0 + c0 + e;
                float v = Cf[r * 132 + c0 + e] + 1.0f;
                if (nn == mm) v += reg;
                o[e] = v;
            }
            float* dst = Ab + (size_t)nn * 512 + m0 + c0;
            *(float4*)&dst[0] = make_float4(o[0], o[1], o[2], o[3]);
            *(float4*)&dst[4] = make_float4(o[4], o[5], o[6], o[7]);
        }
        // transposed half: rows mm = m0+rt, cols n0+h*64 .. +63
#pragma unroll
        for (int pass = 0; pass < 4; ++pass) {
            const int rt  = (tid >> 3) + pass * 32;     // 0..127
            const int c0t = (tid & 7) * 8;              // 0..56
            const int mm  = m0 + rt;
            float o[8];
#pragma unroll
            for (int e = 0; e < 8; ++e) {
                const int nn = n0 + h * 64 + c0t + e;
                float v = Cf[(c0t + e) * 132 + rt] + 1.0f;
                if (nn == mm) v += reg;
                o[e] = v;
            }
            float* dst = Ab + (size_t)mm * 512 + n0 + h * 64 + c0t;
            *(float4*)&dst[0] = make_float4(o[0], o[1], o[2], o[3]);
            *(float4*)&dst[4] = make_float4(o[4], o[5], o[6], o[7]);
        }
    }
}

// Diag-block Cholesky (64x64) + inverse, v3: RAW-pivot fused single-phase.
// P holds the raw (unscaled-column) partial factor; per column j:
//   rd2 = 1/P[j][j];  P[r][m] -= (P[r][j]*rd2)*P[m][j]   (factor rank-1)
//   W[m][r] -= P[m][j]*(W[j][r]*rd2)                      (inverse sweep)
// in ONE barrier-delimited phase (writes all at m>j; reads at col j/row j/own
// RMW cells -> race-free). Scaling by 1/sqrt(diag) deferred to write-out.
// Arithmetic == v2 to ~1-2 ulp (regrouped division). 64 phases vs 256.
__global__ __launch_bounds__(256)
void chol_diag_inv_kernel(float* __restrict__ Aall, float* __restrict__ Winv,
                          float* __restrict__ WinvT, int k)
{
    __shared__ float P[64][65];
    __shared__ float W[64][65];
    const int b = blockIdx.x, tid = threadIdx.x;
    float* A = Aall + (size_t)b * 512 * 512;
    const int j0 = 64 * k;
    const int r = tid & 63;          // row (factor) / RHS column (inverse)
    const int q = tid >> 6;          // 16-wide strip (wave-uniform)

    // load 64x64 (each thread 16 floats); W = I
    {
        const int lr = tid >> 2, lc = (tid & 3) * 16;
#pragma unroll
        for (int i = 0; i < 4; ++i) {
            const float4 v = *(const float4*)(A + (size_t)(j0 + lr) * 512 + j0 + lc + 4*i);
            P[lr][lc + 4*i + 0] = v.x; P[lr][lc + 4*i + 1] = v.y;
            P[lr][lc + 4*i + 2] = v.z; P[lr][lc + 4*i + 3] = v.w;
        }
    }
    for (int t = tid; t < 4096; t += 256)
        W[t >> 6][t & 63] = ((t >> 6) == (t & 63)) ? 1.f : 0.f;
    __syncthreads();

    for (int j = 0; j < 64; ++j) {
        const float rd2 = 1.0f / P[j][j];        // raw pivot (pre-sqrt)
        const float tfa = P[r][j] * rd2;         // factor coefficient
        const float cwd = W[j][r] * rd2;         // inverse coefficient
        float pm[16];
#pragma unroll
        for (int i = 0; i < 16; ++i) pm[i] = P[q * 16 + i][j];
#pragma unroll
        for (int i = 0; i < 16; ++i) {
            const int m = q * 16 + i;
            if (m > j && m <= r) P[r][m] -= tfa * pm[i];
        }
#pragma unroll
        for (int i = 0; i < 16; ++i) {
            const int m = q * 16 + i;
            if (m > j) W[m][r] -= pm[i] * cwd;
        }
        __syncthreads();
    }

    // write back L: lower strictly = raw/sqrt(diag), diag = sqrt, upper = A.
    {
        const int lr = tid >> 2, lc = (tid & 3) * 16;
#pragma unroll
        for (int i = 0; i < 4; ++i) {
            float o[4];
#pragma unroll
            for (int e = 0; e < 4; ++e) {
                const int c = lc + 4*i + e;
                const float pv = P[lr][c];
                if (c < lr)       o[e] = pv / sqrtf(P[c][c]);
                else if (c == lr) o[e] = sqrtf(pv);
                else              o[e] = pv;
            }
            *(float4*)(A + (size_t)(j0 + lr) * 512 + j0 + lc + 4*i) =
                make_float4(o[0], o[1], o[2], o[3]);
        }
    }
    float* Wo  = Winv  + ((size_t)b * 8 + k) * 64 * 64;
    float* WoT = WinvT + ((size_t)b * 8 + k) * 64 * 64;
    for (int t = tid; t < 4096; t += 256) {
        const int rr = t >> 6, cc = t & 63;
        Wo[t]  = W[rr][cc] / sqrtf(P[rr][rr]);
        WoT[t] = W[cc][rr] / sqrtf(P[cc][cc]);
    }
}

// Panel TRSM via inverse: L[i0.., k] = A[i0.., k] @ W^T
__global__ __launch_bounds__(256)
void trsm_kernel(float* __restrict__ Aall, const float* __restrict__ WinvT, int k)
{
    __shared__ float St[BK][BM + 4];
    __shared__ float Wt[BK][BN + 4];
    float* A = Aall + (size_t)blockIdx.y * 512 * 512;
    const float* WT = WinvT + ((size_t)blockIdx.y * 8 + k) * 64 * 64;
    const int i0 = (k + 1 + blockIdx.x) * 64, p0 = k * 64;
    const int tid = threadIdx.x;
    const int li = tid >> 2, lk = (tid & 3) << 2;
    const int wk = tid >> 4, wq = (tid & 15) << 2;
    const int ty = tid >> 4, tx = tid & 15;
    float acc[4][4] = {};
    for (int k0 = 0; k0 < 64; k0 += BK) {
        const float4 u = *(const float4*)(A + (size_t)(i0 + li) * 512 + p0 + k0 + lk);
        St[lk + 0][li] = u.x; St[lk + 1][li] = u.y;
        St[lk + 2][li] = u.z; St[lk + 3][li] = u.w;
        *(float4*)&Wt[wk][wq] = *(const float4*)(WT + (size_t)(k0 + wk) * 64 + wq);
        __syncthreads();
        MICRO(St, Wt);
        __syncthreads();
    }
#pragma unroll
    for (int a = 0; a < 4; ++a) {
        const int r = i0 + (ty << 2) + a;
        *(float4*)(A + (size_t)r * 512 + p0 + (tx << 2)) =
            make_float4(acc[a][0], acc[a][1], acc[a][2], acc[a][3]);
    }
}

// Trailing update: A[ti,tj] -= L[ti,k] L[tj,k]^T
__global__ __launch_bounds__(256)
void chol_trailing_kernel(float* __restrict__ Aall, int k)
{
    __shared__ float Ut[BK][BM + 4];
    __shared__ float Vt[BK][BN + 4];
    float* A = Aall + (size_t)blockIdx.y * 512 * 512;
    const int tid = threadIdx.x;
    int a = 0, rem = (int)blockIdx.x;
    while (rem >= a + 1) { rem -= a + 1; ++a; }
    const int ti = k + 1 + a, tj = k + 1 + rem;
    const int i0 = ti * 64, j0c = tj * 64, p0 = k * 64;

    const int li = tid >> 2, lk = (tid & 3) << 2;
    const int ty = tid >> 4, tx = tid & 15;
    float acc[4][4] = {};

    for (int k0 = 0; k0 < 64; k0 += BK) {
        const float4 u = *(const float4*)(A + (size_t)(i0 + li) * 512 + p0 + k0 + lk);
        const float4 v = *(const float4*)(A + (size_t)(j0c + li) * 512 + p0 + k0 + lk);
        Ut[lk + 0][li] = u.x; Ut[lk + 1][li] = u.y;
        Ut[lk + 2][li] = u.z; Ut[lk + 3][li] = u.w;
        Vt[lk + 0][li] = v.x; Vt[lk + 1][li] = v.y;
        Vt[lk + 2][li] = v.z; Vt[lk + 3][li] = v.w;
        __syncthreads();
        MICRO(Ut, Vt);
        __syncthreads();
    }
#pragma unroll
    for (int aa = 0; aa < 4; ++aa) {
        const int r = i0 + (ty << 2) + aa;
        float* crow = A + (size_t)r * 512 + j0c + (tx << 2);
        float4 cv = *(const float4*)crow;
        cv.x -= acc[aa][0]; cv.y -= acc[aa][1];
        cv.z -= acc[aa][2]; cv.w -= acc[aa][3];
        *(float4*)crow = cv;
    }
}

// Blocked fwd+bwd solve, v4b: 256 blocks (32 batches x 8 col-splits), 256
// threads (thread = 1 output row x 2 cols), XCD-colocated, 4-deep static
// software pipeline with named buffers p0..p3. Replay-verified in R5/R9.
__global__ __launch_bounds__(256, 1)
void fb_solve4_kernel(const float* __restrict__ Aall,
                      const float* __restrict__ Winv,
                      const float* __restrict__ WinvT,
                      const float* __restrict__ Y, float* __restrict__ Zall)
{
    __shared__ float V[512][10];   // 8 used cols + 2 pad
    __shared__ float U[64][10];
    const int tid = threadIdx.x;
    const int b   = (int)blockIdx.x & 31;          // batch -> XCD (b mod 8)
    const int c0  = ((int)blockIdx.x >> 5) * 8;    // col-split
    const int ty  = tid >> 2;            // 0..63: output row within k-block
    const int tx  = tid & 3;             // col pair: cols 2tx, 2tx+1
    const float* A   = Aall + (size_t)b * 512 * 512;
    const float* Yb  = Y    + (size_t)b * 512 * OUTd + c0;
    float*       Zb  = Zall + (size_t)b * 512 * OUTd + c0;
    const float* Wb  = Winv  + (size_t)b * 8 * 4096 + (size_t)ty * 64;
    const float* WbT = WinvT + (size_t)b * 8 * 4096 + (size_t)ty * 64;

    for (int t = tid; t < 512 * 4; t += 256) {
        const int row = t >> 2, p = (t & 3) * 2;
        *(float2*)&V[row][p] = *(const float2*)&Yb[(size_t)row * OUTd + p];
    }
    __syncthreads();

    float acc0, acc1;
    f32x4 p0[4], p1[4], p2[4], p3[4];

#define LDF(P, c, G)                                                            \
    { const int cc_ = ((c) < (G)) ? (c) : (G) - 1;                              \
      _Pragma("unroll") for (int j_ = 0; j_ < 4; ++j_)                          \
        P[j_] = *(const f32x4*)&Arow[16 * cc_ + 4 * j_]; }

#define LDB(P, c, G)                                                            \
    { const int cc_ = ((c) < (G)) ? (c) : (G) - 1;                              \
      _Pragma("unroll") for (int j_ = 0; j_ < 16; ++j_)                         \
        P[j_ >> 2][j_ & 3] = Acol[(size_t)(m1 + 16 * cc_ + j_) * 512]; }

#define CMPV(P, kb)                                                             \
    { _Pragma("unroll") for (int q_ = 0; q_ < 16; ++q_) {                       \
        const float a_ = P[q_ >> 2][q_ & 3];                                    \
        const float2 v_ = *(const float2*)&V[(kb) + q_][2 * tx];                \
        acc0 += a_ * v_.x; acc1 += a_ * v_.y; } }

#define CMPU(P, kb)                                                             \
    { _Pragma("unroll") for (int q_ = 0; q_ < 16; ++q_) {                       \
        const float a_ = P[q_ >> 2][q_ & 3];                                    \
        const float2 v_ = *(const float2*)&U[(kb) + q_][2 * tx];                \
        acc0 += a_ * v_.x; acc1 += a_ * v_.y; } }

#define DIAG(Wrow)                                                              \
    { acc0 = 0.f; acc1 = 0.f;                                                   \
      _Pragma("unroll") for (int j_ = 0; j_ < 4; ++j_) {                        \
        p0[j_] = *(const f32x4*)&(Wrow)[ 0 + 4 * j_];                           \
        p1[j_] = *(const f32x4*)&(Wrow)[16 + 4 * j_];                           \
        p2[j_] = *(const f32x4*)&(Wrow)[32 + 4 * j_];                           \
        p3[j_] = *(const f32x4*)&(Wrow)[48 + 4 * j_]; }                         \
      CMPU(p0, 0); CMPU(p1, 16); CMPU(p2, 32); CMPU(p3, 48); }

    // ---- forward: V_k = W_k (Y_k - L[k, 0:64k] @ V) ----
    for (int k = 0; k < 8; ++k) {
        const int r0 = k * 64;
        const float* Arow = A + (size_t)(r0 + ty) * 512;
        acc0 = 0.f; acc1 = 0.f;
        const int G = r0 >> 4;                   // chunks; multiple of 4
        if (G) {
            LDF(p0, 0, G); LDF(p1, 1, G); LDF(p2, 2, G); LDF(p3, 3, G);
            for (int g = 0; g < G; g += 4) {
                CMPV(p0, 16 * g);      LDF(p0, g + 4, G);
                CMPV(p1, 16 * g + 16); LDF(p1, g + 5, G);
                CMPV(p2, 16 * g + 32); LDF(p2, g + 6, G);
                CMPV(p3, 16 * g + 48); LDF(p3, g + 7, G);
            }
        }
        U[ty][2 * tx]     = V[r0 + ty][2 * tx]     - acc0;
        U[ty][2 * tx + 1] = V[r0 + ty][2 * tx + 1] - acc1;
        __syncthreads();
        DIAG(Wb + (size_t)k * 4096);             // Winv row ty = W[ty][m]
        V[r0 + ty][2 * tx]     = acc0;
        V[r0 + ty][2 * tx + 1] = acc1;
        __syncthreads();
    }

    // ---- backward: Z_k = W_k^T (V_k - L[64(k+1):, k]^T @ Z) ----
    for (int k = 7; k >= 0; --k) {
        const int r0 = k * 64;
        const float* Acol = A + r0 + ty;
        const int m1 = r0 + 64;
        acc0 = 0.f; acc1 = 0.f;
        const int G = (448 - r0) >> 4;           // chunks; multiple of 4
        if (G) {
            LDB(p0, 0, G); LDB(p1, 1, G); LDB(p2, 2, G); LDB(p3, 3, G);
            for (int g = 0; g < G; g += 4) {
                CMPV(p0, m1 + 16 * g);      LDB(p0, g + 4, G);
                CMPV(p1, m1 + 16 * g + 16); LDB(p1, g + 5, G);
                CMPV(p2, m1 + 16 * g + 32); LDB(p2, g + 6, G);
                CMPV(p3, m1 + 16 * g + 48); LDB(p3, g + 7, G);
            }
        }
        U[ty][2 * tx]     = V[r0 + ty][2 * tx]     - acc0;
        U[ty][2 * tx + 1] = V[r0 + ty][2 * tx + 1] - acc1;
        __syncthreads();
        DIAG(WbT + (size_t)k * 4096);            // WinvT row ty = W[m][ty]
        V[r0 + ty][2 * tx]     = acc0;
        V[r0 + ty][2 * tx + 1] = acc1;
        __syncthreads();
    }

    for (int t = tid; t < 512 * 4; t += 256) {
        const int row = t >> 2, p = (t & 3) * 2;
        *(float2*)&Zb[(size_t)row * OUTd + p] = *(const float2*)&V[row][p];
    }
#undef LDF
#undef LDB
#undef CMPV
#undef CMPU
#undef DIAG
}

// w[b] = RS_b^T @ Z_b, RS reconstructed as h+l.
__global__ __launch_bounds__(256)
void out_kernel(const u16* __restrict__ Sh, const u16* __restrict__ Sl,
                const float* __restrict__ Z, float* __restrict__ Wout)
{
    __shared__ float Rt[BK][64 + 4];
    __shared__ float Zt[BK][64 + 4];
    const int tid = threadIdx.x;
    const int b   = blockIdx.y;
    const int d0  = blockIdx.x * 64;
    const int kk  = tid >> 4, cq = (tid & 15) << 2;
    const int ty  = tid >> 4, tx = tid & 15;
    float acc[4][4] = {};

    for (int k0 = 0; k0 < Tt; k0 += BK) {
        const size_t ri = (size_t)(b * Tt + k0 + kk) * RES + d0 + cq;
        const u16x4 hv = *(const u16x4*)&Sh[ri];
        const u16x4 lv = *(const u16x4*)&Sl[ri];
        Rt[kk][cq + 0] = bf2f(hv[0]) + bf2f(lv[0]);
        Rt[kk][cq + 1] = bf2f(hv[1]) + bf2f(lv[1]);
        Rt[kk][cq + 2] = bf2f(hv[2]) + bf2f(lv[2]);
        Rt[kk][cq + 3] = bf2f(hv[3]) + bf2f(lv[3]);
        *(float4*)&Zt[kk][cq] =
            *(const float4*)(Z + ((size_t)b * Tt + k0 + kk) * OUTd + cq);
        __syncthreads();
        MICRO(Rt, Zt);
        __syncthreads();
    }
#pragma unroll
    for (int a = 0; a < 4; ++a) {
        const int d = d0 + (ty << 2) + a;
        *(float4*)(Wout + ((size_t)b * RES + d) * OUTd + (tx << 2)) =
            make_float4(acc[a][0], acc[a][1], acc[a][2], acc[a][3]);
    }
}

// bias: 256 threads/batch, 4 partial sums of 128 rows each + LDS reduce.
__global__ __launch_bounds__(256)
void bias_kernel(const float* __restrict__ Z, float* __restrict__ Bout)
{
    __shared__ float S[4][64];
    const int b = blockIdx.x;
    const int o = threadIdx.x & 63, g = threadIdx.x >> 6;
    const float* Zb = Z + (size_t)b * Tt * OUTd;
    float s = 0.f;
    for (int n = g * 128; n < (g + 1) * 128; ++n) s += Zb[(size_t)n * OUTd + o];
    S[g][o] = s;
    __syncthreads();
    if (threadIdx.x < 64)
        Bout[(size_t)b * OUTd + o] = ((S[0][o] + S[1][o]) + S[2][o]) + S[3][o];
}

extern "C" void kernel_launch(void* const* d_in, const int* in_sizes, int n_in,
                              void* d_out, int out_size, void* d_ws, size_t ws_size,
                              hipStream_t stream)
{
    const float* X    = (const float*)d_in[0];   // (32,512,128)
    const float* Y    = (const float*)d_in[1];   // (32,512,64)
    const float* Wres = (const float*)d_in[2];   // (2048,2048)
    const float* Win  = (const float*)d_in[3];   // (128,2048)
    const float* lam  = (const float*)d_in[4];   // scalar

    float* out  = (float*)d_out;
    float* Wout = out;
    float* Bout = out + (size_t)Bb * RES * OUTd;

    // ws: Sh 64 | Sl 64 | WTh 8 | WTl 8 | WinTh .5 | WinTl .5 | A 32 | Z 4 | Wi 4 | WiT 4 = 189 MB
    char* p = (char*)d_ws;
    u16* Sh    = (u16*)p;   p += (size_t)Bb * Tt * RES * 2;
    u16* Sl    = (u16*)p;   p += (size_t)Bb * Tt * RES * 2;
    u16* WTh   = (u16*)p;   p += (size_t)RES * RES * 2;
    u16* WTl   = (u16*)p;   p += (size_t)RES * RES * 2;
    u16* WinTh = (u16*)p;   p += (size_t)INd * RES * 2;
    u16* WinTl = (u16*)p;   p += (size_t)INd * RES * 2;
    float* A   = (float*)p; p += (size_t)Bb * 512 * 512 * 4;
    float* Z   = (float*)p; p += (size_t)Bb * Tt * OUTd * 4;
    float* Wi  = (float*)p; p += (size_t)Bb * 8 * 64 * 64 * 4;
    float* WiT = (float*)p;

    const dim3 blk(256);
    tconv_kernel<<<dim3(RES / 64, RES / 64), blk, 0, stream>>>(Wres, WTh, WTl, RES, RES);
    tconv_kernel<<<dim3(RES / 64, INd / 64), blk, 0, stream>>>(Win, WinTh, WinTl, INd, RES);

    // classes: s:(cin->cout) 0:(-,2) 1:(2,1) 2:(1,0) 3:(0,1) 4:(1,2) 5:(2,3)
    const dim3 sgrid(RES / 128, Bb);
    step_mfma_kernel<<<sgrid, blk, 0, stream>>>(Sh, Sl, X, WTh, WTl, WinTh, WinTl, 0, 2, 0);
    step_mfma_kernel<<<sgrid, blk, 0, stream>>>(Sh, Sl, X, WTh, WTl, WinTh, WinTl, 2, 1, 1);
    step_mfma_kernel<<<sgrid, blk, 0, stream>>>(Sh, Sl, X, WTh, WTl, WinTh, WinTl, 1, 0, 2);
    step_mfma_kernel<<<sgrid, blk, 0, stream>>>(Sh, Sl, X, WTh, WTl, WinTh, WinTl, 0, 1, 3);
    step_mfma_kernel<<<sgrid, blk, 0, stream>>>(Sh, Sl, X, WTh, WTl, WinTh, WinTl, 1, 2, 4);
    step_mfma_kernel<<<sgrid, blk, 0, stream>>>(Sh, Sl, X, WTh, WTl, WinTh, WinTl, 2, 3, 5);

    gram_mfma_kernel<<<dim3(10, Bb), blk, 0, stream>>>(Sh, Sl, A, lam);

    for (int k = 0; k < 8; ++k) {
        chol_diag_inv_kernel<<<dim3(Bb), dim3(256), 0, stream>>>(A, Wi, WiT, k);
        if (k < 7) {
            trsm_kernel<<<dim3(7 - k, Bb), blk, 0, stream>>>(A, WiT, k);
            const int m = 7 - k;
            chol_trailing_kernel<<<dim3(m * (m + 1) / 2, Bb), blk, 0, stream>>>(A, k);
        }
    }
    fb_solve4_kernel<<<dim3(Bb * 8), dim3(256), 0, stream>>>(A, Wi, WiT, Y, Z);

    out_kernel<<<dim3(RES / 64, Bb), blk, 0, stream>>>(Sh, Sl, Z, Wout);
    bias_kernel<<<dim3(Bb), dim3(256), 0, stream>>>(Z, Bout);
}

// Round 11
// 1920.530 us; speedup vs baseline: 1.4721x; 1.0043x over previous
//
#include <hip/hip_runtime.h>
#include <cmath>

#define Bb   32
#define Tt   512
#define INd  128
#define RES  2048
#define OUTd 64

#define BM 64
#define BN 64
#define BK 16

typedef unsigned short u16;
typedef __attribute__((ext_vector_type(4))) unsigned short u16x4;
typedef __attribute__((ext_vector_type(8))) unsigned short u16x8;
typedef __attribute__((ext_vector_type(8))) short bf8;
typedef __attribute__((ext_vector_type(4))) float f32x4;

// fp32 = bf16 hi (RNE) + bf16 lo (trunc residual); |err| <= 2^-17 |a|
__device__ __forceinline__ void splitf(float a, u16& h, u16& l) {
    unsigned u = __float_as_uint(a);
    unsigned r = (u + 0x7fffu + ((u >> 16) & 1u)) & 0xffff0000u;
    h = (u16)(r >> 16);
    float d = a - __uint_as_float(r);
    l = (u16)(__float_as_uint(d) >> 16);
}
__device__ __forceinline__ float bf2f(u16 h) {
    return __uint_as_float((unsigned)h << 16);
}
__device__ __forceinline__ void split8(const float4& a, const float4& b,
                                       u16x8& h, u16x8& l) {
    u16 hh, ll;
    splitf(a.x, hh, ll); h[0] = hh; l[0] = ll;
    splitf(a.y, hh, ll); h[1] = hh; l[1] = ll;
    splitf(a.z, hh, ll); h[2] = hh; l[2] = ll;
    splitf(a.w, hh, ll); h[3] = hh; l[3] = ll;
    splitf(b.x, hh, ll); h[4] = hh; l[4] = ll;
    splitf(b.y, hh, ll); h[5] = hh; l[5] = ll;
    splitf(b.z, hh, ll); h[6] = hh; l[6] = ll;
    splitf(b.w, hh, ll); h[7] = hh; l[7] = ll;
}

// async global->LDS, 16B per lane. LDS dest is wave-uniform base + lane*16;
// global src is per-lane (carries the chunk swizzle).
__device__ __forceinline__ void gl_lds16(const u16* g, u16* l) {
    __builtin_amdgcn_global_load_lds(
        (const __attribute__((address_space(1))) unsigned int*)g,
        (__attribute__((address_space(3))) unsigned int*)l,
        16, 0, 0);
}

#define MICRO(SA, SB)                                                           \
  do {                                                                          \
    _Pragma("unroll")                                                           \
    for (int kk = 0; kk < BK; ++kk) {                                           \
      const float4 a4 = *(const float4*)&SA[kk][ty << 2];                       \
      const float4 b4 = *(const float4*)&SB[kk][tx << 2];                       \
      acc[0][0] += a4.x*b4.x; acc[0][1] += a4.x*b4.y;                           \
      acc[0][2] += a4.x*b4.z; acc[0][3] += a4.x*b4.w;                           \
      acc[1][0] += a4.y*b4.x; acc[1][1] += a4.y*b4.y;                           \
      acc[1][2] += a4.y*b4.z; acc[1][3] += a4.y*b4.w;                           \
      acc[2][0] += a4.z*b4.x; acc[2][1] += a4.z*b4.y;                           \
      acc[2][2] += a4.z*b4.z; acc[2][3] += a4.z*b4.w;                           \
      acc[3][0] += a4.w*b4.x; acc[3][1] += a4.w*b4.y;                           \
      acc[3][2] += a4.w*b4.z; acc[3][3] += a4.w*b4.w;                           \
    }                                                                           \
  } while (0)

// 128x128 tile, K=32 slice, bf16x3. Linear LDS rows of 32 u16 (64 B) with
// 16B-chunk XOR swizzle c' = c ^ ((row>>1)&3)  ->  max 2-way bank alias (free).
// Buffer layout (u16 offsets): Ah 0 | Al 4096 | Bh 8192 | Bl 12288.
#define MFMA_TILE(BUF)                                                           \
  do {                                                                           \
    bf8 aH[4], aL[4], bH[4], bL[4];                                              \
    const int qd = (quad ^ ((l15 >> 1) & 3)) << 3;                               \
    _Pragma("unroll")                                                            \
    for (int i = 0; i < 4; ++i) {                                                \
      const int ar = (wm*64 + i*16 + l15)*32 + qd;                               \
      const int br = (wn*64 + i*16 + l15)*32 + qd;                               \
      aH[i] = *(const bf8*)&(BUF)[ar];                                           \
      aL[i] = *(const bf8*)&(BUF)[4096 + ar];                                    \
      bH[i] = *(const bf8*)&(BUF)[8192 + br];                                    \
      bL[i] = *(const bf8*)&(BUF)[12288 + br];                                   \
    }                                                                            \
    _Pragma("unroll")                                                            \
    for (int i = 0; i < 4; ++i)                                                  \
      _Pragma("unroll")                                                          \
      for (int j = 0; j < 4; ++j) {                                              \
        acc[i][j] = __builtin_amdgcn_mfma_f32_16x16x32_bf16(aH[i], bH[j], acc[i][j], 0, 0, 0); \
        acc[i][j] = __builtin_amdgcn_mfma_f32_16x16x32_bf16(aH[i], bL[j], acc[i][j], 0, 0, 0); \
        acc[i][j] = __builtin_amdgcn_mfma_f32_16x16x32_bf16(aL[i], bH[j], acc[i][j], 0, 0, 0); \
      }                                                                          \
  } while (0)

// Transpose + split weights: in (K x N fp32) -> outH/outL (N x K bf16).
__global__ __launch_bounds__(256)
void tconv_kernel(const float* __restrict__ in, u16* __restrict__ outH,
                  u16* __restrict__ outL, int K, int N)
{
    __shared__ float T[64][65];
    const int n0 = blockIdx.x * 64, k0 = blockIdx.y * 64;
    const int t = threadIdx.x;
    const int r = t >> 2, c0 = (t & 3) * 16;
#pragma unroll
    for (int i = 0; i < 4; ++i) {
        const float4 v = *(const float4*)&in[(size_t)(k0 + r) * N + n0 + c0 + 4*i];
        T[r][c0 + 4*i + 0] = v.x; T[r][c0 + 4*i + 1] = v.y;
        T[r][c0 + 4*i + 2] = v.z; T[r][c0 + 4*i + 3] = v.w;
    }
    __syncthreads();
    const int n = t >> 2, ck = (t & 3) * 16;
    u16x8 h0, h1, l0, l1;
#pragma unroll
    for (int i = 0; i < 8; ++i) { u16 h, l; splitf(T[ck + i][n], h, l); h0[i] = h; l0[i] = l; }
#pragma unroll
    for (int i = 0; i < 8; ++i) { u16 h, l; splitf(T[ck + 8 + i][n], h, l); h1[i] = h; l1[i] = l; }
    const size_t ob = (size_t)(n0 + n) * K + k0 + ck;
    *(u16x8*)&outH[ob] = h0; *(u16x8*)&outH[ob + 8] = h1;
    *(u16x8*)&outL[ob] = l0; *(u16x8*)&outL[ob + 8] = l1;
}

// Reservoir step on bf16 hi/lo state planes (row = b*512 + 4w + class).
// Replay-verified __syncthreads staging; XCD swizzle REVERTED (R10: -2.4x
// HBM traffic but +9% time -- kernel is L2-locality/structure-bound, and the
// plain mapping keeps same-batch blocks (sharing the A state panel) co-hot).
// Epilogue/input-proj use __sinf (hw v_sin path): abs err ~1e-6, invisible
// under the bf16x3 1.95e-3 floor and 7.46e-3 threshold.
__global__ __launch_bounds__(256)
void step_mfma_kernel(u16* __restrict__ Sh, u16* __restrict__ Sl,
                      const float* __restrict__ X,
                      const u16* __restrict__ WTh, const u16* __restrict__ WTl,
                      const u16* __restrict__ WinTh, const u16* __restrict__ WinTl,
                      int cin, int cout, int s)
{
    __shared__ u16 LB[2 * 16384];             // 2 x 32 KB slice buffers
    u16* buf0 = LB;
    u16* buf1 = LB + 16384;
    float* Cf = (float*)LB;                   // 64x128 f32 = 32 KB (epilogue)

    const int tid = threadIdx.x;
    const int q0  = blockIdx.x * 128;         // reservoir-col tile
    const int b   = blockIdx.y;
    const int bofs = b * Tt;
    const int wid = tid >> 6, lane = tid & 63;
    const int wm = wid & 1, wn = wid >> 1;
    const int l15 = lane & 15, quad = lane >> 4;

    f32x4 acc[4][4];
    const f32x4 zz = {0.f, 0.f, 0.f, 0.f};
#pragma unroll
    for (int i = 0; i < 4; ++i)
#pragma unroll
        for (int j = 0; j < 4; ++j) acc[i][j] = zz;

    // per-wave slice staging: wid 0=Ah(Sh) 1=Al(Sl) 2=Bh(WTh) 3=Bl(WTl).
    const int rl    = lane >> 2;
    const int csrc  = (((lane & 3) ^ ((lane >> 3) & 3)) << 3);
    const u16* plane = (wid == 0) ? (const u16*)Sh
                     : (wid == 1) ? (const u16*)Sl
                     : (wid == 2) ? WTh : WTl;

    auto stage = [&](u16* buf, int k0) {
        u16* ldst = buf + wid * 4096;
#pragma unroll
        for (int i = 0; i < 8; ++i) {
            const int r = i * 16 + rl;
            const size_t grow = (wid < 2) ? (size_t)(bofs + 4 * r + cin)
                                          : (size_t)(q0 + r);
            gl_lds16(&plane[grow * RES + k0 + csrc], ldst + i * 512);
        }
    };

    if (s > 0) {
        stage(buf0, 0);
        __syncthreads();                      // drains vmcnt -> buf0 ready
        for (int k0 = 0; k0 < RES; k0 += 32) {
            u16* cur = (k0 & 32) ? buf1 : buf0;
            u16* nxt = (k0 & 32) ? buf0 : buf1;
            if (k0 + 32 < RES) stage(nxt, k0 + 32);
            MFMA_TILE(cur);
            __syncthreads();                  // nxt staged; cur reads done
        }
    }

    // input projection: K=128 over x[b, 4w+s-2, :] @ Win.
    for (int k0 = 0; k0 < INd; k0 += 32) {
        if (tid < 128) {
            const int rrow = tid;             // 0..127
            const int t = 4 * rrow + s - 2;
            u16x8 h0 = {0,0,0,0,0,0,0,0}, h1 = h0, h2 = h0, h3 = h0;
            u16x8 l0 = h0, l1 = h0, l2 = h0, l3 = h0;
            if (t >= 0) {
                const float* xr = X + (size_t)(bofs + t) * INd + k0;
                const float4 f0 = *(const float4*)&xr[0];
                const float4 f1 = *(const float4*)&xr[4];
                const float4 f2 = *(const float4*)&xr[8];
                const float4 f3 = *(const float4*)&xr[12];
                const float4 f4 = *(const float4*)&xr[16];
                const float4 f5 = *(const float4*)&xr[20];
                const float4 f6 = *(const float4*)&xr[24];
                const float4 f7 = *(const float4*)&xr[28];
                split8(f0, f1, h0, l0); split8(f2, f3, h1, l1);
                split8(f4, f5, h2, l2); split8(f6, f7, h3, l3);
            }
            const int sw = (rrow >> 1) & 3;
            u16* dA = buf0 + rrow * 32;
            *(u16x8*)&dA[(0 ^ sw) << 3] = h0;
            *(u16x8*)&dA[(1 ^ sw) << 3] = h1;
            *(u16x8*)&dA[(2 ^ sw) << 3] = h2;
            *(u16x8*)&dA[(3 ^ sw) << 3] = h3;
            u16* dL = buf0 + 4096 + rrow * 32;
            *(u16x8*)&dL[(0 ^ sw) << 3] = l0;
            *(u16x8*)&dL[(1 ^ sw) << 3] = l1;
            *(u16x8*)&dL[(2 ^ sw) << 3] = l2;
            *(u16x8*)&dL[(3 ^ sw) << 3] = l3;
        } else {
            const u16* wpl = (wid == 2) ? WinTh : WinTl;
            u16* ldst = buf0 + wid * 4096;
#pragma unroll
            for (int i = 0; i < 8; ++i) {
                const int r = i * 16 + rl;
                gl_lds16(&wpl[(size_t)(q0 + r) * INd + k0 + csrc], ldst + i * 512);
            }
        }
        __syncthreads();
        MFMA_TILE(buf0);
        __syncthreads();
    }

    // epilogue via LDS: all global I/O is coalesced u16x8.
    for (int h = 0; h < 2; ++h) {
        __syncthreads();
        if (wm == h) {
#pragma unroll
            for (int i = 0; i < 4; ++i)
#pragma unroll
                for (int j = 0; j < 4; ++j)
#pragma unroll
                    for (int rg = 0; rg < 4; ++rg)
                        Cf[(i * 16 + quad * 4 + rg) * 128 + wn * 64 + j * 16 + l15]
                            = acc[i][j][rg];
        }
        __syncthreads();
#pragma unroll
        for (int pass = 0; pass < 4; ++pass) {
            const int r  = (tid >> 4) + pass * 16;      // 0..63
            const int c0 = (tid & 15) * 8;              // 0..120
            const int wrow = h * 64 + r;
            const float4 v0 = *(const float4*)&Cf[r * 128 + c0];
            const float4 v1 = *(const float4*)&Cf[r * 128 + c0 + 4];
            float vv[8] = {v0.x, v0.y, v0.z, v0.w, v1.x, v1.y, v1.z, v1.w};
            u16x8 ph, pl;
            if (s > 0) {
                const size_t prow = (size_t)(bofs + 4 * wrow + cin) * RES + q0 + c0;
                ph = *(const u16x8*)&Sh[prow];
                pl = *(const u16x8*)&Sl[prow];
            }
            u16x8 oh, ol;
#pragma unroll
            for (int e = 0; e < 8; ++e) {
                float prev = (s > 0) ? (bf2f(ph[e]) + bf2f(pl[e])) : 0.f;
                float v = 0.7f * prev + 0.3f * __sinf(vv[e]);
                u16 hh, ll; splitf(v, hh, ll);
                oh[e] = hh; ol[e] = ll;
            }
            const size_t orow = (size_t)(bofs + 4 * wrow + cout) * RES + q0 + c0;
            *(u16x8*)&Sh[orow] = oh;
            *(u16x8*)&Sl[orow] = ol;
        }
    }
}

// Gram on bf16 planes: A[b] = (Sh+Sl)(Sh+Sl)^T + ones + reg*I, bf16x3.
__global__ __launch_bounds__(256)
void gram_mfma_kernel(const u16* __restrict__ Sh, const u16* __restrict__ Sl,
                      float* __restrict__ A, const float* __restrict__ lam)
{
    __shared__ u16 LB[2 * 16384];
    u16* buf0 = LB;
    u16* buf1 = LB + 16384;
    float* Cf = (float*)LB;                   // 64 x 132 f32 = 33.8 KB

    const int tid = threadIdx.x;
    const int bt  = blockIdx.y;
    int ti = 0, rem = (int)blockIdx.x;
    while (rem >= 4 - ti) { rem -= 4 - ti; ++ti; }
    const int tj = ti + rem;
    const int n0 = ti * 128, m0 = tj * 128;
    const int bofs = bt * Tt;

    const int wid = tid >> 6, lane = tid & 63;
    const int wm = wid & 1, wn = wid >> 1;
    const int l15 = lane & 15, quad = lane >> 4;

    f32x4 acc[4][4];
    const f32x4 zz = {0.f, 0.f, 0.f, 0.f};
#pragma unroll
    for (int i = 0; i < 4; ++i)
#pragma unroll
        for (int j = 0; j < 4; ++j) acc[i][j] = zz;

    const int rl    = lane >> 2;
    const int csrc  = (((lane & 3) ^ ((lane >> 3) & 3)) << 3);
    const u16* plane = (wid & 1) ? Sl : Sh;
    const int rbase  = (wid < 2) ? n0 : m0;

    auto stage = [&](u16* buf, int k0) {
        u16* ldst = buf + wid * 4096;
#pragma unroll
        for (int i = 0; i < 8; ++i) {
            const int r = i * 16 + rl;
            gl_lds16(&plane[(size_t)(bofs + rbase + r) * RES + k0 + csrc],
                     ldst + i * 512);
        }
    };

    stage(buf0, 0);
    __syncthreads();
    for (int k0 = 0; k0 < RES; k0 += 32) {
        u16* cur = (k0 & 32) ? buf1 : buf0;
        u16* nxt = (k0 & 32) ? buf0 : buf1;
        if (k0 + 32 < RES) stage(nxt, k0 + 32);
        MFMA_TILE(cur);
        __syncthreads();
    }

    const float reg = log1pf(expf(lam[0]));
    float* Ab = A + (size_t)bt * 512 * 512;
    for (int h = 0; h < 2; ++h) {
        __syncthreads();
        if (wm == h) {
#pragma unroll
            for (int i = 0; i < 4; ++i)
#pragma unroll
                for (int j = 0; j < 4; ++j)
#pragma unroll
                    for (int rg = 0; rg < 4; ++rg)
                        Cf[(i * 16 + quad * 4 + rg) * 132 + wn * 64 + j * 16 + l15]
                            = acc[i][j][rg];
        }
        __syncthreads();
        // row-major half: rows nn = n0+h*64+r, cols m0..m0+127
#pragma unroll
        for (int pass = 0; pass < 4; ++pass) {
            const int r  = (tid >> 4) + pass * 16;
            const int c0 = (tid & 15) * 8;
            const int nn = n0 + h * 64 + r;
            float o[8];
#pragma unroll
            for (int e = 0; e < 8; ++e) {
                const int mm = m0 + c0 + e;
                float v = Cf[r * 132 + c0 + e] + 1.0f;
                if (nn == mm) v += reg;
                o[e] = v;
            }
            float* dst = Ab + (size_t)nn * 512 + m0 + c0;
            *(float4*)&dst[0] = make_float4(o[0], o[1], o[2], o[3]);
            *(float4*)&dst[4] = make_float4(o[4], o[5], o[6], o[7]);
        }
        // transposed half: rows mm = m0+rt, cols n0+h*64 .. +63
#pragma unroll
        for (int pass = 0; pass < 4; ++pass) {
            const int rt  = (tid >> 3) + pass * 32;     // 0..127
            const int c0t = (tid & 7) * 8;              // 0..56
            const int mm  = m0 + rt;
            float o[8];
#pragma unroll
            for (int e = 0; e < 8; ++e) {
                const int nn = n0 + h * 64 + c0t + e;
                float v = Cf[(c0t + e) * 132 + rt] + 1.0f;
                if (nn == mm) v += reg;
                o[e] = v;
            }
            float* dst = Ab + (size_t)mm * 512 + n0 + h * 64 + c0t;
            *(float4*)&dst[0] = make_float4(o[0], o[1], o[2], o[3]);
            *(float4*)&dst[4] = make_float4(o[4], o[5], o[6], o[7]);
        }
    }
}

// Diag-block Cholesky (64x64) + inverse, v3: RAW-pivot fused single-phase.
__global__ __launch_bounds__(256)
void chol_diag_inv_kernel(float* __restrict__ Aall, float* __restrict__ Winv,
                          float* __restrict__ WinvT, int k)
{
    __shared__ float P[64][65];
    __shared__ float W[64][65];
    const int b = blockIdx.x, tid = threadIdx.x;
    float* A = Aall + (size_t)b * 512 * 512;
    const int j0 = 64 * k;
    const int r = tid & 63;          // row (factor) / RHS column (inverse)
    const int q = tid >> 6;          // 16-wide strip (wave-uniform)

    // load 64x64 (each thread 16 floats); W = I
    {
        const int lr = tid >> 2, lc = (tid & 3) * 16;
#pragma unroll
        for (int i = 0; i < 4; ++i) {
            const float4 v = *(const float4*)(A + (size_t)(j0 + lr) * 512 + j0 + lc + 4*i);
            P[lr][lc + 4*i + 0] = v.x; P[lr][lc + 4*i + 1] = v.y;
            P[lr][lc + 4*i + 2] = v.z; P[lr][lc + 4*i + 3] = v.w;
        }
    }
    for (int t = tid; t < 4096; t += 256)
        W[t >> 6][t & 63] = ((t >> 6) == (t & 63)) ? 1.f : 0.f;
    __syncthreads();

    for (int j = 0; j < 64; ++j) {
        const float rd2 = 1.0f / P[j][j];        // raw pivot (pre-sqrt)
        const float tfa = P[r][j] * rd2;         // factor coefficient
        const float cwd = W[j][r] * rd2;         // inverse coefficient
        float pm[16];
#pragma unroll
        for (int i = 0; i < 16; ++i) pm[i] = P[q * 16 + i][j];
#pragma unroll
        for (int i = 0; i < 16; ++i) {
            const int m = q * 16 + i;
            if (m > j && m <= r) P[r][m] -= tfa * pm[i];
        }
#pragma unroll
        for (int i = 0; i < 16; ++i) {
            const int m = q * 16 + i;
            if (m > j) W[m][r] -= pm[i] * cwd;
        }
        __syncthreads();
    }

    // write back L: lower strictly = raw/sqrt(diag), diag = sqrt, upper = A.
    {
        const int lr = tid >> 2, lc = (tid & 3) * 16;
#pragma unroll
        for (int i = 0; i < 4; ++i) {
            float o[4];
#pragma unroll
            for (int e = 0; e < 4; ++e) {
                const int c = lc + 4*i + e;
                const float pv = P[lr][c];
                if (c < lr)       o[e] = pv / sqrtf(P[c][c]);
                else if (c == lr) o[e] = sqrtf(pv);
                else              o[e] = pv;
            }
            *(float4*)(A + (size_t)(j0 + lr) * 512 + j0 + lc + 4*i) =
                make_float4(o[0], o[1], o[2], o[3]);
        }
    }
    float* Wo  = Winv  + ((size_t)b * 8 + k) * 64 * 64;
    float* WoT = WinvT + ((size_t)b * 8 + k) * 64 * 64;
    for (int t = tid; t < 4096; t += 256) {
        const int rr = t >> 6, cc = t & 63;
        Wo[t]  = W[rr][cc] / sqrtf(P[rr][rr]);
        WoT[t] = W[cc][rr] / sqrtf(P[cc][cc]);
    }
}

// Panel TRSM via inverse: L[i0.., k] = A[i0.., k] @ W^T
__global__ __launch_bounds__(256)
void trsm_kernel(float* __restrict__ Aall, const float* __restrict__ WinvT, int k)
{
    __shared__ float St[BK][BM + 4];
    __shared__ float Wt[BK][BN + 4];
    float* A = Aall + (size_t)blockIdx.y * 512 * 512;
    const float* WT = WinvT + ((size_t)blockIdx.y * 8 + k) * 64 * 64;
    const int i0 = (k + 1 + blockIdx.x) * 64, p0 = k * 64;
    const int tid = threadIdx.x;
    const int li = tid >> 2, lk = (tid & 3) << 2;
    const int wk = tid >> 4, wq = (tid & 15) << 2;
    const int ty = tid >> 4, tx = tid & 15;
    float acc[4][4] = {};
    for (int k0 = 0; k0 < 64; k0 += BK) {
        const float4 u = *(const float4*)(A + (size_t)(i0 + li) * 512 + p0 + k0 + lk);
        St[lk + 0][li] = u.x; St[lk + 1][li] = u.y;
        St[lk + 2][li] = u.z; St[lk + 3][li] = u.w;
        *(float4*)&Wt[wk][wq] = *(const float4*)(WT + (size_t)(k0 + wk) * 64 + wq);
        __syncthreads();
        MICRO(St, Wt);
        __syncthreads();
    }
#pragma unroll
    for (int a = 0; a < 4; ++a) {
        const int r = i0 + (ty << 2) + a;
        *(float4*)(A + (size_t)r * 512 + p0 + (tx << 2)) =
            make_float4(acc[a][0], acc[a][1], acc[a][2], acc[a][3]);
    }
}

// Trailing update: A[ti,tj] -= L[ti,k] L[tj,k]^T
__global__ __launch_bounds__(256)
void chol_trailing_kernel(float* __restrict__ Aall, int k)
{
    __shared__ float Ut[BK][BM + 4];
    __shared__ float Vt[BK][BN + 4];
    float* A = Aall + (size_t)blockIdx.y * 512 * 512;
    const int tid = threadIdx.x;
    int a = 0, rem = (int)blockIdx.x;
    while (rem >= a + 1) { rem -= a + 1; ++a; }
    const int ti = k + 1 + a, tj = k + 1 + rem;
    const int i0 = ti * 64, j0c = tj * 64, p0 = k * 64;

    const int li = tid >> 2, lk = (tid & 3) << 2;
    const int ty = tid >> 4, tx = tid & 15;
    float acc[4][4] = {};

    for (int k0 = 0; k0 < 64; k0 += BK) {
        const float4 u = *(const float4*)(A + (size_t)(i0 + li) * 512 + p0 + k0 + lk);
        const float4 v = *(const float4*)(A + (size_t)(j0c + li) * 512 + p0 + k0 + lk);
        Ut[lk + 0][li] = u.x; Ut[lk + 1][li] = u.y;
        Ut[lk + 2][li] = u.z; Ut[lk + 3][li] = u.w;
        Vt[lk + 0][li] = v.x; Vt[lk + 1][li] = v.y;
        Vt[lk + 2][li] = v.z; Vt[lk + 3][li] = v.w;
        __syncthreads();
        MICRO(Ut, Vt);
        __syncthreads();
    }
#pragma unroll
    for (int aa = 0; aa < 4; ++aa) {
        const int r = i0 + (ty << 2) + aa;
        float* crow = A + (size_t)r * 512 + j0c + (tx << 2);
        float4 cv = *(const float4*)crow;
        cv.x -= acc[aa][0]; cv.y -= acc[aa][1];
        cv.z -= acc[aa][2]; cv.w -= acc[aa][3];
        *(float4*)crow = cv;
    }
}

// Blocked fwd+bwd solve, v4b: 256 blocks (32 batches x 8 col-splits), 256
// threads (thread = 1 output row x 2 cols), XCD-colocated, 4-deep static
// software pipeline with named buffers p0..p3. Replay-verified in R5/R9.
__global__ __launch_bounds__(256, 1)
void fb_solve4_kernel(const float* __restrict__ Aall,
                      const float* __restrict__ Winv,
                      const float* __restrict__ WinvT,
                      const float* __restrict__ Y, float* __restrict__ Zall)
{
    __shared__ float V[512][10];   // 8 used cols + 2 pad
    __shared__ float U[64][10];
    const int tid = threadIdx.x;
    const int b   = (int)blockIdx.x & 31;          // batch -> XCD (b mod 8)
    const int c0  = ((int)blockIdx.x >> 5) * 8;    // col-split
    const int ty  = tid >> 2;            // 0..63: output row within k-block
    const int tx  = tid & 3;             // col pair: cols 2tx, 2tx+1
    const float* A   = Aall + (size_t)b * 512 * 512;
    const float* Yb  = Y    + (size_t)b * 512 * OUTd + c0;
    float*       Zb  = Zall + (size_t)b * 512 * OUTd + c0;
    const float* Wb  = Winv  + (size_t)b * 8 * 4096 + (size_t)ty * 64;
    const float* WbT = WinvT + (size_t)b * 8 * 4096 + (size_t)ty * 64;

    for (int t = tid; t < 512 * 4; t += 256) {
        const int row = t >> 2, p = (t & 3) * 2;
        *(float2*)&V[row][p] = *(const float2*)&Yb[(size_t)row * OUTd + p];
    }
    __syncthreads();

    float acc0, acc1;
    f32x4 p0[4], p1[4], p2[4], p3[4];

#define LDF(P, c, G)                                                            \
    { const int cc_ = ((c) < (G)) ? (c) : (G) - 1;                              \
      _Pragma("unroll") for (int j_ = 0; j_ < 4; ++j_)                          \
        P[j_] = *(const f32x4*)&Arow[16 * cc_ + 4 * j_]; }

#define LDB(P, c, G)                                                            \
    { const int cc_ = ((c) < (G)) ? (c) : (G) - 1;                              \
      _Pragma("unroll") for (int j_ = 0; j_ < 16; ++j_)                         \
        P[j_ >> 2][j_ & 3] = Acol[(size_t)(m1 + 16 * cc_ + j_) * 512]; }

#define CMPV(P, kb)                                                             \
    { _Pragma("unroll") for (int q_ = 0; q_ < 16; ++q_) {                       \
        const float a_ = P[q_ >> 2][q_ & 3];                                    \
        const float2 v_ = *(const float2*)&V[(kb) + q_][2 * tx];                \
        acc0 += a_ * v_.x; acc1 += a_ * v_.y; } }

#define CMPU(P, kb)                                                             \
    { _Pragma("unroll") for (int q_ = 0; q_ < 16; ++q_) {                       \
        const float a_ = P[q_ >> 2][q_ & 3];                                    \
        const float2 v_ = *(const float2*)&U[(kb) + q_][2 * tx];                \
        acc0 += a_ * v_.x; acc1 += a_ * v_.y; } }

#define DIAG(Wrow)                                                              \
    { acc0 = 0.f; acc1 = 0.f;                                                   \
      _Pragma("unroll") for (int j_ = 0; j_ < 4; ++j_) {                        \
        p0[j_] = *(const f32x4*)&(Wrow)[ 0 + 4 * j_];                           \
        p1[j_] = *(const f32x4*)&(Wrow)[16 + 4 * j_];                           \
        p2[j_] = *(const f32x4*)&(Wrow)[32 + 4 * j_];                           \
        p3[j_] = *(const f32x4*)&(Wrow)[48 + 4 * j_]; }                         \
      CMPU(p0, 0); CMPU(p1, 16); CMPU(p2, 32); CMPU(p3, 48); }

    // ---- forward: V_k = W_k (Y_k - L[k, 0:64k] @ V) ----
    for (int k = 0; k < 8; ++k) {
        const int r0 = k * 64;
        const float* Arow = A + (size_t)(r0 + ty) * 512;
        acc0 = 0.f; acc1 = 0.f;
        const int G = r0 >> 4;                   // chunks; multiple of 4
        if (G) {
            LDF(p0, 0, G); LDF(p1, 1, G); LDF(p2, 2, G); LDF(p3, 3, G);
            for (int g = 0; g < G; g += 4) {
                CMPV(p0, 16 * g);      LDF(p0, g + 4, G);
                CMPV(p1, 16 * g + 16); LDF(p1, g + 5, G);
                CMPV(p2, 16 * g + 32); LDF(p2, g + 6, G);
                CMPV(p3, 16 * g + 48); LDF(p3, g + 7, G);
            }
        }
        U[ty][2 * tx]     = V[r0 + ty][2 * tx]     - acc0;
        U[ty][2 * tx + 1] = V[r0 + ty][2 * tx + 1] - acc1;
        __syncthreads();
        DIAG(Wb + (size_t)k * 4096);             // Winv row ty = W[ty][m]
        V[r0 + ty][2 * tx]     = acc0;
        V[r0 + ty][2 * tx + 1] = acc1;
        __syncthreads();
    }

    // ---- backward: Z_k = W_k^T (V_k - L[64(k+1):, k]^T @ Z) ----
    for (int k = 7; k >= 0; --k) {
        const int r0 = k * 64;
        const float* Acol = A + r0 + ty;
        const int m1 = r0 + 64;
        acc0 = 0.f; acc1 = 0.f;
        const int G = (448 - r0) >> 4;           // chunks; multiple of 4
        if (G) {
            LDB(p0, 0, G); LDB(p1, 1, G); LDB(p2, 2, G); LDB(p3, 3, G);
            for (int g = 0; g < G; g += 4) {
                CMPV(p0, m1 + 16 * g);      LDB(p0, g + 4, G);
                CMPV(p1, m1 + 16 * g + 16); LDB(p1, g + 5, G);
                CMPV(p2, m1 + 16 * g + 32); LDB(p2, g + 6, G);
                CMPV(p3, m1 + 16 * g + 48); LDB(p3, g + 7, G);
            }
        }
        U[ty][2 * tx]     = V[r0 + ty][2 * tx]     - acc0;
        U[ty][2 * tx + 1] = V[r0 + ty][2 * tx + 1] - acc1;
        __syncthreads();
        DIAG(WbT + (size_t)k * 4096);            // WinvT row ty = W[m][ty]
        V[r0 + ty][2 * tx]     = acc0;
        V[r0 + ty][2 * tx + 1] = acc1;
        __syncthreads();
    }

    for (int t = tid; t < 512 * 4; t += 256) {
        const int row = t >> 2, p = (t & 3) * 2;
        *(float2*)&Zb[(size_t)row * OUTd + p] = *(const float2*)&V[row][p];
    }
#undef LDF
#undef LDB
#undef CMPV
#undef CMPU
#undef DIAG
}

// w[b] = RS_b^T @ Z_b, RS reconstructed as h+l.
__global__ __launch_bounds__(256)
void out_kernel(const u16* __restrict__ Sh, const u16* __restrict__ Sl,
                const float* __restrict__ Z, float* __restrict__ Wout)
{
    __shared__ float Rt[BK][64 + 4];
    __shared__ float Zt[BK][64 + 4];
    const int tid = threadIdx.x;
    const int b   = blockIdx.y;
    const int d0  = blockIdx.x * 64;
    const int kk  = tid >> 4, cq = (tid & 15) << 2;
    const int ty  = tid >> 4, tx = tid & 15;
    float acc[4][4] = {};

    for (int k0 = 0; k0 < Tt; k0 += BK) {
        const size_t ri = (size_t)(b * Tt + k0 + kk) * RES + d0 + cq;
        const u16x4 hv = *(const u16x4*)&Sh[ri];
        const u16x4 lv = *(const u16x4*)&Sl[ri];
        Rt[kk][cq + 0] = bf2f(hv[0]) + bf2f(lv[0]);
        Rt[kk][cq + 1] = bf2f(hv[1]) + bf2f(lv[1]);
        Rt[kk][cq + 2] = bf2f(hv[2]) + bf2f(lv[2]);
        Rt[kk][cq + 3] = bf2f(hv[3]) + bf2f(lv[3]);
        *(float4*)&Zt[kk][cq] =
            *(const float4*)(Z + ((size_t)b * Tt + k0 + kk) * OUTd + cq);
        __syncthreads();
        MICRO(Rt, Zt);
        __syncthreads();
    }
#pragma unroll
    for (int a = 0; a < 4; ++a) {
        const int d = d0 + (ty << 2) + a;
        *(float4*)(Wout + ((size_t)b * RES + d) * OUTd + (tx << 2)) =
            make_float4(acc[a][0], acc[a][1], acc[a][2], acc[a][3]);
    }
}

// bias: 256 threads/batch, 4 partial sums of 128 rows each + LDS reduce.
__global__ __launch_bounds__(256)
void bias_kernel(const float* __restrict__ Z, float* __restrict__ Bout)
{
    __shared__ float S[4][64];
    const int b = blockIdx.x;
    const int o = threadIdx.x & 63, g = threadIdx.x >> 6;
    const float* Zb = Z + (size_t)b * Tt * OUTd;
    float s = 0.f;
    for (int n = g * 128; n < (g + 1) * 128; ++n) s += Zb[(size_t)n * OUTd + o];
    S[g][o] = s;
    __syncthreads();
    if (threadIdx.x < 64)
        Bout[(size_t)b * OUTd + o] = ((S[0][o] + S[1][o]) + S[2][o]) + S[3][o];
}

extern "C" void kernel_launch(void* const* d_in, const int* in_sizes, int n_in,
                              void* d_out, int out_size, void* d_ws, size_t ws_size,
                              hipStream_t stream)
{
    const float* X    = (const float*)d_in[0];   // (32,512,128)
    const float* Y    = (const float*)d_in[1];   // (32,512,64)
    const float* Wres = (const float*)d_in[2];   // (2048,2048)
    const float* Win  = (const float*)d_in[3];   // (128,2048)
    const float* lam  = (const float*)d_in[4];   // scalar

    float* out  = (float*)d_out;
    float* Wout = out;
    float* Bout = out + (size_t)Bb * RES * OUTd;

    // ws: Sh 64 | Sl 64 | WTh 8 | WTl 8 | WinTh .5 | WinTl .5 | A 32 | Z 4 | Wi 4 | WiT 4 = 189 MB
    char* p = (char*)d_ws;
    u16* Sh    = (u16*)p;   p += (size_t)Bb * Tt * RES * 2;
    u16* Sl    = (u16*)p;   p += (size_t)Bb * Tt * RES * 2;
    u16* WTh   = (u16*)p;   p += (size_t)RES * RES * 2;
    u16* WTl   = (u16*)p;   p += (size_t)RES * RES * 2;
    u16* WinTh = (u16*)p;   p += (size_t)INd * RES * 2;
    u16* WinTl = (u16*)p;   p += (size_t)INd * RES * 2;
    float* A   = (float*)p; p += (size_t)Bb * 512 * 512 * 4;
    float* Z   = (float*)p; p += (size_t)Bb * Tt * OUTd * 4;
    float* Wi  = (float*)p; p += (size_t)Bb * 8 * 64 * 64 * 4;
    float* WiT = (float*)p;

    const dim3 blk(256);
    tconv_kernel<<<dim3(RES / 64, RES / 64), blk, 0, stream>>>(Wres, WTh, WTl, RES, RES);
    tconv_kernel<<<dim3(RES / 64, INd / 64), blk, 0, stream>>>(Win, WinTh, WinTl, INd, RES);

    // classes: s:(cin->cout) 0:(-,2) 1:(2,1) 2:(1,0) 3:(0,1) 4:(1,2) 5:(2,3)
    const dim3 sgrid(RES / 128, Bb);
    step_mfma_kernel<<<sgrid, blk, 0, stream>>>(Sh, Sl, X, WTh, WTl, WinTh, WinTl, 0, 2, 0);
    step_mfma_kernel<<<sgrid, blk, 0, stream>>>(Sh, Sl, X, WTh, WTl, WinTh, WinTl, 2, 1, 1);
    step_mfma_kernel<<<sgrid, blk, 0, stream>>>(Sh, Sl, X, WTh, WTl, WinTh, WinTl, 1, 0, 2);
    step_mfma_kernel<<<sgrid, blk, 0, stream>>>(Sh, Sl, X, WTh, WTl, WinTh, WinTl, 0, 1, 3);
    step_mfma_kernel<<<sgrid, blk, 0, stream>>>(Sh, Sl, X, WTh, WTl, WinTh, WinTl, 1, 2, 4);
    step_mfma_kernel<<<sgrid, blk, 0, stream>>>(Sh, Sl, X, WTh, WTl, WinTh, WinTl, 2, 3, 5);

    gram_mfma_kernel<<<dim3(10, Bb), blk, 0, stream>>>(Sh, Sl, A, lam);

    for (int k = 0; k < 8; ++k) {
        chol_diag_inv_kernel<<<dim3(Bb), dim3(256), 0, stream>>>(A, Wi, WiT, k);
        if (k < 7) {
            trsm_kernel<<<dim3(7 - k, Bb), blk, 0, stream>>>(A, WiT, k);
            const int m = 7 - k;
            chol_trailing_kernel<<<dim3(m * (m + 1) / 2, Bb), blk, 0, stream>>>(A, k);
        }
    }
    fb_solve4_kernel<<<dim3(Bb * 8), dim3(256), 0, stream>>>(A, Wi, WiT, Y, Z);

    out_kernel<<<dim3(RES / 64, Bb), blk, 0, stream>>>(Sh, Sl, Z, Wout);
    bias_kernel<<<dim3(Bb), dim3(256), 0, stream>>>(Z, Bout);
}

// Round 12
// 1700.324 us; speedup vs baseline: 1.6628x; 1.1295x over previous
//
#include <hip/hip_runtime.h>
#include <cmath>

#define Bb   32
#define Tt   512
#define INd  128
#define RES  2048
#define OUTd 64

#define BM 64
#define BN 64
#define BK 16

typedef unsigned short u16;
typedef __attribute__((ext_vector_type(4))) unsigned short u16x4;
typedef __attribute__((ext_vector_type(8))) unsigned short u16x8;
typedef __attribute__((ext_vector_type(8))) short bf8;
typedef __attribute__((ext_vector_type(4))) float f32x4;

// fp32 = bf16 hi (RNE) + bf16 lo (trunc residual); |err| <= 2^-17 |a|
__device__ __forceinline__ void splitf(float a, u16& h, u16& l) {
    unsigned u = __float_as_uint(a);
    unsigned r = (u + 0x7fffu + ((u >> 16) & 1u)) & 0xffff0000u;
    h = (u16)(r >> 16);
    float d = a - __uint_as_float(r);
    l = (u16)(__float_as_uint(d) >> 16);
}
__device__ __forceinline__ float bf2f(u16 h) {
    return __uint_as_float((unsigned)h << 16);
}
__device__ __forceinline__ void split8(const float4& a, const float4& b,
                                       u16x8& h, u16x8& l) {
    u16 hh, ll;
    splitf(a.x, hh, ll); h[0] = hh; l[0] = ll;
    splitf(a.y, hh, ll); h[1] = hh; l[1] = ll;
    splitf(a.z, hh, ll); h[2] = hh; l[2] = ll;
    splitf(a.w, hh, ll); h[3] = hh; l[3] = ll;
    splitf(b.x, hh, ll); h[4] = hh; l[4] = ll;
    splitf(b.y, hh, ll); h[5] = hh; l[5] = ll;
    splitf(b.z, hh, ll); h[6] = hh; l[6] = ll;
    splitf(b.w, hh, ll); h[7] = hh; l[7] = ll;
}

// async global->LDS, 16B per lane. LDS dest is wave-uniform base + lane*16;
// global src is per-lane (carries the chunk swizzle).
__device__ __forceinline__ void gl_lds16(const u16* g, u16* l) {
    __builtin_amdgcn_global_load_lds(
        (const __attribute__((address_space(1))) unsigned int*)g,
        (__attribute__((address_space(3))) unsigned int*)l,
        16, 0, 0);
}

#define MICRO(SA, SB)                                                           \
  do {                                                                          \
    _Pragma("unroll")                                                           \
    for (int kk = 0; kk < BK; ++kk) {                                           \
      const float4 a4 = *(const float4*)&SA[kk][ty << 2];                       \
      const float4 b4 = *(const float4*)&SB[kk][tx << 2];                       \
      acc[0][0] += a4.x*b4.x; acc[0][1] += a4.x*b4.y;                           \
      acc[0][2] += a4.x*b4.z; acc[0][3] += a4.x*b4.w;                           \
      acc[1][0] += a4.y*b4.x; acc[1][1] += a4.y*b4.y;                           \
      acc[1][2] += a4.y*b4.z; acc[1][3] += a4.y*b4.w;                           \
      acc[2][0] += a4.z*b4.x; acc[2][1] += a4.z*b4.y;                           \
      acc[2][2] += a4.z*b4.z; acc[2][3] += a4.z*b4.w;                           \
      acc[3][0] += a4.w*b4.x; acc[3][1] += a4.w*b4.y;                           \
      acc[3][2] += a4.w*b4.z; acc[3][3] += a4.w*b4.w;                           \
    }                                                                           \
  } while (0)

// 128x128 tile, K=32 slice, bf16x3. Linear LDS rows of 32 u16 (64 B) with
// 16B-chunk XOR swizzle c' = c ^ ((row>>1)&3)  ->  max 2-way bank alias (free).
// Buffer layout (u16 offsets): Ah 0 | Al 4096 | Bh 8192 | Bl 12288.
#define MFMA_TILE(BUF)                                                           \
  do {                                                                           \
    bf8 aH[4], aL[4], bH[4], bL[4];                                              \
    const int qd = (quad ^ ((l15 >> 1) & 3)) << 3;                               \
    _Pragma("unroll")                                                            \
    for (int i = 0; i < 4; ++i) {                                                \
      const int ar = (wm*64 + i*16 + l15)*32 + qd;                               \
      const int br = (wn*64 + i*16 + l15)*32 + qd;                               \
      aH[i] = *(const bf8*)&(BUF)[ar];                                           \
      aL[i] = *(const bf8*)&(BUF)[4096 + ar];                                    \
      bH[i] = *(const bf8*)&(BUF)[8192 + br];                                    \
      bL[i] = *(const bf8*)&(BUF)[12288 + br];                                   \
    }                                                                            \
    _Pragma("unroll")                                                            \
    for (int i = 0; i < 4; ++i)                                                  \
      _Pragma("unroll")                                                          \
      for (int j = 0; j < 4; ++j) {                                              \
        acc[i][j] = __builtin_amdgcn_mfma_f32_16x16x32_bf16(aH[i], bH[j], acc[i][j], 0, 0, 0); \
        acc[i][j] = __builtin_amdgcn_mfma_f32_16x16x32_bf16(aH[i], bL[j], acc[i][j], 0, 0, 0); \
        acc[i][j] = __builtin_amdgcn_mfma_f32_16x16x32_bf16(aL[i], bH[j], acc[i][j], 0, 0, 0); \
      }                                                                          \
  } while (0)

// Transpose + split weights: in (K x N fp32) -> outH/outL (N x K bf16).
__global__ __launch_bounds__(256)
void tconv_kernel(const float* __restrict__ in, u16* __restrict__ outH,
                  u16* __restrict__ outL, int K, int N)
{
    __shared__ float T[64][65];
    const int n0 = blockIdx.x * 64, k0 = blockIdx.y * 64;
    const int t = threadIdx.x;
    const int r = t >> 2, c0 = (t & 3) * 16;
#pragma unroll
    for (int i = 0; i < 4; ++i) {
        const float4 v = *(const float4*)&in[(size_t)(k0 + r) * N + n0 + c0 + 4*i];
        T[r][c0 + 4*i + 0] = v.x; T[r][c0 + 4*i + 1] = v.y;
        T[r][c0 + 4*i + 2] = v.z; T[r][c0 + 4*i + 3] = v.w;
    }
    __syncthreads();
    const int n = t >> 2, ck = (t & 3) * 16;
    u16x8 h0, h1, l0, l1;
#pragma unroll
    for (int i = 0; i < 8; ++i) { u16 h, l; splitf(T[ck + i][n], h, l); h0[i] = h; l0[i] = l; }
#pragma unroll
    for (int i = 0; i < 8; ++i) { u16 h, l; splitf(T[ck + 8 + i][n], h, l); h1[i] = h; l1[i] = l; }
    const size_t ob = (size_t)(n0 + n) * K + k0 + ck;
    *(u16x8*)&outH[ob] = h0; *(u16x8*)&outH[ob + 8] = h1;
    *(u16x8*)&outL[ob] = l0; *(u16x8*)&outL[ob + 8] = l1;
}

// Reservoir step on bf16 hi/lo state planes (row = b*512 + 4w + class).
__global__ __launch_bounds__(256)
void step_mfma_kernel(u16* __restrict__ Sh, u16* __restrict__ Sl,
                      const float* __restrict__ X,
                      const u16* __restrict__ WTh, const u16* __restrict__ WTl,
                      const u16* __restrict__ WinTh, const u16* __restrict__ WinTl,
                      int cin, int cout, int s)
{
    __shared__ u16 LB[2 * 16384];             // 2 x 32 KB slice buffers
    u16* buf0 = LB;
    u16* buf1 = LB + 16384;
    float* Cf = (float*)LB;                   // 64x128 f32 = 32 KB (epilogue)

    const int tid = threadIdx.x;
    const int q0  = blockIdx.x * 128;         // reservoir-col tile
    const int b   = blockIdx.y;
    const int bofs = b * Tt;
    const int wid = tid >> 6, lane = tid & 63;
    const int wm = wid & 1, wn = wid >> 1;
    const int l15 = lane & 15, quad = lane >> 4;

    f32x4 acc[4][4];
    const f32x4 zz = {0.f, 0.f, 0.f, 0.f};
#pragma unroll
    for (int i = 0; i < 4; ++i)
#pragma unroll
        for (int j = 0; j < 4; ++j) acc[i][j] = zz;

    // per-wave slice staging: wid 0=Ah(Sh) 1=Al(Sl) 2=Bh(WTh) 3=Bl(WTl).
    const int rl    = lane >> 2;
    const int csrc  = (((lane & 3) ^ ((lane >> 3) & 3)) << 3);
    const u16* plane = (wid == 0) ? (const u16*)Sh
                     : (wid == 1) ? (const u16*)Sl
                     : (wid == 2) ? WTh : WTl;

    auto stage = [&](u16* buf, int k0) {
        u16* ldst = buf + wid * 4096;
#pragma unroll
        for (int i = 0; i < 8; ++i) {
            const int r = i * 16 + rl;
            const size_t grow = (wid < 2) ? (size_t)(bofs + 4 * r + cin)
                                          : (size_t)(q0 + r);
            gl_lds16(&plane[grow * RES + k0 + csrc], ldst + i * 512);
        }
    };

    if (s > 0) {
        stage(buf0, 0);
        __syncthreads();                      // drains vmcnt -> buf0 ready
        for (int k0 = 0; k0 < RES; k0 += 32) {
            u16* cur = (k0 & 32) ? buf1 : buf0;
            u16* nxt = (k0 & 32) ? buf0 : buf1;
            if (k0 + 32 < RES) stage(nxt, k0 + 32);
            MFMA_TILE(cur);
            __syncthreads();                  // nxt staged; cur reads done
        }
    }

    // input projection: K=128 over x[b, 4w+s-2, :] @ Win.
    for (int k0 = 0; k0 < INd; k0 += 32) {
        if (tid < 128) {
            const int rrow = tid;             // 0..127
            const int t = 4 * rrow + s - 2;
            u16x8 h0 = {0,0,0,0,0,0,0,0}, h1 = h0, h2 = h0, h3 = h0;
            u16x8 l0 = h0, l1 = h0, l2 = h0, l3 = h0;
            if (t >= 0) {
                const float* xr = X + (size_t)(bofs + t) * INd + k0;
                const float4 f0 = *(const float4*)&xr[0];
                const float4 f1 = *(const float4*)&xr[4];
                const float4 f2 = *(const float4*)&xr[8];
                const float4 f3 = *(const float4*)&xr[12];
                const float4 f4 = *(const float4*)&xr[16];
                const float4 f5 = *(const float4*)&xr[20];
                const float4 f6 = *(const float4*)&xr[24];
                const float4 f7 = *(const float4*)&xr[28];
                split8(f0, f1, h0, l0); split8(f2, f3, h1, l1);
                split8(f4, f5, h2, l2); split8(f6, f7, h3, l3);
            }
            const int sw = (rrow >> 1) & 3;
            u16* dA = buf0 + rrow * 32;
            *(u16x8*)&dA[(0 ^ sw) << 3] = h0;
            *(u16x8*)&dA[(1 ^ sw) << 3] = h1;
            *(u16x8*)&dA[(2 ^ sw) << 3] = h2;
            *(u16x8*)&dA[(3 ^ sw) << 3] = h3;
            u16* dL = buf0 + 4096 + rrow * 32;
            *(u16x8*)&dL[(0 ^ sw) << 3] = l0;
            *(u16x8*)&dL[(1 ^ sw) << 3] = l1;
            *(u16x8*)&dL[(2 ^ sw) << 3] = l2;
            *(u16x8*)&dL[(3 ^ sw) << 3] = l3;
        } else {
            const u16* wpl = (wid == 2) ? WinTh : WinTl;
            u16* ldst = buf0 + wid * 4096;
#pragma unroll
            for (int i = 0; i < 8; ++i) {
                const int r = i * 16 + rl;
                gl_lds16(&wpl[(size_t)(q0 + r) * INd + k0 + csrc], ldst + i * 512);
            }
        }
        __syncthreads();
        MFMA_TILE(buf0);
        __syncthreads();
    }

    // epilogue via LDS: all global I/O is coalesced u16x8.
    for (int h = 0; h < 2; ++h) {
        __syncthreads();
        if (wm == h) {
#pragma unroll
            for (int i = 0; i < 4; ++i)
#pragma unroll
                for (int j = 0; j < 4; ++j)
#pragma unroll
                    for (int rg = 0; rg < 4; ++rg)
                        Cf[(i * 16 + quad * 4 + rg) * 128 + wn * 64 + j * 16 + l15]
                            = acc[i][j][rg];
        }
        __syncthreads();
#pragma unroll
        for (int pass = 0; pass < 4; ++pass) {
            const int r  = (tid >> 4) + pass * 16;      // 0..63
            const int c0 = (tid & 15) * 8;              // 0..120
            const int wrow = h * 64 + r;
            const float4 v0 = *(const float4*)&Cf[r * 128 + c0];
            const float4 v1 = *(const float4*)&Cf[r * 128 + c0 + 4];
            float vv[8] = {v0.x, v0.y, v0.z, v0.w, v1.x, v1.y, v1.z, v1.w};
            u16x8 ph, pl;
            if (s > 0) {
                const size_t prow = (size_t)(bofs + 4 * wrow + cin) * RES + q0 + c0;
                ph = *(const u16x8*)&Sh[prow];
                pl = *(const u16x8*)&Sl[prow];
            }
            u16x8 oh, ol;
#pragma unroll
            for (int e = 0; e < 8; ++e) {
                float prev = (s > 0) ? (bf2f(ph[e]) + bf2f(pl[e])) : 0.f;
                float v = 0.7f * prev + 0.3f * __sinf(vv[e]);
                u16 hh, ll; splitf(v, hh, ll);
                oh[e] = hh; ol[e] = ll;
            }
            const size_t orow = (size_t)(bofs + 4 * wrow + cout) * RES + q0 + c0;
            *(u16x8*)&Sh[orow] = oh;
            *(u16x8*)&Sl[orow] = ol;
        }
    }
}

// Gram on bf16 planes: A[b] = (Sh+Sl)(Sh+Sl)^T + ones + reg*I, bf16x3.
__global__ __launch_bounds__(256)
void gram_mfma_kernel(const u16* __restrict__ Sh, const u16* __restrict__ Sl,
                      float* __restrict__ A, const float* __restrict__ lam)
{
    __shared__ u16 LB[2 * 16384];
    u16* buf0 = LB;
    u16* buf1 = LB + 16384;
    float* Cf = (float*)LB;                   // 64 x 132 f32 = 33.8 KB

    const int tid = threadIdx.x;
    const int bt  = blockIdx.y;
    int ti = 0, rem = (int)blockIdx.x;
    while (rem >= 4 - ti) { rem -= 4 - ti; ++ti; }
    const int tj = ti + rem;
    const int n0 = ti * 128, m0 = tj * 128;
    const int bofs = bt * Tt;

    const int wid = tid >> 6, lane = tid & 63;
    const int wm = wid & 1, wn = wid >> 1;
    const int l15 = lane & 15, quad = lane >> 4;

    f32x4 acc[4][4];
    const f32x4 zz = {0.f, 0.f, 0.f, 0.f};
#pragma unroll
    for (int i = 0; i < 4; ++i)
#pragma unroll
        for (int j = 0; j < 4; ++j) acc[i][j] = zz;

    const int rl    = lane >> 2;
    const int csrc  = (((lane & 3) ^ ((lane >> 3) & 3)) << 3);
    const u16* plane = (wid & 1) ? Sl : Sh;
    const int rbase  = (wid < 2) ? n0 : m0;

    auto stage = [&](u16* buf, int k0) {
        u16* ldst = buf + wid * 4096;
#pragma unroll
        for (int i = 0; i < 8; ++i) {
            const int r = i * 16 + rl;
            gl_lds16(&plane[(size_t)(bofs + rbase + r) * RES + k0 + csrc],
                     ldst + i * 512);
        }
    };

    stage(buf0, 0);
    __syncthreads();
    for (int k0 = 0; k0 < RES; k0 += 32) {
        u16* cur = (k0 & 32) ? buf1 : buf0;
        u16* nxt = (k0 & 32) ? buf0 : buf1;
        if (k0 + 32 < RES) stage(nxt, k0 + 32);
        MFMA_TILE(cur);
        __syncthreads();
    }

    const float reg = log1pf(expf(lam[0]));
    float* Ab = A + (size_t)bt * 512 * 512;
    for (int h = 0; h < 2; ++h) {
        __syncthreads();
        if (wm == h) {
#pragma unroll
            for (int i = 0; i < 4; ++i)
#pragma unroll
                for (int j = 0; j < 4; ++j)
#pragma unroll
                    for (int rg = 0; rg < 4; ++rg)
                        Cf[(i * 16 + quad * 4 + rg) * 132 + wn * 64 + j * 16 + l15]
                            = acc[i][j][rg];
        }
        __syncthreads();
        // row-major half: rows nn = n0+h*64+r, cols m0..m0+127
#pragma unroll
        for (int pass = 0; pass < 4; ++pass) {
            const int r  = (tid >> 4) + pass * 16;
            const int c0 = (tid & 15) * 8;
            const int nn = n0 + h * 64 + r;
            float o[8];
#pragma unroll
            for (int e = 0; e < 8; ++e) {
                const int mm = m0 + c0 + e;
                float v = Cf[r * 132 + c0 + e] + 1.0f;
                if (nn == mm) v += reg;
                o[e] = v;
            }
            float* dst = Ab + (size_t)nn * 512 + m0 + c0;
            *(float4*)&dst[0] = make_float4(o[0], o[1], o[2], o[3]);
            *(float4*)&dst[4] = make_float4(o[4], o[5], o[6], o[7]);
        }
        // transposed half: rows mm = m0+rt, cols n0+h*64 .. +63
#pragma unroll
        for (int pass = 0; pass < 4; ++pass) {
            const int rt  = (tid >> 3) + pass * 32;     // 0..127
            const int c0t = (tid & 7) * 8;              // 0..56
            const int mm  = m0 + rt;
            float o[8];
#pragma unroll
            for (int e = 0; e < 8; ++e) {
                const int nn = n0 + h * 64 + c0t + e;
                float v = Cf[(c0t + e) * 132 + rt] + 1.0f;
                if (nn == mm) v += reg;
                o[e] = v;
            }
            float* dst = Ab + (size_t)mm * 512 + n0 + h * 64 + c0t;
            *(float4*)&dst[0] = make_float4(o[0], o[1], o[2], o[3]);
            *(float4*)&dst[4] = make_float4(o[4], o[5], o[6], o[7]);
        }
    }
}

// Diag-block Cholesky (64x64) + inverse, v4: RAW-pivot fused phase with
// BATCHED LDS reads. v3's phase serialized 32 predicated read-modify-writes
// (each exposing ~120cy LDS latency -> 4840 cy/phase, measured). v4 loads
// pm[16] (col j), po[16] (P row r), wo[16] (W col r) as 48 pipelined reads
// (one waitcnt), computes in VALU, then issues 32 predicated writes.
// Arithmetic identical to v3 (reads reordered; unwritten cells unchanged).
__global__ __launch_bounds__(256)
void chol_diag_inv_kernel(float* __restrict__ Aall, float* __restrict__ Winv,
                          float* __restrict__ WinvT, int k)
{
    __shared__ float P[64][65];
    __shared__ float W[64][65];
    const int b = blockIdx.x, tid = threadIdx.x;
    float* A = Aall + (size_t)b * 512 * 512;
    const int j0 = 64 * k;
    const int r = tid & 63;          // row (factor) / RHS column (inverse)
    const int q = tid >> 6;          // 16-wide strip (wave-uniform)

    // load 64x64 (each thread 16 floats); W = I
    {
        const int lr = tid >> 2, lc = (tid & 3) * 16;
#pragma unroll
        for (int i = 0; i < 4; ++i) {
            const float4 v = *(const float4*)(A + (size_t)(j0 + lr) * 512 + j0 + lc + 4*i);
            P[lr][lc + 4*i + 0] = v.x; P[lr][lc + 4*i + 1] = v.y;
            P[lr][lc + 4*i + 2] = v.z; P[lr][lc + 4*i + 3] = v.w;
        }
    }
    for (int t = tid; t < 4096; t += 256)
        W[t >> 6][t & 63] = ((t >> 6) == (t & 63)) ? 1.f : 0.f;
    __syncthreads();

    for (int j = 0; j < 64; ++j) {
        // ---- batched read phase (48 pipelined ds_reads, one waitcnt) ----
        const float pjj = P[j][j];
        const float prj = P[r][j];
        const float wjr = W[j][r];
        float pm[16], po[16], wo[16];
#pragma unroll
        for (int i = 0; i < 16; ++i) pm[i] = P[q * 16 + i][j];
#pragma unroll
        for (int i = 0; i < 16; ++i) po[i] = P[r][q * 16 + i];
#pragma unroll
        for (int i = 0; i < 16; ++i) wo[i] = W[q * 16 + i][r];
        // ---- VALU ----
        const float rd2 = 1.0f / pjj;
        const float tfa = prj * rd2;
        const float cwd = wjr * rd2;
        // ---- batched write phase (predicated, no read-after on same cell) --
#pragma unroll
        for (int i = 0; i < 16; ++i) {
            const int m = q * 16 + i;
            if (m > j && m <= r) P[r][m] = po[i] - tfa * pm[i];
        }
#pragma unroll
        for (int i = 0; i < 16; ++i) {
            const int m = q * 16 + i;
            if (m > j) W[m][r] = wo[i] - pm[i] * cwd;
        }
        __syncthreads();
    }

    // write back L: lower strictly = raw/sqrt(diag), diag = sqrt, upper = A.
    {
        const int lr = tid >> 2, lc = (tid & 3) * 16;
#pragma unroll
        for (int i = 0; i < 4; ++i) {
            float o[4];
#pragma unroll
            for (int e = 0; e < 4; ++e) {
                const int c = lc + 4*i + e;
                const float pv = P[lr][c];
                if (c < lr)       o[e] = pv / sqrtf(P[c][c]);
                else if (c == lr) o[e] = sqrtf(pv);
                else              o[e] = pv;
            }
            *(float4*)(A + (size_t)(j0 + lr) * 512 + j0 + lc + 4*i) =
                make_float4(o[0], o[1], o[2], o[3]);
        }
    }
    float* Wo  = Winv  + ((size_t)b * 8 + k) * 64 * 64;
    float* WoT = WinvT + ((size_t)b * 8 + k) * 64 * 64;
    for (int t = tid; t < 4096; t += 256) {
        const int rr = t >> 6, cc = t & 63;
        Wo[t]  = W[rr][cc] / sqrtf(P[rr][rr]);
        WoT[t] = W[cc][rr] / sqrtf(P[cc][cc]);
    }
}

// Panel TRSM via inverse: L[i0.., k] = A[i0.., k] @ W^T
__global__ __launch_bounds__(256)
void trsm_kernel(float* __restrict__ Aall, const float* __restrict__ WinvT, int k)
{
    __shared__ float St[BK][BM + 4];
    __shared__ float Wt[BK][BN + 4];
    float* A = Aall + (size_t)blockIdx.y * 512 * 512;
    const float* WT = WinvT + ((size_t)blockIdx.y * 8 + k) * 64 * 64;
    const int i0 = (k + 1 + blockIdx.x) * 64, p0 = k * 64;
    const int tid = threadIdx.x;
    const int li = tid >> 2, lk = (tid & 3) << 2;
    const int wk = tid >> 4, wq = (tid & 15) << 2;
    const int ty = tid >> 4, tx = tid & 15;
    float acc[4][4] = {};
    for (int k0 = 0; k0 < 64; k0 += BK) {
        const float4 u = *(const float4*)(A + (size_t)(i0 + li) * 512 + p0 + k0 + lk);
        St[lk + 0][li] = u.x; St[lk + 1][li] = u.y;
        St[lk + 2][li] = u.z; St[lk + 3][li] = u.w;
        *(float4*)&Wt[wk][wq] = *(const float4*)(WT + (size_t)(k0 + wk) * 64 + wq);
        __syncthreads();
        MICRO(St, Wt);
        __syncthreads();
    }
#pragma unroll
    for (int a = 0; a < 4; ++a) {
        const int r = i0 + (ty << 2) + a;
        *(float4*)(A + (size_t)r * 512 + p0 + (tx << 2)) =
            make_float4(acc[a][0], acc[a][1], acc[a][2], acc[a][3]);
    }
}

// Trailing update: A[ti,tj] -= L[ti,k] L[tj,k]^T
__global__ __launch_bounds__(256)
void chol_trailing_kernel(float* __restrict__ Aall, int k)
{
    __shared__ float Ut[BK][BM + 4];
    __shared__ float Vt[BK][BN + 4];
    float* A = Aall + (size_t)blockIdx.y * 512 * 512;
    const int tid = threadIdx.x;
    int a = 0, rem = (int)blockIdx.x;
    while (rem >= a + 1) { rem -= a + 1; ++a; }
    const int ti = k + 1 + a, tj = k + 1 + rem;
    const int i0 = ti * 64, j0c = tj * 64, p0 = k * 64;

    const int li = tid >> 2, lk = (tid & 3) << 2;
    const int ty = tid >> 4, tx = tid & 15;
    float acc[4][4] = {};

    for (int k0 = 0; k0 < 64; k0 += BK) {
        const float4 u = *(const float4*)(A + (size_t)(i0 + li) * 512 + p0 + k0 + lk);
        const float4 v = *(const float4*)(A + (size_t)(j0c + li) * 512 + p0 + k0 + lk);
        Ut[lk + 0][li] = u.x; Ut[lk + 1][li] = u.y;
        Ut[lk + 2][li] = u.z; Ut[lk + 3][li] = u.w;
        Vt[lk + 0][li] = v.x; Vt[lk + 1][li] = v.y;
        Vt[lk + 2][li] = v.z; Vt[lk + 3][li] = v.w;
        __syncthreads();
        MICRO(Ut, Vt);
        __syncthreads();
    }
#pragma unroll
    for (int aa = 0; aa < 4; ++aa) {
        const int r = i0 + (ty << 2) + aa;
        float* crow = A + (size_t)r * 512 + j0c + (tx << 2);
        float4 cv = *(const float4*)crow;
        cv.x -= acc[aa][0]; cv.y -= acc[aa][1];
        cv.z -= acc[aa][2]; cv.w -= acc[aa][3];
        *(float4*)crow = cv;
    }
}

// Blocked fwd+bwd solve, v4b: 256 blocks (32 batches x 8 col-splits), 256
// threads (thread = 1 output row x 2 cols), XCD-colocated, 4-deep static
// software pipeline with named buffers p0..p3. Replay-verified in R5/R9.
__global__ __launch_bounds__(256, 1)
void fb_solve4_kernel(const float* __restrict__ Aall,
                      const float* __restrict__ Winv,
                      const float* __restrict__ WinvT,
                      const float* __restrict__ Y, float* __restrict__ Zall)
{
    __shared__ float V[512][10];   // 8 used cols + 2 pad
    __shared__ float U[64][10];
    const int tid = threadIdx.x;
    const int b   = (int)blockIdx.x & 31;          // batch -> XCD (b mod 8)
    const int c0  = ((int)blockIdx.x >> 5) * 8;    // col-split
    const int ty  = tid >> 2;            // 0..63: output row within k-block
    const int tx  = tid & 3;             // col pair: cols 2tx, 2tx+1
    const float* A   = Aall + (size_t)b * 512 * 512;
    const float* Yb  = Y    + (size_t)b * 512 * OUTd + c0;
    float*       Zb  = Zall + (size_t)b * 512 * OUTd + c0;
    const float* Wb  = Winv  + (size_t)b * 8 * 4096 + (size_t)ty * 64;
    const float* WbT = WinvT + (size_t)b * 8 * 4096 + (size_t)ty * 64;

    for (int t = tid; t < 512 * 4; t += 256) {
        const int row = t >> 2, p = (t & 3) * 2;
        *(float2*)&V[row][p] = *(const float2*)&Yb[(size_t)row * OUTd + p];
    }
    __syncthreads();

    float acc0, acc1;
    f32x4 p0[4], p1[4], p2[4], p3[4];

#define LDF(P, c, G)                                                            \
    { const int cc_ = ((c) < (G)) ? (c) : (G) - 1;                              \
      _Pragma("unroll") for (int j_ = 0; j_ < 4; ++j_)                          \
        P[j_] = *(const f32x4*)&Arow[16 * cc_ + 4 * j_]; }

#define LDB(P, c, G)                                                            \
    { const int cc_ = ((c) < (G)) ? (c) : (G) - 1;                              \
      _Pragma("unroll") for (int j_ = 0; j_ < 16; ++j_)                         \
        P[j_ >> 2][j_ & 3] = Acol[(size_t)(m1 + 16 * cc_ + j_) * 512]; }

#define CMPV(P, kb)                                                             \
    { _Pragma("unroll") for (int q_ = 0; q_ < 16; ++q_) {                       \
        const float a_ = P[q_ >> 2][q_ & 3];                                    \
        const float2 v_ = *(const float2*)&V[(kb) + q_][2 * tx];                \
        acc0 += a_ * v_.x; acc1 += a_ * v_.y; } }

#define CMPU(P, kb)                                                             \
    { _Pragma("unroll") for (int q_ = 0; q_ < 16; ++q_) {                       \
        const float a_ = P[q_ >> 2][q_ & 3];                                    \
        const float2 v_ = *(const float2*)&U[(kb) + q_][2 * tx];                \
        acc0 += a_ * v_.x; acc1 += a_ * v_.y; } }

#define DIAG(Wrow)                                                              \
    { acc0 = 0.f; acc1 = 0.f;                                                   \
      _Pragma("unroll") for (int j_ = 0; j_ < 4; ++j_) {                        \
        p0[j_] = *(const f32x4*)&(Wrow)[ 0 + 4 * j_];                           \
        p1[j_] = *(const f32x4*)&(Wrow)[16 + 4 * j_];                           \
        p2[j_] = *(const f32x4*)&(Wrow)[32 + 4 * j_];                           \
        p3[j_] = *(const f32x4*)&(Wrow)[48 + 4 * j_]; }                         \
      CMPU(p0, 0); CMPU(p1, 16); CMPU(p2, 32); CMPU(p3, 48); }

    // ---- forward: V_k = W_k (Y_k - L[k, 0:64k] @ V) ----
    for (int k = 0; k < 8; ++k) {
        const int r0 = k * 64;
        const float* Arow = A + (size_t)(r0 + ty) * 512;
        acc0 = 0.f; acc1 = 0.f;
        const int G = r0 >> 4;                   // chunks; multiple of 4
        if (G) {
            LDF(p0, 0, G); LDF(p1, 1, G); LDF(p2, 2, G); LDF(p3, 3, G);
            for (int g = 0; g < G; g += 4) {
                CMPV(p0, 16 * g);      LDF(p0, g + 4, G);
                CMPV(p1, 16 * g + 16); LDF(p1, g + 5, G);
                CMPV(p2, 16 * g + 32); LDF(p2, g + 6, G);
                CMPV(p3, 16 * g + 48); LDF(p3, g + 7, G);
            }
        }
        U[ty][2 * tx]     = V[r0 + ty][2 * tx]     - acc0;
        U[ty][2 * tx + 1] = V[r0 + ty][2 * tx + 1] - acc1;
        __syncthreads();
        DIAG(Wb + (size_t)k * 4096);             // Winv row ty = W[ty][m]
        V[r0 + ty][2 * tx]     = acc0;
        V[r0 + ty][2 * tx + 1] = acc1;
        __syncthreads();
    }

    // ---- backward: Z_k = W_k^T (V_k - L[64(k+1):, k]^T @ Z) ----
    for (int k = 7; k >= 0; --k) {
        const int r0 = k * 64;
        const float* Acol = A + r0 + ty;
        const int m1 = r0 + 64;
        acc0 = 0.f; acc1 = 0.f;
        const int G = (448 - r0) >> 4;           // chunks; multiple of 4
        if (G) {
            LDB(p0, 0, G); LDB(p1, 1, G); LDB(p2, 2, G); LDB(p3, 3, G);
            for (int g = 0; g < G; g += 4) {
                CMPV(p0, m1 + 16 * g);      LDB(p0, g + 4, G);
                CMPV(p1, m1 + 16 * g + 16); LDB(p1, g + 5, G);
                CMPV(p2, m1 + 16 * g + 32); LDB(p2, g + 6, G);
                CMPV(p3, m1 + 16 * g + 48); LDB(p3, g + 7, G);
            }
        }
        U[ty][2 * tx]     = V[r0 + ty][2 * tx]     - acc0;
        U[ty][2 * tx + 1] = V[r0 + ty][2 * tx + 1] - acc1;
        __syncthreads();
        DIAG(WbT + (size_t)k * 4096);            // WinvT row ty = W[m][ty]
        V[r0 + ty][2 * tx]     = acc0;
        V[r0 + ty][2 * tx + 1] = acc1;
        __syncthreads();
    }

    for (int t = tid; t < 512 * 4; t += 256) {
        const int row = t >> 2, p = (t & 3) * 2;
        *(float2*)&Zb[(size_t)row * OUTd + p] = *(const float2*)&V[row][p];
    }
#undef LDF
#undef LDB
#undef CMPV
#undef CMPU
#undef DIAG
}

// w[b] = RS_b^T @ Z_b, RS reconstructed as h+l.
__global__ __launch_bounds__(256)
void out_kernel(const u16* __restrict__ Sh, const u16* __restrict__ Sl,
                const float* __restrict__ Z, float* __restrict__ Wout)
{
    __shared__ float Rt[BK][64 + 4];
    __shared__ float Zt[BK][64 + 4];
    const int tid = threadIdx.x;
    const int b   = blockIdx.y;
    const int d0  = blockIdx.x * 64;
    const int kk  = tid >> 4, cq = (tid & 15) << 2;
    const int ty  = tid >> 4, tx = tid & 15;
    float acc[4][4] = {};

    for (int k0 = 0; k0 < Tt; k0 += BK) {
        const size_t ri = (size_t)(b * Tt + k0 + kk) * RES + d0 + cq;
        const u16x4 hv = *(const u16x4*)&Sh[ri];
        const u16x4 lv = *(const u16x4*)&Sl[ri];
        Rt[kk][cq + 0] = bf2f(hv[0]) + bf2f(lv[0]);
        Rt[kk][cq + 1] = bf2f(hv[1]) + bf2f(lv[1]);
        Rt[kk][cq + 2] = bf2f(hv[2]) + bf2f(lv[2]);
        Rt[kk][cq + 3] = bf2f(hv[3]) + bf2f(lv[3]);
        *(float4*)&Zt[kk][cq] =
            *(const float4*)(Z + ((size_t)b * Tt + k0 + kk) * OUTd + cq);
        __syncthreads();
        MICRO(Rt, Zt);
        __syncthreads();
    }
#pragma unroll
    for (int a = 0; a < 4; ++a) {
        const int d = d0 + (ty << 2) + a;
        *(float4*)(Wout + ((size_t)b * RES + d) * OUTd + (tx << 2)) =
            make_float4(acc[a][0], acc[a][1], acc[a][2], acc[a][3]);
    }
}

// bias: 256 threads/batch, 4 partial sums of 128 rows each + LDS reduce.
__global__ __launch_bounds__(256)
void bias_kernel(const float* __restrict__ Z, float* __restrict__ Bout)
{
    __shared__ float S[4][64];
    const int b = blockIdx.x;
    const int o = threadIdx.x & 63, g = threadIdx.x >> 6;
    const float* Zb = Z + (size_t)b * Tt * OUTd;
    float s = 0.f;
    for (int n = g * 128; n < (g + 1) * 128; ++n) s += Zb[(size_t)n * OUTd + o];
    S[g][o] = s;
    __syncthreads();
    if (threadIdx.x < 64)
        Bout[(size_t)b * OUTd + o] = ((S[0][o] + S[1][o]) + S[2][o]) + S[3][o];
}

extern "C" void kernel_launch(void* const* d_in, const int* in_sizes, int n_in,
                              void* d_out, int out_size, void* d_ws, size_t ws_size,
                              hipStream_t stream)
{
    const float* X    = (const float*)d_in[0];   // (32,512,128)
    const float* Y    = (const float*)d_in[1];   // (32,512,64)
    const float* Wres = (const float*)d_in[2];   // (2048,2048)
    const float* Win  = (const float*)d_in[3];   // (128,2048)
    const float* lam  = (const float*)d_in[4];   // scalar

    float* out  = (float*)d_out;
    float* Wout = out;
    float* Bout = out + (size_t)Bb * RES * OUTd;

    // ws: Sh 64 | Sl 64 | WTh 8 | WTl 8 | WinTh .5 | WinTl .5 | A 32 | Z 4 | Wi 4 | WiT 4 = 189 MB
    char* p = (char*)d_ws;
    u16* Sh    = (u16*)p;   p += (size_t)Bb * Tt * RES * 2;
    u16* Sl    = (u16*)p;   p += (size_t)Bb * Tt * RES * 2;
    u16* WTh   = (u16*)p;   p += (size_t)RES * RES * 2;
    u16* WTl   = (u16*)p;   p += (size_t)RES * RES * 2;
    u16* WinTh = (u16*)p;   p += (size_t)INd * RES * 2;
    u16* WinTl = (u16*)p;   p += (size_t)INd * RES * 2;
    float* A   = (float*)p; p += (size_t)Bb * 512 * 512 * 4;
    float* Z   = (float*)p; p += (size_t)Bb * Tt * OUTd * 4;
    float* Wi  = (float*)p; p += (size_t)Bb * 8 * 64 * 64 * 4;
    float* WiT = (float*)p;

    const dim3 blk(256);
    tconv_kernel<<<dim3(RES / 64, RES / 64), blk, 0, stream>>>(Wres, WTh, WTl, RES, RES);
    tconv_kernel<<<dim3(RES / 64, INd / 64), blk, 0, stream>>>(Win, WinTh, WinTl, INd, RES);

    // classes: s:(cin->cout) 0:(-,2) 1:(2,1) 2:(1,0) 3:(0,1) 4:(1,2) 5:(2,3)
    const dim3 sgrid(RES / 128, Bb);
    step_mfma_kernel<<<sgrid, blk, 0, stream>>>(Sh, Sl, X, WTh, WTl, WinTh, WinTl, 0, 2, 0);
    step_mfma_kernel<<<sgrid, blk, 0, stream>>>(Sh, Sl, X, WTh, WTl, WinTh, WinTl, 2, 1, 1);
    step_mfma_kernel<<<sgrid, blk, 0, stream>>>(Sh, Sl, X, WTh, WTl, WinTh, WinTl, 1, 0, 2);
    step_mfma_kernel<<<sgrid, blk, 0, stream>>>(Sh, Sl, X, WTh, WTl, WinTh, WinTl, 0, 1, 3);
    step_mfma_kernel<<<sgrid, blk, 0, stream>>>(Sh, Sl, X, WTh, WTl, WinTh, WinTl, 1, 2, 4);
    step_mfma_kernel<<<sgrid, blk, 0, stream>>>(Sh, Sl, X, WTh, WTl, WinTh, WinTl, 2, 3, 5);

    gram_mfma_kernel<<<dim3(10, Bb), blk, 0, stream>>>(Sh, Sl, A, lam);

    for (int k = 0; k < 8; ++k) {
        chol_diag_inv_kernel<<<dim3(Bb), dim3(256), 0, stream>>>(A, Wi, WiT, k);
        if (k < 7) {
            trsm_kernel<<<dim3(7 - k, Bb), blk, 0, stream>>>(A, WiT, k);
            const int m = 7 - k;
            chol_trailing_kernel<<<dim3(m * (m + 1) / 2, Bb), blk, 0, stream>>>(A, k);
        }
    }
    fb_solve4_kernel<<<dim3(Bb * 8), dim3(256), 0, stream>>>(A, Wi, WiT, Y, Z);

    out_kernel<<<dim3(RES / 64, Bb), blk, 0, stream>>>(Sh, Sl, Z, Wout);
    bias_kernel<<<dim3(Bb), dim3(256), 0, stream>>>(Z, Bout);
}